// Round 6
// baseline (16953.911 us; speedup 1.0000x reference)
//
#include <hip/hip_runtime.h>

#define EPSV 1e-5f

typedef unsigned int uivec4 __attribute__((ext_vector_type(4)));

__device__ __forceinline__ float b2f(unsigned short u) {
  unsigned int x = ((unsigned int)u) << 16;
  return __uint_as_float(x);
}
__device__ __forceinline__ unsigned short f2b(float f) {
  unsigned int x = __float_as_uint(f);
  unsigned int r = (x + 0x7FFFu + ((x >> 16) & 1u)) >> 16;
  return (unsigned short)r;
}
__device__ __forceinline__ float sigm(float x) { return 1.0f / (1.0f + expf(-x)); }
__device__ __forceinline__ float bflo(unsigned int u) { return __uint_as_float(u << 16); }
__device__ __forceinline__ float bfhi(unsigned int u) { return __uint_as_float(u & 0xFFFF0000u); }

// ---- coherence-point (device-coherent) access: bypass L1+L2 both ways ----
__device__ __forceinline__ void stg_bf16(unsigned short* p, float v) {
  unsigned short h = f2b(v);
  asm volatile("global_store_short %0, %1, off sc0 sc1" ::"v"(p), "v"(h) : "memory");
}
__device__ __forceinline__ void ldg2_sc(const unsigned short* p0, const unsigned short* p1,
                                        uivec4& a, uivec4& b) {
  asm volatile(
      "global_load_dwordx4 %0, %2, off sc0 sc1\n\t"
      "global_load_dwordx4 %1, %3, off sc0 sc1\n\t"
      "s_waitcnt vmcnt(0)"
      : "=&v"(a), "=&v"(b)
      : "v"(p0), "v"(p1)
      : "memory");
}
// 8 x 16B: two buffers, offsets 0/16/32/48
__device__ __forceinline__ void ldg8o_sc(const unsigned short* p0, const unsigned short* p1,
                                         uivec4& a, uivec4& b, uivec4& c, uivec4& d,
                                         uivec4& e, uivec4& f, uivec4& g, uivec4& h) {
  asm volatile(
      "global_load_dwordx4 %0, %8, off sc0 sc1\n\t"
      "global_load_dwordx4 %1, %8, off offset:16 sc0 sc1\n\t"
      "global_load_dwordx4 %2, %8, off offset:32 sc0 sc1\n\t"
      "global_load_dwordx4 %3, %8, off offset:48 sc0 sc1\n\t"
      "global_load_dwordx4 %4, %9, off sc0 sc1\n\t"
      "global_load_dwordx4 %5, %9, off offset:16 sc0 sc1\n\t"
      "global_load_dwordx4 %6, %9, off offset:32 sc0 sc1\n\t"
      "global_load_dwordx4 %7, %9, off offset:48 sc0 sc1\n\t"
      "s_waitcnt vmcnt(0)"
      : "=&v"(a), "=&v"(b), "=&v"(c), "=&v"(d), "=&v"(e), "=&v"(f), "=&v"(g), "=&v"(h)
      : "v"(p0), "v"(p1)
      : "memory");
}
// 12 x 16B: three buffers
__device__ __forceinline__ void ldg12_sc(const unsigned short* p0, const unsigned short* p1,
                                         const unsigned short* p2, uivec4* r) {
  asm volatile(
      "global_load_dwordx4 %0, %12, off sc0 sc1\n\t"
      "global_load_dwordx4 %1, %12, off offset:16 sc0 sc1\n\t"
      "global_load_dwordx4 %2, %12, off offset:32 sc0 sc1\n\t"
      "global_load_dwordx4 %3, %12, off offset:48 sc0 sc1\n\t"
      "global_load_dwordx4 %4, %13, off sc0 sc1\n\t"
      "global_load_dwordx4 %5, %13, off offset:16 sc0 sc1\n\t"
      "global_load_dwordx4 %6, %13, off offset:32 sc0 sc1\n\t"
      "global_load_dwordx4 %7, %13, off offset:48 sc0 sc1\n\t"
      "global_load_dwordx4 %8, %14, off sc0 sc1\n\t"
      "global_load_dwordx4 %9, %14, off offset:16 sc0 sc1\n\t"
      "global_load_dwordx4 %10, %14, off offset:32 sc0 sc1\n\t"
      "global_load_dwordx4 %11, %14, off offset:48 sc0 sc1\n\t"
      "s_waitcnt vmcnt(0)"
      : "=&v"(r[0]), "=&v"(r[1]), "=&v"(r[2]), "=&v"(r[3]), "=&v"(r[4]), "=&v"(r[5]),
        "=&v"(r[6]), "=&v"(r[7]), "=&v"(r[8]), "=&v"(r[9]), "=&v"(r[10]), "=&v"(r[11])
      : "v"(p0), "v"(p1), "v"(p2)
      : "memory");
}
__device__ __forceinline__ void bf8_to_lds(float* dst, uivec4 u) {
  float2 p;
  p.x = __uint_as_float(u.x << 16); p.y = __uint_as_float(u.x & 0xFFFF0000u);
  *(float2*)(dst + 0) = p;
  p.x = __uint_as_float(u.y << 16); p.y = __uint_as_float(u.y & 0xFFFF0000u);
  *(float2*)(dst + 2) = p;
  p.x = __uint_as_float(u.z << 16); p.y = __uint_as_float(u.z & 0xFFFF0000u);
  *(float2*)(dst + 4) = p;
  p.x = __uint_as_float(u.w << 16); p.y = __uint_as_float(u.w & 0xFFFF0000u);
  *(float2*)(dst + 6) = p;
}
__device__ __forceinline__ unsigned int ldcnt(const unsigned int* p) {
  return __hip_atomic_load(p, __ATOMIC_RELAXED, __HIP_MEMORY_SCOPE_AGENT);
}

// ---------------- dtype detection ----------------
__global__ void k_detect(const void* __restrict__ embp, const void* __restrict__ zmp,
                         int* __restrict__ flags) {
  __shared__ int sh[4];
  int tid = threadIdx.x;
  if (tid < 4) sh[tid] = 0;
  __syncthreads();
  const unsigned short* u = (const unsigned short*)embp;
  int bad = 0;
  for (int i = tid; i < 4096; i += 256) {
    float f = fabsf(b2f(u[i]));
    if (!(f < 1e10f)) bad = 1;
  }
  if (bad) atomicAdd(&sh[3], 1);
  const unsigned char* p = (const unsigned char*)zmp;
  int codd = 0, c0 = 0, c1v = 0;
  for (int i = tid; i < 65536; i += 256) {
    unsigned char v = p[i];
    if (v) {
      if (i & 1) codd++;
      if ((i & 3) == 0) c0++;
      if (v == 1) c1v++;
    }
  }
  atomicAdd(&sh[0], codd); atomicAdd(&sh[1], c0); atomicAdd(&sh[2], c1v);
  __syncthreads();
  if (tid == 0) {
    flags[0] = sh[3] ? 1 : 0;
    int mode;
    if (sh[0] == 0) mode = 1;
    else if (sh[2] > 0) mode = 0;
    else if (sh[1] == 0) mode = 2;
    else mode = 3;
    flags[1] = mode;
  }
}

__global__ void k_cvt(const void* __restrict__ src, float* __restrict__ dst, int n,
                      const int* __restrict__ flags) {
  int i = blockIdx.x * 256 + threadIdx.x;
  if (i >= n) return;
  if (flags[0]) dst[i] = ((const float*)src)[i];
  else dst[i] = b2f(((const unsigned short*)src)[i]);
}

__device__ __forceinline__ bool mask_at(const void* p, size_t i, int mode) {
  switch (mode) {
    case 0: return ((const unsigned char*)p)[i] != 0;
    case 1: return ((const int*)p)[i] != 0;
    case 2: return ((const float*)p)[i] != 0.0f;
    default: return ((const unsigned short*)p)[i] != 0;
  }
}

// ---------------- embedding ----------------
__global__ void k_embed(const int* __restrict__ ph, const float* __restrict__ emb,
                        float* __restrict__ X) {
  int bl = blockIdx.x;
  int p = ph[bl];
  X[(size_t)bl * 256 + threadIdx.x] = emb[(size_t)p * 256 + threadIdx.x];
}

// ---------------- k=3 conv, E=256 -> E=256, SAME ----------------
__global__ __launch_bounds__(256) void k_conv3(const float* __restrict__ X,
                                               const float* __restrict__ Wc,
                                               float* __restrict__ Y) {
  __shared__ float xs[6 * 256];
  int blk = blockIdx.x;
  int b = blk >> 6, l0 = (blk & 63) * 4;
  for (int i = threadIdx.x; i < 6 * 256; i += 256) {
    int dl = i >> 8, ci = i & 255;
    int ll = l0 - 1 + dl;
    xs[i] = (ll >= 0 && ll < 256) ? X[(size_t)(b * 256 + ll) * 256 + ci] : 0.0f;
  }
  __syncthreads();
  int co = threadIdx.x;
  float acc[4] = {0.f, 0.f, 0.f, 0.f};
  for (int i = 0; i < 768; ++i) {
    int d = i >> 8, ci = i & 255;
    float wv = Wc[(size_t)i * 256 + co];
#pragma unroll
    for (int j = 0; j < 4; ++j) acc[j] += xs[(d + j) * 256 + ci] * wv;
  }
#pragma unroll
  for (int j = 0; j < 4; ++j) Y[(size_t)(b * 256 + l0 + j) * 256 + co] = acc[j];
}

// ---------------- per-channel mean/var ----------------
__global__ __launch_bounds__(256) void k_colstats(const float* __restrict__ X, int R, int C,
                                                  float* __restrict__ st) {
  int c = blockIdx.x;
  float s = 0.f, q = 0.f;
  for (int r = threadIdx.x; r < R; r += 256) {
    float v = X[(size_t)r * C + c];
    s += v; q += v * v;
  }
  __shared__ float rs_[256], rq_[256];
  rs_[threadIdx.x] = s; rq_[threadIdx.x] = q;
  __syncthreads();
  for (int k = 128; k > 0; k >>= 1) {
    if (threadIdx.x < k) { rs_[threadIdx.x] += rs_[threadIdx.x + k]; rq_[threadIdx.x] += rq_[threadIdx.x + k]; }
    __syncthreads();
  }
  if (threadIdx.x == 0) {
    float m = rs_[0] / R;
    st[c] = m;
    st[C + c] = rq_[0] / R - m * m;
  }
}

template <int ACT>
__global__ void k_bnact(const float* __restrict__ X, float* __restrict__ Y,
                        const float* __restrict__ st, const float* __restrict__ sc,
                        const float* __restrict__ of, int Cmask, int n) {
  int i = blockIdx.x * 256 + threadIdx.x;
  if (i >= n) return;
  int C = Cmask + 1;
  int c = i & Cmask;
  float m = st[c], v = st[C + c];
  float y = (X[i] - m) * rsqrtf(v + EPSV) * sc[c] + of[c];
  Y[i] = ACT ? tanhf(y) : fmaxf(y, 0.0f);
}

// ---------------- generic GEMM ----------------
// OBF: 0=f32 row-major, 1=bf16 row-major,
//      2=bf16 decoder-gate layout [t][w128][b16][g4*4+j],
//      3=f32  encoder-gate layout [l][w64][b16][g4*4+j]
template <int OBF>
__global__ __launch_bounds__(256) void k_gemm(const float* __restrict__ Ap,
                                              const float* __restrict__ Bp,
                                              const float* __restrict__ bias,
                                              void* __restrict__ Cp, int M, int K, int N) {
  __shared__ float al[16 * 768];
  int row0 = blockIdx.x * 16;
  int c = blockIdx.y * 256 + threadIdx.x;
  for (int i = threadIdx.x; i < 16 * K; i += 256) al[i] = Ap[(size_t)row0 * K + i];
  __syncthreads();
  float acc[16];
  float bv = bias ? bias[c] : 0.0f;
#pragma unroll
  for (int j = 0; j < 16; ++j) acc[j] = bv;
  for (int k = 0; k < K; ++k) {
    float b = Bp[(size_t)k * N + c];
#pragma unroll
    for (int j = 0; j < 16; ++j) acc[j] += al[j * K + k] * b;
  }
  if (OBF == 0) {
    float* C = (float*)Cp;
#pragma unroll
    for (int j = 0; j < 16; ++j) C[(size_t)(row0 + j) * N + c] = acc[j];
  } else if (OBF == 1) {
    unsigned short* C = (unsigned short*)Cp;
#pragma unroll
    for (int j = 0; j < 16; ++j) C[(size_t)(row0 + j) * N + c] = f2b(acc[j]);
  } else if (OBF == 2) {
    unsigned short* C = (unsigned short*)Cp;
    int g = c >> 9, w = (c & 511) >> 2, jj = c & 3;
#pragma unroll
    for (int j = 0; j < 16; ++j) {
      int row = row0 + j;
      int b = row >> 9, t = row & 511;
      C[((size_t)t * 128 + w) * 256 + b * 16 + g * 4 + jj] = f2b(acc[j]);
    }
  } else {
    float* C = (float*)Cp;
    int g = c >> 8, w = (c & 255) >> 2, jj = c & 3;
#pragma unroll
    for (int j = 0; j < 16; ++j) {
      int row = row0 + j;
      int b = row >> 8, l = row & 255;
      C[((size_t)l * 64 + w) * 256 + b * 16 + g * 4 + jj] = acc[j];
    }
  }
}

// ---------------- duration cumsum ----------------
__global__ void k_cumsum(const float* __restrict__ dur, float* __restrict__ mid) {
  int b = threadIdx.x;
  if (b >= 16) return;
  float run = 0.f;
  for (int l = 0; l < 256; ++l) {
    float d = dur[b * 256 + l];
    run += d;
    mid[b * 256 + l] = run - 0.5f * d;
  }
}

// ---------------- persistent bi-LSTM encoder ----------------
// grid 128: wg<64 fwd, >=64 bwd. Each wg owns 4 h-cols (of 256). 256 threads.
// Conflict-free LDS: row stride 258 (==2 mod 32), stage mapping b=tid&15.
#define EHS 258
__global__ __launch_bounds__(256) void k_enc_lstm(const float* __restrict__ GFp,
                                                  const float* __restrict__ GBp,
                                                  const float* __restrict__ Wf,
                                                  const float* __restrict__ Wb,
                                                  float* __restrict__ enc,
                                                  unsigned short* __restrict__ encB,
                                                  const int* __restrict__ lengths,
                                                  unsigned int* __restrict__ cnt) {
  const int tid = threadIdx.x;
  const int wg = blockIdx.x;
  const int dir = wg >> 6;
  const int w = wg & 63;
  const float* Gpre = dir ? GBp : GFp;
  const float* W = dir ? Wb : Wf;
  unsigned int* c_self = cnt + (size_t)dir * 256 * 128;

  __shared__ __align__(16) float hs[16 * EHS];
  __shared__ __align__(16) float wh[16 * EHS];
  __shared__ float part2[16 * 258];
  __shared__ float gl[256];
  __shared__ float cst[64];
  __shared__ int rs[16];

  for (int i = tid; i < 16 * 256; i += 256) {
    int gc = i >> 8, k = i & 255;
    wh[gc * EHS + k] = W[(size_t)(256 + k) * 1024 + (gc >> 2) * 256 + (w * 4 + (gc & 3))];
  }
  if (tid < 64) cst[tid] = 0.0f;
  __syncthreads();

  const int og = tid >> 4, s = tid & 15;
  const int bq = og >> 2, jj = og & 3;
  const int b_ = tid >> 4, j_ = (tid >> 2) & 3, g_ = tid & 3;
  const int bqr = tid >> 6, ar = (tid >> 4) & 3, jjr = (tid >> 2) & 3, gr = tid & 3;

  for (int t = 0; t < 256; ++t) {
    const int l = dir ? (255 - t) : t;
    if (tid < 16) rs[tid] = (dir == 1) && (l >= lengths[tid] - 1);
    float gpre = Gpre[((size_t)l * 64 + w) * 256 + b_ * 16 + g_ * 4 + j_];
    if (t > 0 && tid < 8) {
      const unsigned int* a = c_self + (size_t)(t - 1) * 128 + tid * 16;
      unsigned int gcount = 0;
      while (ldcnt(a) < 8u) {
        __builtin_amdgcn_s_sleep(2);
        if (++gcount > (1u << 16)) break;
      }
    }
    __syncthreads();
    if (t > 0) {
      const int lprev = dir ? (l + 1) : (l - 1);
      int b = tid & 15, q = tid >> 4;  // b=tid&15 -> conflict-reduced LDS writes
      const unsigned short* p = encB + ((size_t)dir << 20) + (((size_t)lprev * 16 + b) << 8) + q * 16;
      uivec4 a0, a1;
      ldg2_sc(p, p + 8, a0, a1);
      if (rs[b]) {
        a0.x = a0.y = a0.z = a0.w = 0u;
        a1.x = a1.y = a1.z = a1.w = 0u;
      }
      float* d = &hs[b * EHS + q * 16];
      bf8_to_lds(d, a0);
      bf8_to_lds(d + 8, a1);
    }
    __syncthreads();

    float acc[4][4];
#pragma unroll
    for (int a = 0; a < 4; ++a) { acc[a][0] = 0; acc[a][1] = 0; acc[a][2] = 0; acc[a][3] = 0; }
    if (t > 0) {
      const int b0 = bq * 4;
#pragma unroll
      for (int i = 0; i < 8; ++i) {
        int kk = i * 32 + 2 * s;
        float2 h0 = *(const float2*)&hs[(b0 + 0) * EHS + kk];
        float2 h1 = *(const float2*)&hs[(b0 + 1) * EHS + kk];
        float2 h2 = *(const float2*)&hs[(b0 + 2) * EHS + kk];
        float2 h3 = *(const float2*)&hs[(b0 + 3) * EHS + kk];
#pragma unroll
        for (int g = 0; g < 4; ++g) {
          float2 wv = *(const float2*)&wh[(g * 4 + jj) * EHS + kk];
          acc[0][g] += h0.x * wv.x + h0.y * wv.y;
          acc[1][g] += h1.x * wv.x + h1.y * wv.y;
          acc[2][g] += h2.x * wv.x + h2.y * wv.y;
          acc[3][g] += h3.x * wv.x + h3.y * wv.y;
        }
      }
    }
#pragma unroll
    for (int a = 0; a < 4; ++a)
#pragma unroll
      for (int g = 0; g < 4; ++g)
        part2[(a * 4 + g) * 258 + tid] = acc[a][g];
    __syncthreads();
    {
      float sum = gpre;
      if (t > 0) {
        int base = (ar * 4 + gr) * 258 + (bqr * 4 + jjr) * 16;
#pragma unroll
        for (int ss = 0; ss < 16; ++ss) sum += part2[base + ss];
      }
      gl[tid] = sum;
    }
    __syncthreads();
    if (tid < 64) {
      int b = tid >> 2, j = tid & 3;
      float4 G = ((const float4*)gl)[tid];
      float c = cst[tid];
      if (t == 0 || rs[b]) c = 0.0f;
      c = sigm(G.z + 1.0f) * c + sigm(G.x) * tanhf(G.y);
      float h = sigm(G.w) * tanhf(c);
      cst[tid] = c;
      enc[(size_t)(b * 256 + l) * 512 + dir * 256 + (w * 4 + j)] = h;  // plain, cross-kernel
      stg_bf16(&encB[((size_t)dir << 20) + (((size_t)l * 16 + b) << 8) + (w * 4 + j)], h);
    }
    asm volatile("s_waitcnt vmcnt(0)" ::: "memory");
    __syncthreads();
    if (tid == 0)
      __hip_atomic_fetch_add(c_self + (size_t)t * 128 + (w >> 3) * 16, 1u,
                             __ATOMIC_RELAXED, __HIP_MEMORY_SCOPE_AGENT);
  }
}

// ---------------- Gaussian-softmax upsampling ----------------
__global__ __launch_bounds__(256) void k_upsample(const float* __restrict__ mid,
                                                  const float* __restrict__ enc,
                                                  float* __restrict__ cond) {
  int blk = blockIdx.x;
  int b = blk >> 5, t0 = (blk & 31) * 16;
  int tid = threadIdx.x;
  __shared__ float wls[16][256];
  __shared__ float red[256];
  float mp = mid[b * 256 + tid];
  for (int tt = 0; tt < 16; ++tt) {
    float tpos = (float)(t0 + tt);
    float d = mp - tpos;
    float d2 = d * d * 0.1f;
    red[tid] = d2; __syncthreads();
    for (int k = 128; k > 0; k >>= 1) { if (tid < k) red[tid] = fminf(red[tid], red[tid + k]); __syncthreads(); }
    float mn = red[0]; __syncthreads();
    float e = expf(mn - d2);
    red[tid] = e; __syncthreads();
    for (int k = 128; k > 0; k >>= 1) { if (tid < k) red[tid] += red[tid + k]; __syncthreads(); }
    float sum = red[0]; __syncthreads();
    wls[tt][tid] = e / sum;
  }
  __syncthreads();
  float a0[16], a1[16];
#pragma unroll
  for (int i = 0; i < 16; ++i) { a0[i] = 0; a1[i] = 0; }
  for (int l = 0; l < 256; ++l) {
    float e0 = enc[(size_t)(b * 256 + l) * 512 + tid];
    float e1 = enc[(size_t)(b * 256 + l) * 512 + 256 + tid];
#pragma unroll
    for (int tt = 0; tt < 16; ++tt) { float wv = wls[tt][l]; a0[tt] += wv * e0; a1[tt] += wv * e1; }
  }
  for (int tt = 0; tt < 16; ++tt) {
    cond[(size_t)(b * 512 + t0 + tt) * 512 + tid] = a0[tt];
    cond[(size_t)(b * 512 + t0 + tt) * 512 + 256 + tid] = a1[tt];
  }
}

__global__ void k_concat(const float* __restrict__ cond, const float* __restrict__ p,
                         float* __restrict__ din) {
  size_t i = (size_t)blockIdx.x * 256 + threadIdx.x;
  int r = (int)(i / 768);
  int c = (int)(i % 768);
  din[i] = (c < 512) ? cond[(size_t)r * 512 + c] : p[(size_t)r * 256 + (c - 512)];
}

// ---------------- merged 2-layer zoneout LSTM decoder ----------------
// 128 WGs; WG w owns cols [4w,4w+4) of BOTH layers. L2 lags L1 by one step.
// One flag round + one broadcast per super-step tau (0..512).
#define DHSU 776  // u32 stride per batch-row: 768 pairs (h1c|h1n|h2c) + 8 pad
#define DW1S 514  // f32 stride wh1
#define DW2S 520  // u32 stride wh2 (bf16-packed)
__global__ __launch_bounds__(256) void k_dec_lstm(
    const unsigned short* __restrict__ D1x, const unsigned short* __restrict__ D2x,
    const float* __restrict__ W1, const float* __restrict__ W2,
    const void* __restrict__ zh1, const void* __restrict__ zc1,
    const void* __restrict__ zh2, const void* __restrict__ zc2,
    unsigned short* __restrict__ h1cB, unsigned short* __restrict__ h1nB,
    unsigned short* __restrict__ h2cB,
    float* __restrict__ h1n, float* __restrict__ h2n,
    unsigned int* __restrict__ cnt1,
    const int* __restrict__ flags) {
  const int tid = threadIdx.x;
  const int w = blockIdx.x;  // 0..127

  __shared__ __align__(16) unsigned int hsu[16 * DHSU];
  __shared__ __align__(16) float wh1[16 * DW1S];
  __shared__ __align__(16) unsigned int wh2u[16 * DW2S];
  __shared__ float part2[32 * 258];
  __shared__ float gl1[256], gl2[256];
  __shared__ float cst1[64], hst1[64], cst2[64], hst2[64];

  const int mmode = flags[1];

  for (int i = tid; i < 16 * 512; i += 256) {
    int gc = i >> 9, k = i & 511;
    wh1[gc * DW1S + k] = W1[(size_t)(768 + k) * 2048 + (gc >> 2) * 512 + (w * 4 + (gc & 3))];
  }
  for (int i = tid; i < 16 * 512; i += 256) {
    int gc = i >> 9, pu = i & 511;
    const float* src = &W2[(size_t)(768 + 2 * pu) * 2048 + (gc >> 2) * 512 + (w * 4 + (gc & 3))];
    unsigned int lo = f2b(src[0]);
    unsigned int hi = f2b(src[2048]);
    wh2u[gc * DW2S + pu] = lo | (hi << 16);
  }
  if (tid < 64) { cst1[tid] = 0; hst1[tid] = 0; cst2[tid] = 0; hst2[tid] = 0; }
  __syncthreads();

  const int og = tid >> 4, s = tid & 15;
  const int bq = og >> 2, jj = og & 3;
  const int b0 = bq * 4;
  const int b_ = tid >> 4, j_ = (tid >> 2) & 3, g_ = tid & 3;
  const int bqr = tid >> 6, ar = (tid >> 4) & 3, jjr = (tid >> 2) & 3, gr = tid & 3;

  for (int tau = 0; tau <= 512; ++tau) {
    // prefetch gates (plain loads, static data)
    float dxv1 = 0.0f, dxv2 = 0.0f;
    if (tau < 512)
      dxv1 = b2f(D1x[((size_t)tau * 128 + w) * 256 + b_ * 16 + g_ * 4 + j_]);
    if (tau >= 1)
      dxv2 = b2f(D2x[((size_t)(tau - 1) * 128 + w) * 256 + b_ * 16 + g_ * 4 + j_]);

    if (tau >= 1 && tid < 8) {
      const unsigned int* a = cnt1 + (size_t)(tau - 1) * 128 + tid * 16;
      unsigned int gcount = 0;
      while (ldcnt(a) < 16u) {
        __builtin_amdgcn_s_sleep(2);
        if (++gcount > (1u << 16)) break;
      }
    }
    __syncthreads();

    if (tau >= 1) {
      int b = tid & 15, q = tid >> 4;
      const unsigned short* p0 = h1cB + (((size_t)(tau - 1) * 16 + b) << 9) + q * 32;
      const unsigned short* p1 = h1nB + (((size_t)(tau - 1) * 16 + b) << 9) + q * 32;
      uivec4 r[12];
      if (tau >= 2) {
        const unsigned short* p2 = h2cB + (((size_t)(tau - 2) * 16 + b) << 9) + q * 32;
        ldg12_sc(p0, p1, p2, r);
      } else {
        ldg8o_sc(p0, p1, r[0], r[1], r[2], r[3], r[4], r[5], r[6], r[7]);
        uivec4 z; z.x = z.y = z.z = z.w = 0u;
        r[8] = z; r[9] = z; r[10] = z; r[11] = z;
      }
      unsigned int base = b * DHSU + q * 16;
#pragma unroll
      for (int m = 0; m < 3; ++m)
#pragma unroll
        for (int grp = 0; grp < 4; ++grp)
          *(uivec4*)&hsu[base + m * 256 + grp * 4] = r[m * 4 + grp];
    }
    __syncthreads();

    const bool doDot1 = (tau >= 1 && tau < 512);
    const bool doDot2 = (tau >= 1);
    float acc1[4][4], acc2[4][4];
#pragma unroll
    for (int a = 0; a < 4; ++a)
#pragma unroll
      for (int g = 0; g < 4; ++g) { acc1[a][g] = 0.0f; acc2[a][g] = 0.0f; }

    if (doDot1) {
      for (int i = 0; i < 16; ++i) {
        int p = i * 16 + s;
        unsigned int u0 = hsu[(b0 + 0) * DHSU + p];
        unsigned int u1 = hsu[(b0 + 1) * DHSU + p];
        unsigned int u2 = hsu[(b0 + 2) * DHSU + p];
        unsigned int u3 = hsu[(b0 + 3) * DHSU + p];
        float l0 = bflo(u0), h0 = bfhi(u0), l1 = bflo(u1), h1 = bfhi(u1);
        float l2 = bflo(u2), h2 = bfhi(u2), l3 = bflo(u3), h3 = bfhi(u3);
#pragma unroll
        for (int g = 0; g < 4; ++g) {
          float2 wv = *(const float2*)&wh1[(g * 4 + jj) * DW1S + 2 * p];
          acc1[0][g] += l0 * wv.x + h0 * wv.y;
          acc1[1][g] += l1 * wv.x + h1 * wv.y;
          acc1[2][g] += l2 * wv.x + h2 * wv.y;
          acc1[3][g] += l3 * wv.x + h3 * wv.y;
        }
      }
    }
    if (doDot2) {
      for (int i = 0; i < 32; ++i) {
        int pk = i * 16 + s;
        int p = 256 + pk;
        unsigned int u0 = hsu[(b0 + 0) * DHSU + p];
        unsigned int u1 = hsu[(b0 + 1) * DHSU + p];
        unsigned int u2 = hsu[(b0 + 2) * DHSU + p];
        unsigned int u3 = hsu[(b0 + 3) * DHSU + p];
        float l0 = bflo(u0), h0 = bfhi(u0), l1 = bflo(u1), h1 = bfhi(u1);
        float l2 = bflo(u2), h2 = bfhi(u2), l3 = bflo(u3), h3 = bfhi(u3);
#pragma unroll
        for (int g = 0; g < 4; ++g) {
          unsigned int wu = wh2u[(g * 4 + jj) * DW2S + pk];
          float wl = bflo(wu), whi = bfhi(wu);
          acc2[0][g] += l0 * wl + h0 * whi;
          acc2[1][g] += l1 * wl + h1 * whi;
          acc2[2][g] += l2 * wl + h2 * whi;
          acc2[3][g] += l3 * wl + h3 * whi;
        }
      }
    }
#pragma unroll
    for (int a = 0; a < 4; ++a)
#pragma unroll
      for (int g = 0; g < 4; ++g) {
        part2[(a * 4 + g) * 258 + tid] = acc1[a][g];
        part2[(16 + a * 4 + g) * 258 + tid] = acc2[a][g];
      }
    __syncthreads();
    {
      int base = (ar * 4 + gr) * 258 + (bqr * 4 + jjr) * 16;
      float s1 = dxv1, s2 = dxv2;
      if (doDot1) {
#pragma unroll
        for (int ss = 0; ss < 16; ++ss) s1 += part2[base + ss];
      }
      if (doDot2) {
#pragma unroll
        for (int ss = 0; ss < 16; ++ss) s2 += part2[16 * 258 + base + ss];
      }
      gl1[tid] = s1;
      gl2[tid] = s2;
    }
    __syncthreads();

    if (tid < 64) {
      if (tau < 512) {
        int b = tid >> 2, j = tid & 3, colg = w * 4 + j;
        float4 G = ((const float4*)gl1)[tid];
        float cold = (tau == 0) ? 0.0f : cst1[tid];
        float hold = (tau == 0) ? 0.0f : hst1[tid];
        float nc = sigm(G.z + 1.0f) * cold + sigm(G.x) * tanhf(G.y);
        float nh = sigm(G.w) * tanhf(nc);
        size_t mi = ((size_t)b * 512 + tau) * 512 + colg;
        bool mh = mask_at(zh1, mi, mmode);
        bool mc = mask_at(zc1, mi, mmode);
        cst1[tid] = mc ? cold : nc;
        float hkeep = mh ? hold : nh;
        hst1[tid] = hkeep;
        h1n[(size_t)(tau * 16 + b) * 512 + colg] = nh;  // plain f32 for k_proj
        stg_bf16(&h1cB[(((size_t)tau * 16 + b) << 9) + colg], hkeep);
        stg_bf16(&h1nB[(((size_t)tau * 16 + b) << 9) + colg], nh);
      }
    } else if (tid < 128) {
      if (tau >= 1) {
        int u = tid - 64;
        int t2 = tau - 1;
        int b = u >> 2, j = u & 3, colg = w * 4 + j;
        float4 G = ((const float4*)gl2)[u];
        float cold = (tau == 1) ? 0.0f : cst2[u];
        float hold = (tau == 1) ? 0.0f : hst2[u];
        float nc = sigm(G.z + 1.0f) * cold + sigm(G.x) * tanhf(G.y);
        float nh = sigm(G.w) * tanhf(nc);
        size_t mi = ((size_t)b * 512 + t2) * 512 + colg;
        bool mh = mask_at(zh2, mi, mmode);
        bool mc = mask_at(zc2, mi, mmode);
        cst2[u] = mc ? cold : nc;
        float hkeep = mh ? hold : nh;
        hst2[u] = hkeep;
        h2n[(size_t)(t2 * 16 + b) * 512 + colg] = nh;  // plain f32 for k_proj
        stg_bf16(&h2cB[(((size_t)t2 * 16 + b) << 9) + colg], hkeep);
      }
    }
    asm volatile("s_waitcnt vmcnt(0)" ::: "memory");
    __syncthreads();
    if (tid == 0)
      __hip_atomic_fetch_add(cnt1 + (size_t)tau * 128 + (w >> 4) * 16, 1u,
                             __ATOMIC_RELAXED, __HIP_MEMORY_SCOPE_AGENT);
  }
}

// ---------------- projection ----------------
__global__ __launch_bounds__(320) void k_proj(const float* __restrict__ cond,
                                              const float* __restrict__ h1n,
                                              const float* __restrict__ h2n,
                                              const float* __restrict__ pw,
                                              const float* __restrict__ pb,
                                              float* __restrict__ mel) {
  __shared__ float as_[4 * 1536];
  int r0 = blockIdx.x * 4;
  for (int i = threadIdx.x; i < 4 * 1536; i += 320) {
    int row = i / 1536, k = i % 1536;
    int r = r0 + row;
    int b = r >> 9, t = r & 511;
    float v;
    if (k < 512) v = cond[(size_t)r * 512 + k];
    else if (k < 1024) v = h1n[(size_t)(t * 16 + b) * 512 + (k - 512)];
    else v = h2n[(size_t)(t * 16 + b) * 512 + (k - 1024)];
    as_[i] = v;
  }
  __syncthreads();
  int row = threadIdx.x / 80, co = threadIdx.x % 80;
  float acc = pb[co];
  for (int k = 0; k < 1536; ++k) acc += as_[row * 1536 + k] * pw[(size_t)k * 80 + co];
  mel[(size_t)(r0 + row) * 80 + co] = acc;
}

// ---------------- k=5 conv ----------------
__global__ __launch_bounds__(256) void k_conv5(const float* __restrict__ X, int Cin,
                                               float* __restrict__ Y, int Cout,
                                               const float* __restrict__ Wc,
                                               const float* __restrict__ bias) {
  extern __shared__ float ys[];
  int blk = blockIdx.x;
  int b = blk >> 6, t0 = (blk & 63) * 8;
  for (int i = threadIdx.x; i < 12 * Cin; i += 256) {
    int rr = i / Cin, ci = i % Cin;
    int tt = t0 - 2 + rr;
    ys[i] = (tt >= 0 && tt < 512) ? X[(size_t)(b * 512 + tt) * Cin + ci] : 0.0f;
  }
  __syncthreads();
  for (int co = threadIdx.x; co < Cout; co += 256) {
    float acc[8];
    float bv = bias ? bias[co] : 0.0f;
#pragma unroll
    for (int j = 0; j < 8; ++j) acc[j] = bv;
    for (int dt = 0; dt < 5; ++dt)
      for (int ci = 0; ci < Cin; ++ci) {
        float wv = Wc[(size_t)(dt * Cin + ci) * Cout + co];
#pragma unroll
        for (int j = 0; j < 8; ++j) acc[j] += ys[(j + dt) * Cin + ci] * wv;
      }
#pragma unroll
    for (int j = 0; j < 8; ++j) Y[(size_t)(b * 512 + t0 + j) * Cout + co] = acc[j];
  }
}

__global__ void k_out(const float* __restrict__ mel, const float* __restrict__ res,
                      void* __restrict__ out, const int* __restrict__ flags) {
  int i = blockIdx.x * 256 + threadIdx.x;
  float m = mel[i];
  float f = m + res[i];
  if (flags[0]) {
    ((float*)out)[i] = m;
    ((float*)out)[655360 + i] = f;
  } else {
    unsigned short* o = (unsigned short*)out;
    o[i] = f2b(m);
    o[655360 + i] = f2b(f);
  }
}

// ---------------- host launch ----------------
extern "C" void kernel_launch(void* const* d_in, const int* in_sizes, int n_in,
                              void* d_out, int out_size, void* d_ws, size_t ws_size,
                              hipStream_t stream) {
  char* ws = (char*)d_ws;
  size_t o = 0;
  auto A_ = [&](size_t nb) { size_t r = o; o += (nb + 255) & ~(size_t)255; return r; };
  const size_t FLAGS = A_(256);
  const size_t SYNC = A_(786432);
  const size_t STATS = A_(4096);
  const size_t C_MELS = A_(655360ull * 4), C_DUR = A_(4096 * 4), C_EMB = A_(65536 * 4),
               C_ECW = A_(589824ull * 4), C_EBS = A_(768 * 4), C_EBO = A_(768 * 4),
               C_LFW = A_(524288ull * 4), C_LFB = A_(1024 * 4), C_LBW = A_(524288ull * 4),
               C_LBB = A_(1024 * 4), C_PW1 = A_(20480 * 4), C_P1S = A_(256 * 4),
               C_P1O = A_(256 * 4), C_PW2 = A_(65536 * 4), C_P2S = A_(256 * 4),
               C_P2O = A_(256 * 4), C_DW1 = A_(2621440ull * 4), C_DB1 = A_(2048 * 4),
               C_DW2 = A_(3670016ull * 4), C_DB2 = A_(2048 * 4), C_PRW = A_(122880ull * 4),
               C_PRB = A_(512), C_W0 = A_(204800ull * 4), C_WM = A_(3932160ull * 4),
               C_W4 = A_(204800ull * 4), C_B4 = A_(512), C_PBS = A_(2048 * 4),
               C_PBO = A_(2048 * 4);
  const size_t R1 = A_(16777216), R2 = A_(16777216), R3 = A_(16777216), R4 = A_(16777216),
               MID = A_(4096 * 4), R5 = A_(16777216), R6 = A_(16777216), R7 = A_(25165824),
               D1X = A_(33554432), D2X = A_(33554432), MELP = A_(2621440);
  const size_t XA = R1, XB = R1 + 4194304;
  const size_t GF = R2;
  const size_t GB = R3, H1N = R3;
  const size_t ENC = R4, H2N = R4;
  const size_t COND = R5, PA = R5;
  const size_t PREA = R6, PREB = R6 + 8388608, PB = R6;
  const size_t DECIN = R7, RESID = R7;
  // bf16 broadcast buffers (intra-kernel only; read via sc0/sc1 bypass -> alias-safe)
  const size_t H1CB = R1, H1NB = R1 + 8388608;  // decoder phase: R1 free
  const size_t H2CB = R2;                       // decoder phase: R2 free
  const size_t ENCB = R7;                       // encoder phase: R7 untouched until concat

  auto F = [&](size_t off) { return (float*)(ws + off); };
  auto U = [&](size_t off) { return (unsigned short*)(ws + off); };
  int* flags = (int*)(ws + FLAGS);
  unsigned int* cntE = (unsigned int*)(ws + SYNC);
  unsigned int* cnt1 = (unsigned int*)(ws + SYNC + 262144);

  hipMemsetAsync(ws + SYNC, 0, 786432, stream);
  k_detect<<<1, 256, 0, stream>>>(d_in[8], d_in[4], flags);

  struct CV { int idx; size_t off; int n; };
  const CV cvs[] = {
      {2, C_MELS, 655360}, {3, C_DUR, 4096}, {8, C_EMB, 65536}, {9, C_ECW, 589824},
      {10, C_EBS, 768}, {11, C_EBO, 768}, {12, C_LFW, 524288}, {13, C_LFB, 1024},
      {14, C_LBW, 524288}, {15, C_LBB, 1024}, {16, C_PW1, 20480}, {17, C_P1S, 256},
      {18, C_P1O, 256}, {19, C_PW2, 65536}, {20, C_P2S, 256}, {21, C_P2O, 256},
      {22, C_DW1, 2621440}, {23, C_DB1, 2048}, {24, C_DW2, 3670016}, {25, C_DB2, 2048},
      {26, C_PRW, 122880}, {27, C_PRB, 80}, {28, C_W0, 204800}, {29, C_WM, 3932160},
      {30, C_W4, 204800}, {31, C_B4, 80}, {32, C_PBS, 2048}, {33, C_PBO, 2048}};
  for (int i = 0; i < (int)(sizeof(cvs) / sizeof(cvs[0])); ++i)
    k_cvt<<<(cvs[i].n + 255) / 256, 256, 0, stream>>>(d_in[cvs[i].idx], F(cvs[i].off), cvs[i].n, flags);

  k_embed<<<4096, 256, 0, stream>>>((const int*)d_in[0], F(C_EMB), F(XA));
  for (int i = 0; i < 3; ++i) {
    k_conv3<<<1024, 256, 0, stream>>>(F(XA), F(C_ECW) + (size_t)i * 196608, F(XB));
    k_colstats<<<256, 256, 0, stream>>>(F(XB), 4096, 256, F(STATS));
    k_bnact<0><<<4096, 256, 0, stream>>>(F(XB), F(XA), F(STATS), F(C_EBS) + i * 256, F(C_EBO) + i * 256, 255, 1048576);
  }
  k_gemm<3><<<dim3(256, 4), 256, 0, stream>>>(F(XA), F(C_LFW), F(C_LFB), (void*)(ws + GF), 4096, 256, 1024);
  k_gemm<3><<<dim3(256, 4), 256, 0, stream>>>(F(XA), F(C_LBW), F(C_LBB), (void*)(ws + GB), 4096, 256, 1024);
  k_cumsum<<<1, 64, 0, stream>>>(F(C_DUR), F(MID));
  k_enc_lstm<<<128, 256, 0, stream>>>(F(GF), F(GB), F(C_LFW), F(C_LBW), F(ENC), U(ENCB),
                                      (const int*)d_in[1], cntE);
  k_upsample<<<512, 256, 0, stream>>>(F(MID), F(ENC), F(COND));

  k_gemm<0><<<dim3(512, 1), 256, 0, stream>>>(F(C_MELS), F(C_PW1), nullptr, (void*)(ws + PREA), 8192, 80, 256);
  k_colstats<<<256, 256, 0, stream>>>(F(PREA), 8192, 256, F(STATS));
  k_bnact<0><<<8192, 256, 0, stream>>>(F(PREA), F(PREB), F(STATS), F(C_P1S), F(C_P1O), 255, 2097152);
  k_gemm<0><<<dim3(512, 1), 256, 0, stream>>>(F(PREB), F(C_PW2), nullptr, (void*)(ws + PREA), 8192, 256, 256);
  k_colstats<<<256, 256, 0, stream>>>(F(PREA), 8192, 256, F(STATS));
  k_bnact<0><<<8192, 256, 0, stream>>>(F(PREA), F(PREB), F(STATS), F(C_P2S), F(C_P2O), 255, 2097152);

  k_concat<<<24576, 256, 0, stream>>>(F(COND), F(PREB), F(DECIN));
  k_gemm<2><<<dim3(512, 8), 256, 0, stream>>>(F(DECIN), F(C_DW1), F(C_DB1), (void*)(ws + D1X), 8192, 768, 2048);
  k_gemm<2><<<dim3(512, 8), 256, 0, stream>>>(F(DECIN), F(C_DW2), F(C_DB2), (void*)(ws + D2X), 8192, 768, 2048);
  k_dec_lstm<<<128, 256, 0, stream>>>((const unsigned short*)(ws + D1X), (const unsigned short*)(ws + D2X),
                                      F(C_DW1), F(C_DW2), d_in[4], d_in[5], d_in[6], d_in[7],
                                      U(H1CB), U(H1NB), U(H2CB),
                                      F(H1N), F(H2N), cnt1, flags);
  k_proj<<<2048, 320, 0, stream>>>(F(COND), F(H1N), F(H2N), F(C_PRW), F(C_PRB), F(MELP));

  k_conv5<<<1024, 256, 12 * 80 * 4, stream>>>(F(MELP), 80, F(PA), 512, F(C_W0), nullptr);
  k_colstats<<<512, 256, 0, stream>>>(F(PA), 8192, 512, F(STATS));
  k_bnact<1><<<16384, 256, 0, stream>>>(F(PA), F(PB), F(STATS), F(C_PBS), F(C_PBO), 511, 4194304);
  for (int i = 0; i < 3; ++i) {
    k_conv5<<<1024, 256, 12 * 512 * 4, stream>>>(F(PB), 512, F(PA), 512, F(C_WM) + (size_t)i * 1310720, nullptr);
    k_colstats<<<512, 256, 0, stream>>>(F(PA), 8192, 512, F(STATS));
    k_bnact<1><<<16384, 256, 0, stream>>>(F(PA), F(PB), F(STATS), F(C_PBS) + (i + 1) * 512, F(C_PBO) + (i + 1) * 512, 511, 4194304);
  }
  k_conv5<<<1024, 256, 12 * 512 * 4, stream>>>(F(PB), 512, F(RESID), 80, F(C_W4), F(C_B4));
  k_out<<<2560, 256, 0, stream>>>(F(MELP), F(RESID), d_out, flags);
}

// Round 7
// 16269.405 us; speedup vs baseline: 1.0421x; 1.0421x over previous
//
#include <hip/hip_runtime.h>

#define EPSV 1e-5f

typedef unsigned int uivec4 __attribute__((ext_vector_type(4)));

__device__ __forceinline__ float b2f(unsigned short u) {
  unsigned int x = ((unsigned int)u) << 16;
  return __uint_as_float(x);
}
__device__ __forceinline__ unsigned short f2b(float f) {
  unsigned int x = __float_as_uint(f);
  unsigned int r = (x + 0x7FFFu + ((x >> 16) & 1u)) >> 16;
  return (unsigned short)r;
}
__device__ __forceinline__ float sigm(float x) { return 1.0f / (1.0f + expf(-x)); }
__device__ __forceinline__ float bflo(unsigned int u) { return __uint_as_float(u << 16); }
__device__ __forceinline__ float bfhi(unsigned int u) { return __uint_as_float(u & 0xFFFF0000u); }

// ---- coherence-point (device-coherent) access: bypass L1+L2 both ways ----
__device__ __forceinline__ void stg_bf16(unsigned short* p, float v) {
  unsigned short h = f2b(v);
  asm volatile("global_store_short %0, %1, off sc0 sc1" ::"v"(p), "v"(h) : "memory");
}
__device__ __forceinline__ void ldg2_sc(const unsigned short* p0, const unsigned short* p1,
                                        uivec4& a, uivec4& b) {
  asm volatile(
      "global_load_dwordx4 %0, %2, off sc0 sc1\n\t"
      "global_load_dwordx4 %1, %3, off sc0 sc1\n\t"
      "s_waitcnt vmcnt(0)"
      : "=&v"(a), "=&v"(b)
      : "v"(p0), "v"(p1)
      : "memory");
}
// 4 x 16B from one pointer at byte offsets 0/256/512/768 (no wait)
__device__ __forceinline__ void ldg4f_nw(const unsigned short* p, uivec4& a, uivec4& b,
                                         uivec4& c, uivec4& d) {
  asm volatile(
      "global_load_dwordx4 %0, %4, off sc0 sc1\n\t"
      "global_load_dwordx4 %1, %4, off offset:256 sc0 sc1\n\t"
      "global_load_dwordx4 %2, %4, off offset:512 sc0 sc1\n\t"
      "global_load_dwordx4 %3, %4, off offset:768 sc0 sc1"
      : "=&v"(a), "=&v"(b), "=&v"(c), "=&v"(d)
      : "v"(p)
      : "memory");
}
__device__ __forceinline__ void vm0() { asm volatile("s_waitcnt vmcnt(0)" ::: "memory"); }

__device__ __forceinline__ void bf8_to_lds(float* dst, uivec4 u) {
  float2 p;
  p.x = __uint_as_float(u.x << 16); p.y = __uint_as_float(u.x & 0xFFFF0000u);
  *(float2*)(dst + 0) = p;
  p.x = __uint_as_float(u.y << 16); p.y = __uint_as_float(u.y & 0xFFFF0000u);
  *(float2*)(dst + 2) = p;
  p.x = __uint_as_float(u.z << 16); p.y = __uint_as_float(u.z & 0xFFFF0000u);
  *(float2*)(dst + 4) = p;
  p.x = __uint_as_float(u.w << 16); p.y = __uint_as_float(u.w & 0xFFFF0000u);
  *(float2*)(dst + 6) = p;
}
__device__ __forceinline__ unsigned int ldcnt(const unsigned int* p) {
  return __hip_atomic_load(p, __ATOMIC_RELAXED, __HIP_MEMORY_SCOPE_AGENT);
}

// ---------------- dtype detection ----------------
__global__ void k_detect(const void* __restrict__ embp, const void* __restrict__ zmp,
                         int* __restrict__ flags) {
  __shared__ int sh[4];
  int tid = threadIdx.x;
  if (tid < 4) sh[tid] = 0;
  __syncthreads();
  const unsigned short* u = (const unsigned short*)embp;
  int bad = 0;
  for (int i = tid; i < 4096; i += 256) {
    float f = fabsf(b2f(u[i]));
    if (!(f < 1e10f)) bad = 1;
  }
  if (bad) atomicAdd(&sh[3], 1);
  const unsigned char* p = (const unsigned char*)zmp;
  int codd = 0, c0 = 0, c1v = 0;
  for (int i = tid; i < 65536; i += 256) {
    unsigned char v = p[i];
    if (v) {
      if (i & 1) codd++;
      if ((i & 3) == 0) c0++;
      if (v == 1) c1v++;
    }
  }
  atomicAdd(&sh[0], codd); atomicAdd(&sh[1], c0); atomicAdd(&sh[2], c1v);
  __syncthreads();
  if (tid == 0) {
    flags[0] = sh[3] ? 1 : 0;
    int mode;
    if (sh[0] == 0) mode = 1;
    else if (sh[2] > 0) mode = 0;
    else if (sh[1] == 0) mode = 2;
    else mode = 3;
    flags[1] = mode;
  }
}

__global__ void k_cvt(const void* __restrict__ src, float* __restrict__ dst, int n,
                      const int* __restrict__ flags) {
  int i = blockIdx.x * 256 + threadIdx.x;
  if (i >= n) return;
  if (flags[0]) dst[i] = ((const float*)src)[i];
  else dst[i] = b2f(((const unsigned short*)src)[i]);
}

__device__ __forceinline__ bool mask_at(const void* p, size_t i, int mode) {
  switch (mode) {
    case 0: return ((const unsigned char*)p)[i] != 0;
    case 1: return ((const int*)p)[i] != 0;
    case 2: return ((const float*)p)[i] != 0.0f;
    default: return ((const unsigned short*)p)[i] != 0;
  }
}

// ---------------- embedding ----------------
__global__ void k_embed(const int* __restrict__ ph, const float* __restrict__ emb,
                        float* __restrict__ X) {
  int bl = blockIdx.x;
  int p = ph[bl];
  X[(size_t)bl * 256 + threadIdx.x] = emb[(size_t)p * 256 + threadIdx.x];
}

// ---------------- k=3 conv, E=256 -> E=256, SAME ----------------
__global__ __launch_bounds__(256) void k_conv3(const float* __restrict__ X,
                                               const float* __restrict__ Wc,
                                               float* __restrict__ Y) {
  __shared__ float xs[6 * 256];
  int blk = blockIdx.x;
  int b = blk >> 6, l0 = (blk & 63) * 4;
  for (int i = threadIdx.x; i < 6 * 256; i += 256) {
    int dl = i >> 8, ci = i & 255;
    int ll = l0 - 1 + dl;
    xs[i] = (ll >= 0 && ll < 256) ? X[(size_t)(b * 256 + ll) * 256 + ci] : 0.0f;
  }
  __syncthreads();
  int co = threadIdx.x;
  float acc[4] = {0.f, 0.f, 0.f, 0.f};
  for (int i = 0; i < 768; ++i) {
    int d = i >> 8, ci = i & 255;
    float wv = Wc[(size_t)i * 256 + co];
#pragma unroll
    for (int j = 0; j < 4; ++j) acc[j] += xs[(d + j) * 256 + ci] * wv;
  }
#pragma unroll
  for (int j = 0; j < 4; ++j) Y[(size_t)(b * 256 + l0 + j) * 256 + co] = acc[j];
}

// ---------------- per-channel mean/var: 2-stage coalesced, deterministic ----------------
// stage1: 256 row-blocks; thread c sweeps columns (coalesced). part[blk][2C]: sums then sumsq.
__global__ __launch_bounds__(256) void k_cs1(const float* __restrict__ X, int RB, int C,
                                             float* __restrict__ part) {
  int blk = blockIdx.x;
  int r0 = blk * RB;
  float s0 = 0.f, q0 = 0.f, s1 = 0.f, q1 = 0.f;
  for (int rr = 0; rr < RB; ++rr) {
    const float* row = X + (size_t)(r0 + rr) * C;
    float v = row[threadIdx.x];
    s0 += v; q0 += v * v;
    if (C > 256) {
      float v1 = row[256 + threadIdx.x];
      s1 += v1; q1 += v1 * v1;
    }
  }
  float* pr = part + (size_t)blk * 2 * C;
  pr[threadIdx.x] = s0;
  pr[C + threadIdx.x] = q0;
  if (C > 256) {
    pr[256 + threadIdx.x] = s1;
    pr[C + 256 + threadIdx.x] = q1;
  }
}
// stage2: one block per column; reduce 256 partials.
__global__ __launch_bounds__(256) void k_cs2(const float* __restrict__ part, int C, int R,
                                             float* __restrict__ st) {
  int c = blockIdx.x;
  int t = threadIdx.x;
  __shared__ float rs_[256], rq_[256];
  rs_[t] = part[(size_t)t * 2 * C + c];
  rq_[t] = part[(size_t)t * 2 * C + C + c];
  __syncthreads();
  for (int k = 128; k > 0; k >>= 1) {
    if (t < k) { rs_[t] += rs_[t + k]; rq_[t] += rq_[t + k]; }
    __syncthreads();
  }
  if (t == 0) {
    float m = rs_[0] / R;
    st[c] = m;
    st[C + c] = rq_[0] / R - m * m;
  }
}

template <int ACT>
__global__ void k_bnact(const float* __restrict__ X, float* __restrict__ Y,
                        const float* __restrict__ st, const float* __restrict__ sc,
                        const float* __restrict__ of, int Cmask, int n) {
  int i = blockIdx.x * 256 + threadIdx.x;
  if (i >= n) return;
  int C = Cmask + 1;
  int c = i & Cmask;
  float m = st[c], v = st[C + c];
  float y = (X[i] - m) * rsqrtf(v + EPSV) * sc[c] + of[c];
  Y[i] = ACT ? tanhf(y) : fmaxf(y, 0.0f);
}

// ---------------- generic GEMM ----------------
template <int OBF>
__global__ __launch_bounds__(256) void k_gemm(const float* __restrict__ Ap,
                                              const float* __restrict__ Bp,
                                              const float* __restrict__ bias,
                                              void* __restrict__ Cp, int M, int K, int N) {
  __shared__ float al[16 * 768];
  int row0 = blockIdx.x * 16;
  int c = blockIdx.y * 256 + threadIdx.x;
  for (int i = threadIdx.x; i < 16 * K; i += 256) al[i] = Ap[(size_t)row0 * K + i];
  __syncthreads();
  float acc[16];
  float bv = bias ? bias[c] : 0.0f;
#pragma unroll
  for (int j = 0; j < 16; ++j) acc[j] = bv;
  for (int k = 0; k < K; ++k) {
    float b = Bp[(size_t)k * N + c];
#pragma unroll
    for (int j = 0; j < 16; ++j) acc[j] += al[j * K + k] * b;
  }
  if (OBF == 0) {
    float* C = (float*)Cp;
#pragma unroll
    for (int j = 0; j < 16; ++j) C[(size_t)(row0 + j) * N + c] = acc[j];
  } else if (OBF == 1) {
    unsigned short* C = (unsigned short*)Cp;
#pragma unroll
    for (int j = 0; j < 16; ++j) C[(size_t)(row0 + j) * N + c] = f2b(acc[j]);
  } else if (OBF == 2) {
    unsigned short* C = (unsigned short*)Cp;
    int g = c >> 9, w = (c & 511) >> 2, jj = c & 3;
#pragma unroll
    for (int j = 0; j < 16; ++j) {
      int row = row0 + j;
      int b = row >> 9, t = row & 511;
      C[((size_t)t * 128 + w) * 256 + b * 16 + g * 4 + jj] = f2b(acc[j]);
    }
  } else {
    float* C = (float*)Cp;
    int g = c >> 8, w = (c & 255) >> 2, jj = c & 3;
#pragma unroll
    for (int j = 0; j < 16; ++j) {
      int row = row0 + j;
      int b = row >> 8, l = row & 255;
      C[((size_t)l * 64 + w) * 256 + b * 16 + g * 4 + jj] = acc[j];
    }
  }
}

// ---------------- duration cumsum ----------------
__global__ void k_cumsum(const float* __restrict__ dur, float* __restrict__ mid) {
  int b = threadIdx.x;
  if (b >= 16) return;
  float run = 0.f;
  for (int l = 0; l < 256; ++l) {
    float d = dur[b * 256 + l];
    run += d;
    mid[b * 256 + l] = run - 0.5f * d;
  }
}

// ---------------- persistent bi-LSTM encoder ----------------
#define EHS 258
__global__ __launch_bounds__(256) void k_enc_lstm(const float* __restrict__ GFp,
                                                  const float* __restrict__ GBp,
                                                  const float* __restrict__ Wf,
                                                  const float* __restrict__ Wb,
                                                  float* __restrict__ enc,
                                                  unsigned short* __restrict__ encB,
                                                  const int* __restrict__ lengths,
                                                  unsigned int* __restrict__ cnt) {
  const int tid = threadIdx.x;
  const int wg = blockIdx.x;
  const int dir = wg >> 6;
  const int w = wg & 63;
  const float* Gpre = dir ? GBp : GFp;
  const float* W = dir ? Wb : Wf;
  unsigned int* c_self = cnt + (size_t)dir * 256 * 128;

  __shared__ __align__(16) float hs[16 * EHS];
  __shared__ __align__(16) float wh[16 * EHS];
  __shared__ float part2[16 * 258];
  __shared__ float gl[256];
  __shared__ float cst[64];
  __shared__ int rs[16];

  for (int i = tid; i < 16 * 256; i += 256) {
    int gc = i >> 8, k = i & 255;
    wh[gc * EHS + k] = W[(size_t)(256 + k) * 1024 + (gc >> 2) * 256 + (w * 4 + (gc & 3))];
  }
  if (tid < 64) cst[tid] = 0.0f;
  __syncthreads();

  const int og = tid >> 4, s = tid & 15;
  const int bq = og >> 2, jj = og & 3;
  const int b_ = tid >> 4, j_ = (tid >> 2) & 3, g_ = tid & 3;
  const int bqr = tid >> 6, ar = (tid >> 4) & 3, jjr = (tid >> 2) & 3, gr = tid & 3;

  for (int t = 0; t < 256; ++t) {
    const int l = dir ? (255 - t) : t;
    if (tid < 16) rs[tid] = (dir == 1) && (l >= lengths[tid] - 1);
    float gpre = Gpre[((size_t)l * 64 + w) * 256 + b_ * 16 + g_ * 4 + j_];
    if (t > 0 && tid < 8) {
      const unsigned int* a = c_self + (size_t)(t - 1) * 128 + tid * 16;
      unsigned int gcount = 0;
      while (ldcnt(a) < 8u) {
        __builtin_amdgcn_s_sleep(2);
        if (++gcount > (1u << 16)) break;
      }
    }
    __syncthreads();
    if (t > 0) {
      const int lprev = dir ? (l + 1) : (l - 1);
      int b = tid & 15, q = tid >> 4;
      const unsigned short* p = encB + ((size_t)dir << 20) + (((size_t)lprev * 16 + b) << 8) + q * 16;
      uivec4 a0, a1;
      ldg2_sc(p, p + 8, a0, a1);
      if (rs[b]) {
        a0.x = a0.y = a0.z = a0.w = 0u;
        a1.x = a1.y = a1.z = a1.w = 0u;
      }
      float* d = &hs[b * EHS + q * 16];
      bf8_to_lds(d, a0);
      bf8_to_lds(d + 8, a1);
    }
    __syncthreads();

    float acc[4][4];
#pragma unroll
    for (int a = 0; a < 4; ++a) { acc[a][0] = 0; acc[a][1] = 0; acc[a][2] = 0; acc[a][3] = 0; }
    if (t > 0) {
      const int b0 = bq * 4;
#pragma unroll
      for (int i = 0; i < 8; ++i) {
        int kk = i * 32 + 2 * s;
        float2 h0 = *(const float2*)&hs[(b0 + 0) * EHS + kk];
        float2 h1 = *(const float2*)&hs[(b0 + 1) * EHS + kk];
        float2 h2 = *(const float2*)&hs[(b0 + 2) * EHS + kk];
        float2 h3 = *(const float2*)&hs[(b0 + 3) * EHS + kk];
#pragma unroll
        for (int g = 0; g < 4; ++g) {
          float2 wv = *(const float2*)&wh[(g * 4 + jj) * EHS + kk];
          acc[0][g] += h0.x * wv.x + h0.y * wv.y;
          acc[1][g] += h1.x * wv.x + h1.y * wv.y;
          acc[2][g] += h2.x * wv.x + h2.y * wv.y;
          acc[3][g] += h3.x * wv.x + h3.y * wv.y;
        }
      }
    }
#pragma unroll
    for (int a = 0; a < 4; ++a)
#pragma unroll
      for (int g = 0; g < 4; ++g)
        part2[(a * 4 + g) * 258 + tid] = acc[a][g];
    __syncthreads();
    {
      float sum = gpre;
      if (t > 0) {
        int base = (ar * 4 + gr) * 258 + (bqr * 4 + jjr) * 16;
#pragma unroll
        for (int ss = 0; ss < 16; ++ss) sum += part2[base + ss];
      }
      gl[tid] = sum;
    }
    __syncthreads();
    if (tid < 64) {
      int b = tid >> 2, j = tid & 3;
      float4 G = ((const float4*)gl)[tid];
      float c = cst[tid];
      if (t == 0 || rs[b]) c = 0.0f;
      c = sigm(G.z + 1.0f) * c + sigm(G.x) * tanhf(G.y);
      float h = sigm(G.w) * tanhf(c);
      cst[tid] = c;
      enc[(size_t)(b * 256 + l) * 512 + dir * 256 + (w * 4 + j)] = h;
      stg_bf16(&encB[((size_t)dir << 20) + (((size_t)l * 16 + b) << 8) + (w * 4 + j)], h);
    }
    vm0();
    __syncthreads();
    if (tid == 0)
      __hip_atomic_fetch_add(c_self + (size_t)t * 128 + (w >> 3) * 16, 1u,
                             __ATOMIC_RELAXED, __HIP_MEMORY_SCOPE_AGENT);
  }
}

// ---------------- Gaussian-softmax upsampling ----------------
__global__ __launch_bounds__(256) void k_upsample(const float* __restrict__ mid,
                                                  const float* __restrict__ enc,
                                                  float* __restrict__ cond) {
  int blk = blockIdx.x;
  int b = blk >> 5, t0 = (blk & 31) * 16;
  int tid = threadIdx.x;
  __shared__ float wls[16][256];
  __shared__ float red[256];
  float mp = mid[b * 256 + tid];
  for (int tt = 0; tt < 16; ++tt) {
    float tpos = (float)(t0 + tt);
    float d = mp - tpos;
    float d2 = d * d * 0.1f;
    red[tid] = d2; __syncthreads();
    for (int k = 128; k > 0; k >>= 1) { if (tid < k) red[tid] = fminf(red[tid], red[tid + k]); __syncthreads(); }
    float mn = red[0]; __syncthreads();
    float e = expf(mn - d2);
    red[tid] = e; __syncthreads();
    for (int k = 128; k > 0; k >>= 1) { if (tid < k) red[tid] += red[tid + k]; __syncthreads(); }
    float sum = red[0]; __syncthreads();
    wls[tt][tid] = e / sum;
  }
  __syncthreads();
  float a0[16], a1[16];
#pragma unroll
  for (int i = 0; i < 16; ++i) { a0[i] = 0; a1[i] = 0; }
  for (int l = 0; l < 256; ++l) {
    float e0 = enc[(size_t)(b * 256 + l) * 512 + tid];
    float e1 = enc[(size_t)(b * 256 + l) * 512 + 256 + tid];
#pragma unroll
    for (int tt = 0; tt < 16; ++tt) { float wv = wls[tt][l]; a0[tt] += wv * e0; a1[tt] += wv * e1; }
  }
  for (int tt = 0; tt < 16; ++tt) {
    cond[(size_t)(b * 512 + t0 + tt) * 512 + tid] = a0[tt];
    cond[(size_t)(b * 512 + t0 + tt) * 512 + 256 + tid] = a1[tt];
  }
}

__global__ void k_concat(const float* __restrict__ cond, const float* __restrict__ p,
                         float* __restrict__ din) {
  size_t i = (size_t)blockIdx.x * 256 + threadIdx.x;
  int r = (int)(i / 768);
  int c = (int)(i % 768);
  din[i] = (c < 512) ? cond[(size_t)r * 512 + c] : p[(size_t)r * 256 + (c - 512)];
}

// ---------------- merged 2-layer zoneout LSTM decoder ----------------
#define DHSU 776
#define DW1S 514
#define DW2S 520
__global__ __launch_bounds__(256) void k_dec_lstm(
    const unsigned short* __restrict__ D1x, const unsigned short* __restrict__ D2x,
    const float* __restrict__ W1, const float* __restrict__ W2,
    const void* __restrict__ zh1, const void* __restrict__ zc1,
    const void* __restrict__ zh2, const void* __restrict__ zc2,
    unsigned short* __restrict__ h1cB, unsigned short* __restrict__ h1nB,
    unsigned short* __restrict__ h2cB,
    float* __restrict__ h1n, float* __restrict__ h2n,
    unsigned int* __restrict__ cnt1,
    const int* __restrict__ flags) {
  const int tid = threadIdx.x;
  const int w = blockIdx.x;

  __shared__ __align__(16) unsigned int hsu[16 * DHSU];
  __shared__ __align__(16) float wh1[16 * DW1S];
  __shared__ __align__(16) unsigned int wh2u[16 * DW2S];
  __shared__ float part2[32 * 258];
  __shared__ float gl1[256], gl2[256];
  __shared__ float cst1[64], hst1[64], cst2[64], hst2[64];

  const int mmode = flags[1];

  for (int i = tid; i < 16 * 512; i += 256) {
    int gc = i >> 9, k = i & 511;
    wh1[gc * DW1S + k] = W1[(size_t)(768 + k) * 2048 + (gc >> 2) * 512 + (w * 4 + (gc & 3))];
  }
  for (int i = tid; i < 16 * 512; i += 256) {
    int gc = i >> 9, pu = i & 511;
    const float* src = &W2[(size_t)(768 + 2 * pu) * 2048 + (gc >> 2) * 512 + (w * 4 + (gc & 3))];
    unsigned int lo = f2b(src[0]);
    unsigned int hi = f2b(src[2048]);
    wh2u[gc * DW2S + pu] = lo | (hi << 16);
  }
  if (tid < 64) { cst1[tid] = 0; hst1[tid] = 0; cst2[tid] = 0; hst2[tid] = 0; }
  __syncthreads();

  const int og = tid >> 4, s = tid & 15;
  const int bq = og >> 2, jj = og & 3;
  const int b0 = bq * 4;
  const int b_ = tid >> 4, j_ = (tid >> 2) & 3, g_ = tid & 3;
  const int bqr = tid >> 6, ar = (tid >> 4) & 3, jjr = (tid >> 2) & 3, gr = tid & 3;

  for (int tau = 0; tau <= 512; ++tau) {
    float dxv1 = 0.0f, dxv2 = 0.0f;
    if (tau < 512)
      dxv1 = b2f(D1x[((size_t)tau * 128 + w) * 256 + b_ * 16 + g_ * 4 + j_]);
    if (tau >= 1)
      dxv2 = b2f(D2x[((size_t)(tau - 1) * 128 + w) * 256 + b_ * 16 + g_ * 4 + j_]);

    if (tau >= 1 && tid < 8) {
      const unsigned int* a = cnt1 + (size_t)(tau - 1) * 128 + tid * 16;
      unsigned int gcount = 0;
      while (ldcnt(a) < 16u) {
        __builtin_amdgcn_s_sleep(2);
        if (++gcount > (1u << 16)) break;
      }
    }
    __syncthreads();

    if (tau >= 1) {
      // coalesced stage: 16 consecutive lanes read 256B contiguous per buffer-chunk
      int b = tid >> 4, q = tid & 15;
      const unsigned short* p0 = h1cB + (((size_t)(tau - 1) * 16 + b) << 9) + q * 8;
      const unsigned short* p1 = h1nB + (((size_t)(tau - 1) * 16 + b) << 9) + q * 8;
      uivec4 r[12];
      ldg4f_nw(p0, r[0], r[1], r[2], r[3]);
      ldg4f_nw(p1, r[4], r[5], r[6], r[7]);
      if (tau >= 2) {
        const unsigned short* p2 = h2cB + (((size_t)(tau - 2) * 16 + b) << 9) + q * 8;
        ldg4f_nw(p2, r[8], r[9], r[10], r[11]);
      } else {
        uivec4 z; z.x = z.y = z.z = z.w = 0u;
        r[8] = z; r[9] = z; r[10] = z; r[11] = z;
      }
      vm0();
      unsigned int base = b * DHSU + q * 4;
#pragma unroll
      for (int m = 0; m < 4; ++m) *(uivec4*)&hsu[base + 64 * m] = r[m];
#pragma unroll
      for (int m = 0; m < 4; ++m) *(uivec4*)&hsu[base + 256 + 64 * m] = r[4 + m];
#pragma unroll
      for (int m = 0; m < 4; ++m) *(uivec4*)&hsu[base + 512 + 64 * m] = r[8 + m];
    }
    __syncthreads();

    const bool doDot1 = (tau >= 1 && tau < 512);
    const bool doDot2 = (tau >= 1);
    float acc1[4][4], acc2[4][4];
#pragma unroll
    for (int a = 0; a < 4; ++a)
#pragma unroll
      for (int g = 0; g < 4; ++g) { acc1[a][g] = 0.0f; acc2[a][g] = 0.0f; }

    if (doDot1) {
      for (int i = 0; i < 16; ++i) {
        int p = i * 16 + s;
        unsigned int u0 = hsu[(b0 + 0) * DHSU + p];
        unsigned int u1 = hsu[(b0 + 1) * DHSU + p];
        unsigned int u2 = hsu[(b0 + 2) * DHSU + p];
        unsigned int u3 = hsu[(b0 + 3) * DHSU + p];
        float l0 = bflo(u0), h0 = bfhi(u0), l1 = bflo(u1), h1 = bfhi(u1);
        float l2 = bflo(u2), h2 = bfhi(u2), l3 = bflo(u3), h3 = bfhi(u3);
#pragma unroll
        for (int g = 0; g < 4; ++g) {
          float2 wv = *(const float2*)&wh1[(g * 4 + jj) * DW1S + 2 * p];
          acc1[0][g] += l0 * wv.x + h0 * wv.y;
          acc1[1][g] += l1 * wv.x + h1 * wv.y;
          acc1[2][g] += l2 * wv.x + h2 * wv.y;
          acc1[3][g] += l3 * wv.x + h3 * wv.y;
        }
      }
    }
    if (doDot2) {
      for (int i = 0; i < 32; ++i) {
        int pk = i * 16 + s;
        int p = 256 + pk;
        unsigned int u0 = hsu[(b0 + 0) * DHSU + p];
        unsigned int u1 = hsu[(b0 + 1) * DHSU + p];
        unsigned int u2 = hsu[(b0 + 2) * DHSU + p];
        unsigned int u3 = hsu[(b0 + 3) * DHSU + p];
        float l0 = bflo(u0), h0 = bfhi(u0), l1 = bflo(u1), h1 = bfhi(u1);
        float l2 = bflo(u2), h2 = bfhi(u2), l3 = bflo(u3), h3 = bfhi(u3);
#pragma unroll
        for (int g = 0; g < 4; ++g) {
          unsigned int wu = wh2u[(g * 4 + jj) * DW2S + pk];
          float wl = bflo(wu), whi = bfhi(wu);
          acc2[0][g] += l0 * wl + h0 * whi;
          acc2[1][g] += l1 * wl + h1 * whi;
          acc2[2][g] += l2 * wl + h2 * whi;
          acc2[3][g] += l3 * wl + h3 * whi;
        }
      }
    }
#pragma unroll
    for (int a = 0; a < 4; ++a)
#pragma unroll
      for (int g = 0; g < 4; ++g) {
        part2[(a * 4 + g) * 258 + tid] = acc1[a][g];
        part2[(16 + a * 4 + g) * 258 + tid] = acc2[a][g];
      }
    __syncthreads();
    {
      int base = (ar * 4 + gr) * 258 + (bqr * 4 + jjr) * 16;
      float s1 = dxv1, s2 = dxv2;
      if (doDot1) {
#pragma unroll
        for (int ss = 0; ss < 16; ++ss) s1 += part2[base + ss];
      }
      if (doDot2) {
#pragma unroll
        for (int ss = 0; ss < 16; ++ss) s2 += part2[16 * 258 + base + ss];
      }
      gl1[tid] = s1;
      gl2[tid] = s2;
    }
    __syncthreads();

    if (tid < 64) {
      if (tau < 512) {
        int b = tid >> 2, j = tid & 3, colg = w * 4 + j;
        float4 G = ((const float4*)gl1)[tid];
        float cold = (tau == 0) ? 0.0f : cst1[tid];
        float hold = (tau == 0) ? 0.0f : hst1[tid];
        float nc = sigm(G.z + 1.0f) * cold + sigm(G.x) * tanhf(G.y);
        float nh = sigm(G.w) * tanhf(nc);
        size_t mi = ((size_t)b * 512 + tau) * 512 + colg;
        bool mh = mask_at(zh1, mi, mmode);
        bool mc = mask_at(zc1, mi, mmode);
        cst1[tid] = mc ? cold : nc;
        float hkeep = mh ? hold : nh;
        hst1[tid] = hkeep;
        h1n[(size_t)(tau * 16 + b) * 512 + colg] = nh;
        stg_bf16(&h1cB[(((size_t)tau * 16 + b) << 9) + colg], hkeep);
        stg_bf16(&h1nB[(((size_t)tau * 16 + b) << 9) + colg], nh);
      }
    } else if (tid < 128) {
      if (tau >= 1) {
        int u = tid - 64;
        int t2 = tau - 1;
        int b = u >> 2, j = u & 3, colg = w * 4 + j;
        float4 G = ((const float4*)gl2)[u];
        float cold = (tau == 1) ? 0.0f : cst2[u];
        float hold = (tau == 1) ? 0.0f : hst2[u];
        float nc = sigm(G.z + 1.0f) * cold + sigm(G.x) * tanhf(G.y);
        float nh = sigm(G.w) * tanhf(nc);
        size_t mi = ((size_t)b * 512 + t2) * 512 + colg;
        bool mh = mask_at(zh2, mi, mmode);
        bool mc = mask_at(zc2, mi, mmode);
        cst2[u] = mc ? cold : nc;
        float hkeep = mh ? hold : nh;
        hst2[u] = hkeep;
        h2n[(size_t)(t2 * 16 + b) * 512 + colg] = nh;
        stg_bf16(&h2cB[(((size_t)t2 * 16 + b) << 9) + colg], hkeep);
      }
    }
    vm0();
    __syncthreads();
    if (tid == 0)
      __hip_atomic_fetch_add(cnt1 + (size_t)tau * 128 + (w >> 4) * 16, 1u,
                             __ATOMIC_RELAXED, __HIP_MEMORY_SCOPE_AGENT);
  }
}

// ---------------- projection ----------------
__global__ __launch_bounds__(320) void k_proj(const float* __restrict__ cond,
                                              const float* __restrict__ h1n,
                                              const float* __restrict__ h2n,
                                              const float* __restrict__ pw,
                                              const float* __restrict__ pb,
                                              float* __restrict__ mel) {
  __shared__ float as_[4 * 1536];
  int r0 = blockIdx.x * 4;
  for (int i = threadIdx.x; i < 4 * 1536; i += 320) {
    int row = i / 1536, k = i % 1536;
    int r = r0 + row;
    int b = r >> 9, t = r & 511;
    float v;
    if (k < 512) v = cond[(size_t)r * 512 + k];
    else if (k < 1024) v = h1n[(size_t)(t * 16 + b) * 512 + (k - 512)];
    else v = h2n[(size_t)(t * 16 + b) * 512 + (k - 1024)];
    as_[i] = v;
  }
  __syncthreads();
  int row = threadIdx.x / 80, co = threadIdx.x % 80;
  float acc = pb[co];
  for (int k = 0; k < 1536; ++k) acc += as_[row * 1536 + k] * pw[(size_t)k * 80 + co];
  mel[(size_t)(r0 + row) * 80 + co] = acc;
}

// ---------------- k=5 conv ----------------
__global__ __launch_bounds__(256) void k_conv5(const float* __restrict__ X, int Cin,
                                               float* __restrict__ Y, int Cout,
                                               const float* __restrict__ Wc,
                                               const float* __restrict__ bias) {
  extern __shared__ float ys[];
  int blk = blockIdx.x;
  int b = blk >> 6, t0 = (blk & 63) * 8;
  for (int i = threadIdx.x; i < 12 * Cin; i += 256) {
    int rr = i / Cin, ci = i % Cin;
    int tt = t0 - 2 + rr;
    ys[i] = (tt >= 0 && tt < 512) ? X[(size_t)(b * 512 + tt) * Cin + ci] : 0.0f;
  }
  __syncthreads();
  for (int co = threadIdx.x; co < Cout; co += 256) {
    float acc[8];
    float bv = bias ? bias[co] : 0.0f;
#pragma unroll
    for (int j = 0; j < 8; ++j) acc[j] = bv;
    for (int dt = 0; dt < 5; ++dt)
      for (int ci = 0; ci < Cin; ++ci) {
        float wv = Wc[(size_t)(dt * Cin + ci) * Cout + co];
#pragma unroll
        for (int j = 0; j < 8; ++j) acc[j] += ys[(j + dt) * Cin + ci] * wv;
      }
#pragma unroll
    for (int j = 0; j < 8; ++j) Y[(size_t)(b * 512 + t0 + j) * Cout + co] = acc[j];
  }
}

__global__ void k_out(const float* __restrict__ mel, const float* __restrict__ res,
                      void* __restrict__ out, const int* __restrict__ flags) {
  int i = blockIdx.x * 256 + threadIdx.x;
  float m = mel[i];
  float f = m + res[i];
  if (flags[0]) {
    ((float*)out)[i] = m;
    ((float*)out)[655360 + i] = f;
  } else {
    unsigned short* o = (unsigned short*)out;
    o[i] = f2b(m);
    o[655360 + i] = f2b(f);
  }
}

// ---------------- host launch ----------------
extern "C" void kernel_launch(void* const* d_in, const int* in_sizes, int n_in,
                              void* d_out, int out_size, void* d_ws, size_t ws_size,
                              hipStream_t stream) {
  char* ws = (char*)d_ws;
  size_t o = 0;
  auto A_ = [&](size_t nb) { size_t r = o; o += (nb + 255) & ~(size_t)255; return r; };
  const size_t FLAGS = A_(256);
  const size_t SYNC = A_(786432);
  const size_t STATS = A_(4096);
  const size_t PARTS = A_(1048576 + 4096);
  const size_t C_MELS = A_(655360ull * 4), C_DUR = A_(4096 * 4), C_EMB = A_(65536 * 4),
               C_ECW = A_(589824ull * 4), C_EBS = A_(768 * 4), C_EBO = A_(768 * 4),
               C_LFW = A_(524288ull * 4), C_LFB = A_(1024 * 4), C_LBW = A_(524288ull * 4),
               C_LBB = A_(1024 * 4), C_PW1 = A_(20480 * 4), C_P1S = A_(256 * 4),
               C_P1O = A_(256 * 4), C_PW2 = A_(65536 * 4), C_P2S = A_(256 * 4),
               C_P2O = A_(256 * 4), C_DW1 = A_(2621440ull * 4), C_DB1 = A_(2048 * 4),
               C_DW2 = A_(3670016ull * 4), C_DB2 = A_(2048 * 4), C_PRW = A_(122880ull * 4),
               C_PRB = A_(512), C_W0 = A_(204800ull * 4), C_WM = A_(3932160ull * 4),
               C_W4 = A_(204800ull * 4), C_B4 = A_(512), C_PBS = A_(2048 * 4),
               C_PBO = A_(2048 * 4);
  const size_t R1 = A_(16777216), R2 = A_(16777216), R3 = A_(16777216), R4 = A_(16777216),
               MID = A_(4096 * 4), R5 = A_(16777216), R6 = A_(16777216), R7 = A_(25165824),
               D1X = A_(33554432), D2X = A_(33554432), MELP = A_(2621440);
  const size_t XA = R1, XB = R1 + 4194304;
  const size_t GF = R2;
  const size_t GB = R3, H1N = R3;
  const size_t ENC = R4, H2N = R4;
  const size_t COND = R5, PA = R5;
  const size_t PREA = R6, PREB = R6 + 8388608, PB = R6;
  const size_t DECIN = R7, RESID = R7;
  const size_t H1CB = R1, H1NB = R1 + 8388608;
  const size_t H2CB = R2;
  const size_t ENCB = R7;

  auto F = [&](size_t off) { return (float*)(ws + off); };
  auto U = [&](size_t off) { return (unsigned short*)(ws + off); };
  int* flags = (int*)(ws + FLAGS);
  unsigned int* cntE = (unsigned int*)(ws + SYNC);
  unsigned int* cnt1 = (unsigned int*)(ws + SYNC + 262144);

  hipMemsetAsync(ws + SYNC, 0, 786432, stream);
  k_detect<<<1, 256, 0, stream>>>(d_in[8], d_in[4], flags);

  struct CV { int idx; size_t off; int n; };
  const CV cvs[] = {
      {2, C_MELS, 655360}, {3, C_DUR, 4096}, {8, C_EMB, 65536}, {9, C_ECW, 589824},
      {10, C_EBS, 768}, {11, C_EBO, 768}, {12, C_LFW, 524288}, {13, C_LFB, 1024},
      {14, C_LBW, 524288}, {15, C_LBB, 1024}, {16, C_PW1, 20480}, {17, C_P1S, 256},
      {18, C_P1O, 256}, {19, C_PW2, 65536}, {20, C_P2S, 256}, {21, C_P2O, 256},
      {22, C_DW1, 2621440}, {23, C_DB1, 2048}, {24, C_DW2, 3670016}, {25, C_DB2, 2048},
      {26, C_PRW, 122880}, {27, C_PRB, 80}, {28, C_W0, 204800}, {29, C_WM, 3932160},
      {30, C_W4, 204800}, {31, C_B4, 80}, {32, C_PBS, 2048}, {33, C_PBO, 2048}};
  for (int i = 0; i < (int)(sizeof(cvs) / sizeof(cvs[0])); ++i)
    k_cvt<<<(cvs[i].n + 255) / 256, 256, 0, stream>>>(d_in[cvs[i].idx], F(cvs[i].off), cvs[i].n, flags);

  k_embed<<<4096, 256, 0, stream>>>((const int*)d_in[0], F(C_EMB), F(XA));
  for (int i = 0; i < 3; ++i) {
    k_conv3<<<1024, 256, 0, stream>>>(F(XA), F(C_ECW) + (size_t)i * 196608, F(XB));
    k_cs1<<<256, 256, 0, stream>>>(F(XB), 16, 256, F(PARTS));
    k_cs2<<<256, 256, 0, stream>>>(F(PARTS), 256, 4096, F(STATS));
    k_bnact<0><<<4096, 256, 0, stream>>>(F(XB), F(XA), F(STATS), F(C_EBS) + i * 256, F(C_EBO) + i * 256, 255, 1048576);
  }
  k_gemm<3><<<dim3(256, 4), 256, 0, stream>>>(F(XA), F(C_LFW), F(C_LFB), (void*)(ws + GF), 4096, 256, 1024);
  k_gemm<3><<<dim3(256, 4), 256, 0, stream>>>(F(XA), F(C_LBW), F(C_LBB), (void*)(ws + GB), 4096, 256, 1024);
  k_cumsum<<<1, 64, 0, stream>>>(F(C_DUR), F(MID));
  k_enc_lstm<<<128, 256, 0, stream>>>(F(GF), F(GB), F(C_LFW), F(C_LBW), F(ENC), U(ENCB),
                                      (const int*)d_in[1], cntE);
  k_upsample<<<512, 256, 0, stream>>>(F(MID), F(ENC), F(COND));

  k_gemm<0><<<dim3(512, 1), 256, 0, stream>>>(F(C_MELS), F(C_PW1), nullptr, (void*)(ws + PREA), 8192, 80, 256);
  k_cs1<<<256, 256, 0, stream>>>(F(PREA), 32, 256, F(PARTS));
  k_cs2<<<256, 256, 0, stream>>>(F(PARTS), 256, 8192, F(STATS));
  k_bnact<0><<<8192, 256, 0, stream>>>(F(PREA), F(PREB), F(STATS), F(C_P1S), F(C_P1O), 255, 2097152);
  k_gemm<0><<<dim3(512, 1), 256, 0, stream>>>(F(PREB), F(C_PW2), nullptr, (void*)(ws + PREA), 8192, 256, 256);
  k_cs1<<<256, 256, 0, stream>>>(F(PREA), 32, 256, F(PARTS));
  k_cs2<<<256, 256, 0, stream>>>(F(PARTS), 256, 8192, F(STATS));
  k_bnact<0><<<8192, 256, 0, stream>>>(F(PREA), F(PREB), F(STATS), F(C_P2S), F(C_P2O), 255, 2097152);

  k_concat<<<24576, 256, 0, stream>>>(F(COND), F(PREB), F(DECIN));
  k_gemm<2><<<dim3(512, 8), 256, 0, stream>>>(F(DECIN), F(C_DW1), F(C_DB1), (void*)(ws + D1X), 8192, 768, 2048);
  k_gemm<2><<<dim3(512, 8), 256, 0, stream>>>(F(DECIN), F(C_DW2), F(C_DB2), (void*)(ws + D2X), 8192, 768, 2048);
  k_dec_lstm<<<128, 256, 0, stream>>>((const unsigned short*)(ws + D1X), (const unsigned short*)(ws + D2X),
                                      F(C_DW1), F(C_DW2), d_in[4], d_in[5], d_in[6], d_in[7],
                                      U(H1CB), U(H1NB), U(H2CB),
                                      F(H1N), F(H2N), cnt1, flags);
  k_proj<<<2048, 320, 0, stream>>>(F(COND), F(H1N), F(H2N), F(C_PRW), F(C_PRB), F(MELP));

  k_conv5<<<1024, 256, 12 * 80 * 4, stream>>>(F(MELP), 80, F(PA), 512, F(C_W0), nullptr);
  k_cs1<<<256, 256, 0, stream>>>(F(PA), 32, 512, F(PARTS));
  k_cs2<<<512, 256, 0, stream>>>(F(PARTS), 512, 8192, F(STATS));
  k_bnact<1><<<16384, 256, 0, stream>>>(F(PA), F(PB), F(STATS), F(C_PBS), F(C_PBO), 511, 4194304);
  for (int i = 0; i < 3; ++i) {
    k_conv5<<<1024, 256, 12 * 512 * 4, stream>>>(F(PB), 512, F(PA), 512, F(C_WM) + (size_t)i * 1310720, nullptr);
    k_cs1<<<256, 256, 0, stream>>>(F(PA), 32, 512, F(PARTS));
    k_cs2<<<512, 256, 0, stream>>>(F(PARTS), 512, 8192, F(STATS));
    k_bnact<1><<<16384, 256, 0, stream>>>(F(PA), F(PB), F(STATS), F(C_PBS) + (i + 1) * 512, F(C_PBO) + (i + 1) * 512, 511, 4194304);
  }
  k_conv5<<<1024, 256, 12 * 512 * 4, stream>>>(F(PB), 512, F(RESID), 80, F(C_W4), F(C_B4));
  k_out<<<2560, 256, 0, stream>>>(F(MELP), F(RESID), d_out, flags);
}

// Round 8
// 9628.536 us; speedup vs baseline: 1.7608x; 1.6897x over previous
//
#include <hip/hip_runtime.h>

#define EPSV 1e-5f

typedef unsigned int uivec4 __attribute__((ext_vector_type(4)));
typedef short bh8 __attribute__((ext_vector_type(8)));
typedef float f32x4 __attribute__((ext_vector_type(4)));

__device__ __forceinline__ float b2f(unsigned short u) {
  unsigned int x = ((unsigned int)u) << 16;
  return __uint_as_float(x);
}
__device__ __forceinline__ unsigned short f2b(float f) {
  unsigned int x = __float_as_uint(f);
  unsigned int r = (x + 0x7FFFu + ((x >> 16) & 1u)) >> 16;
  return (unsigned short)r;
}
__device__ __forceinline__ float sigm(float x) { return 1.0f / (1.0f + expf(-x)); }
__device__ __forceinline__ float bflo(unsigned int u) { return __uint_as_float(u << 16); }
__device__ __forceinline__ float bfhi(unsigned int u) { return __uint_as_float(u & 0xFFFF0000u); }

// ---- coherence-point (device-coherent) access: bypass L1+L2 both ways ----
__device__ __forceinline__ void stg_bf16(unsigned short* p, float v) {
  unsigned short h = f2b(v);
  asm volatile("global_store_short %0, %1, off sc0 sc1" ::"v"(p), "v"(h) : "memory");
}
__device__ __forceinline__ void ldg2_sc(const unsigned short* p0, const unsigned short* p1,
                                        uivec4& a, uivec4& b) {
  asm volatile(
      "global_load_dwordx4 %0, %2, off sc0 sc1\n\t"
      "global_load_dwordx4 %1, %3, off sc0 sc1\n\t"
      "s_waitcnt vmcnt(0)"
      : "=&v"(a), "=&v"(b)
      : "v"(p0), "v"(p1)
      : "memory");
}
__device__ __forceinline__ void ldg4f_nw(const unsigned short* p, uivec4& a, uivec4& b,
                                         uivec4& c, uivec4& d) {
  asm volatile(
      "global_load_dwordx4 %0, %4, off sc0 sc1\n\t"
      "global_load_dwordx4 %1, %4, off offset:256 sc0 sc1\n\t"
      "global_load_dwordx4 %2, %4, off offset:512 sc0 sc1\n\t"
      "global_load_dwordx4 %3, %4, off offset:768 sc0 sc1"
      : "=&v"(a), "=&v"(b), "=&v"(c), "=&v"(d)
      : "v"(p)
      : "memory");
}
__device__ __forceinline__ void vm0() { asm volatile("s_waitcnt vmcnt(0)" ::: "memory"); }

__device__ __forceinline__ void bf8_to_lds(float* dst, uivec4 u) {
  float2 p;
  p.x = __uint_as_float(u.x << 16); p.y = __uint_as_float(u.x & 0xFFFF0000u);
  *(float2*)(dst + 0) = p;
  p.x = __uint_as_float(u.y << 16); p.y = __uint_as_float(u.y & 0xFFFF0000u);
  *(float2*)(dst + 2) = p;
  p.x = __uint_as_float(u.z << 16); p.y = __uint_as_float(u.z & 0xFFFF0000u);
  *(float2*)(dst + 4) = p;
  p.x = __uint_as_float(u.w << 16); p.y = __uint_as_float(u.w & 0xFFFF0000u);
  *(float2*)(dst + 6) = p;
}
__device__ __forceinline__ unsigned int ldcnt(const unsigned int* p) {
  return __hip_atomic_load(p, __ATOMIC_RELAXED, __HIP_MEMORY_SCOPE_AGENT);
}

// ---------------- dtype detection ----------------
__global__ void k_detect(const void* __restrict__ embp, const void* __restrict__ zmp,
                         int* __restrict__ flags) {
  __shared__ int sh[4];
  int tid = threadIdx.x;
  if (tid < 4) sh[tid] = 0;
  __syncthreads();
  const unsigned short* u = (const unsigned short*)embp;
  int bad = 0;
  for (int i = tid; i < 4096; i += 256) {
    float f = fabsf(b2f(u[i]));
    if (!(f < 1e10f)) bad = 1;
  }
  if (bad) atomicAdd(&sh[3], 1);
  const unsigned char* p = (const unsigned char*)zmp;
  int codd = 0, c0 = 0, c1v = 0;
  for (int i = tid; i < 65536; i += 256) {
    unsigned char v = p[i];
    if (v) {
      if (i & 1) codd++;
      if ((i & 3) == 0) c0++;
      if (v == 1) c1v++;
    }
  }
  atomicAdd(&sh[0], codd); atomicAdd(&sh[1], c0); atomicAdd(&sh[2], c1v);
  __syncthreads();
  if (tid == 0) {
    flags[0] = sh[3] ? 1 : 0;
    int mode;
    if (sh[0] == 0) mode = 1;
    else if (sh[2] > 0) mode = 0;
    else if (sh[1] == 0) mode = 2;
    else mode = 3;
    flags[1] = mode;
  }
}

__global__ void k_cvt(const void* __restrict__ src, float* __restrict__ dst, int n,
                      const int* __restrict__ flags) {
  int i = blockIdx.x * 256 + threadIdx.x;
  if (i >= n) return;
  if (flags[0]) dst[i] = ((const float*)src)[i];
  else dst[i] = b2f(((const unsigned short*)src)[i]);
}

__global__ void k_cvtb(const float* __restrict__ src, unsigned short* __restrict__ dst, int n) {
  int i = blockIdx.x * 256 + threadIdx.x;
  if (i >= n) return;
  dst[i] = f2b(src[i]);
}

__device__ __forceinline__ bool mask_at(const void* p, size_t i, int mode) {
  switch (mode) {
    case 0: return ((const unsigned char*)p)[i] != 0;
    case 1: return ((const int*)p)[i] != 0;
    case 2: return ((const float*)p)[i] != 0.0f;
    default: return ((const unsigned short*)p)[i] != 0;
  }
}

// ---------------- embedding ----------------
__global__ void k_embed(const int* __restrict__ ph, const float* __restrict__ emb,
                        float* __restrict__ X) {
  int bl = blockIdx.x;
  int p = ph[bl];
  X[(size_t)bl * 256 + threadIdx.x] = emb[(size_t)p * 256 + threadIdx.x];
}

// ---------------- k=3 conv, E=256 -> E=256, SAME ----------------
__global__ __launch_bounds__(256) void k_conv3(const float* __restrict__ X,
                                               const float* __restrict__ Wc,
                                               float* __restrict__ Y) {
  __shared__ float xs[6 * 256];
  int blk = blockIdx.x;
  int b = blk >> 6, l0 = (blk & 63) * 4;
  for (int i = threadIdx.x; i < 6 * 256; i += 256) {
    int dl = i >> 8, ci = i & 255;
    int ll = l0 - 1 + dl;
    xs[i] = (ll >= 0 && ll < 256) ? X[(size_t)(b * 256 + ll) * 256 + ci] : 0.0f;
  }
  __syncthreads();
  int co = threadIdx.x;
  float acc[4] = {0.f, 0.f, 0.f, 0.f};
  for (int i = 0; i < 768; ++i) {
    int d = i >> 8, ci = i & 255;
    float wv = Wc[(size_t)i * 256 + co];
#pragma unroll
    for (int j = 0; j < 4; ++j) acc[j] += xs[(d + j) * 256 + ci] * wv;
  }
#pragma unroll
  for (int j = 0; j < 4; ++j) Y[(size_t)(b * 256 + l0 + j) * 256 + co] = acc[j];
}

// ---------------- per-channel mean/var: 2-stage coalesced, deterministic ----------------
__global__ __launch_bounds__(256) void k_cs1(const float* __restrict__ X, int RB, int C,
                                             float* __restrict__ part) {
  int blk = blockIdx.x;
  int r0 = blk * RB;
  float s0 = 0.f, q0 = 0.f, s1 = 0.f, q1 = 0.f;
  for (int rr = 0; rr < RB; ++rr) {
    const float* row = X + (size_t)(r0 + rr) * C;
    float v = row[threadIdx.x];
    s0 += v; q0 += v * v;
    if (C > 256) {
      float v1 = row[256 + threadIdx.x];
      s1 += v1; q1 += v1 * v1;
    }
  }
  float* pr = part + (size_t)blk * 2 * C;
  pr[threadIdx.x] = s0;
  pr[C + threadIdx.x] = q0;
  if (C > 256) {
    pr[256 + threadIdx.x] = s1;
    pr[C + 256 + threadIdx.x] = q1;
  }
}
__global__ __launch_bounds__(256) void k_cs2(const float* __restrict__ part, int C, int R,
                                             float* __restrict__ st) {
  int c = blockIdx.x;
  int t = threadIdx.x;
  __shared__ float rs_[256], rq_[256];
  rs_[t] = part[(size_t)t * 2 * C + c];
  rq_[t] = part[(size_t)t * 2 * C + C + c];
  __syncthreads();
  for (int k = 128; k > 0; k >>= 1) {
    if (t < k) { rs_[t] += rs_[t + k]; rq_[t] += rq_[t + k]; }
    __syncthreads();
  }
  if (t == 0) {
    float m = rs_[0] / R;
    st[c] = m;
    st[C + c] = rq_[0] / R - m * m;
  }
}

template <int ACT>
__global__ void k_bnact(const float* __restrict__ X, float* __restrict__ Y,
                        const float* __restrict__ st, const float* __restrict__ sc,
                        const float* __restrict__ of, int Cmask, int n) {
  int i = blockIdx.x * 256 + threadIdx.x;
  if (i >= n) return;
  int C = Cmask + 1;
  int c = i & Cmask;
  float m = st[c], v = st[C + c];
  float y = (X[i] - m) * rsqrtf(v + EPSV) * sc[c] + of[c];
  Y[i] = ACT ? tanhf(y) : fmaxf(y, 0.0f);
}

// ---------------- generic VALU GEMM (prenet only now) ----------------
template <int OBF>
__global__ __launch_bounds__(256) void k_gemm(const float* __restrict__ Ap,
                                              const float* __restrict__ Bp,
                                              const float* __restrict__ bias,
                                              void* __restrict__ Cp, int M, int K, int N) {
  __shared__ float al[16 * 768];
  int row0 = blockIdx.x * 16;
  int c = blockIdx.y * 256 + threadIdx.x;
  for (int i = threadIdx.x; i < 16 * K; i += 256) al[i] = Ap[(size_t)row0 * K + i];
  __syncthreads();
  float acc[16];
  float bv = bias ? bias[c] : 0.0f;
#pragma unroll
  for (int j = 0; j < 16; ++j) acc[j] = bv;
  for (int k = 0; k < K; ++k) {
    float b = Bp[(size_t)k * N + c];
#pragma unroll
    for (int j = 0; j < 16; ++j) acc[j] += al[j * K + k] * b;
  }
  if (OBF == 0) {
    float* C = (float*)Cp;
#pragma unroll
    for (int j = 0; j < 16; ++j) C[(size_t)(row0 + j) * N + c] = acc[j];
  }
}

// ---------------- tiled transpose f32[K][ldn] -> bf16[N][K] ----------------
__global__ __launch_bounds__(256) void k_trb(const float* __restrict__ src, int ldn,
                                             unsigned short* __restrict__ dst, int K, int N) {
  __shared__ float tl[64][65];
  int k0 = blockIdx.x * 64, n0 = blockIdx.y * 64;
  int tid = threadIdx.x;
#pragma unroll
  for (int p = 0; p < 16; ++p) {
    int idx = p * 256 + tid;
    int r = idx >> 6, c = idx & 63;
    tl[r][c] = src[(size_t)(k0 + r) * ldn + n0 + c];
  }
  __syncthreads();
#pragma unroll
  for (int p = 0; p < 16; ++p) {
    int idx = p * 256 + tid;
    int rr = idx >> 6, cc = idx & 63;
    dst[(size_t)(n0 + rr) * K + k0 + cc] = f2b(tl[cc][rr]);
  }
}

// ---------------- im2col (k=5 SAME over t within each batch) f32 -> bf16 ----------------
__global__ __launch_bounds__(256) void k_i2c(const float* __restrict__ X,
                                             unsigned short* __restrict__ out) {
  int r = blockIdx.x;
  int b = r >> 9, t = r & 511;
#pragma unroll
  for (int p = 0; p < 10; ++p) {
    int col = p * 256 + threadIdx.x;
    int dt = col >> 9, ci = col & 511;
    int tt = t + dt - 2;
    float v = (tt >= 0 && tt < 512) ? X[((size_t)(b * 512 + tt)) * 512 + ci] : 0.0f;
    out[(size_t)r * 2560 + col] = f2b(v);
  }
}

// ---------------- MFMA GEMM: C[M,N] = A[M,K]bf16 @ Bt[N,K]bf16^T (+bias) ----------------
// OBF: 0 = f32 row-major, 2 = bf16 decoder-gate layout, 3 = f32 encoder-gate layout
template <int OBF>
__global__ __launch_bounds__(256) void k_mf(const unsigned short* __restrict__ A,
                                            const unsigned short* __restrict__ Bt,
                                            const float* __restrict__ bias,
                                            void* __restrict__ Cp, int M, int N, int K) {
  const int lane = threadIdx.x & 63, wv = threadIdx.x >> 6;
  const int m0 = blockIdx.x * 64 + wv * 16;
  const int n0 = blockIdx.y * 64;
  const int koff = (lane >> 4) << 3;
  const unsigned short* arow = A + (size_t)(m0 + (lane & 15)) * K + koff;
  const unsigned short* brow0 = Bt + (size_t)(n0 + 0 * 16 + (lane & 15)) * K + koff;
  const unsigned short* brow1 = Bt + (size_t)(n0 + 1 * 16 + (lane & 15)) * K + koff;
  const unsigned short* brow2 = Bt + (size_t)(n0 + 2 * 16 + (lane & 15)) * K + koff;
  const unsigned short* brow3 = Bt + (size_t)(n0 + 3 * 16 + (lane & 15)) * K + koff;
  f32x4 acc0 = {0.f, 0.f, 0.f, 0.f}, acc1 = {0.f, 0.f, 0.f, 0.f};
  f32x4 acc2 = {0.f, 0.f, 0.f, 0.f}, acc3 = {0.f, 0.f, 0.f, 0.f};
  for (int k = 0; k < K; k += 32) {
    bh8 a = *(const bh8*)(arow + k);
    bh8 b0 = *(const bh8*)(brow0 + k);
    bh8 b1 = *(const bh8*)(brow1 + k);
    bh8 b2 = *(const bh8*)(brow2 + k);
    bh8 b3 = *(const bh8*)(brow3 + k);
    acc0 = __builtin_amdgcn_mfma_f32_16x16x32_bf16(a, b0, acc0, 0, 0, 0);
    acc1 = __builtin_amdgcn_mfma_f32_16x16x32_bf16(a, b1, acc1, 0, 0, 0);
    acc2 = __builtin_amdgcn_mfma_f32_16x16x32_bf16(a, b2, acc2, 0, 0, 0);
    acc3 = __builtin_amdgcn_mfma_f32_16x16x32_bf16(a, b3, acc3, 0, 0, 0);
  }
  const int r0 = m0 + ((lane >> 4) << 2);
  const int nl = lane & 15;
  float av[4][4];
#pragma unroll
  for (int r = 0; r < 4; ++r) { av[0][r] = acc0[r]; av[1][r] = acc1[r]; av[2][r] = acc2[r]; av[3][r] = acc3[r]; }
#pragma unroll
  for (int t = 0; t < 4; ++t) {
    int n = n0 + t * 16 + nl;
    float bv = bias ? bias[n] : 0.0f;
#pragma unroll
    for (int r = 0; r < 4; ++r) {
      float v = av[t][r] + bv;
      int row = r0 + r;
      if (OBF == 0) {
        ((float*)Cp)[(size_t)row * N + n] = v;
      } else if (OBF == 2) {
        int b = row >> 9, tt = row & 511;
        int g = n >> 9, w = (n & 511) >> 2, jj = n & 3;
        ((unsigned short*)Cp)[((size_t)tt * 128 + w) * 256 + b * 16 + g * 4 + jj] = f2b(v);
      } else {
        int b = row >> 8, l = row & 255;
        int g = n >> 8, w = (n & 255) >> 2, jj = n & 3;
        ((float*)Cp)[((size_t)l * 64 + w) * 256 + b * 16 + g * 4 + jj] = v;
      }
    }
  }
}

// ---------------- duration cumsum ----------------
__global__ void k_cumsum(const float* __restrict__ dur, float* __restrict__ mid) {
  int b = threadIdx.x;
  if (b >= 16) return;
  float run = 0.f;
  for (int l = 0; l < 256; ++l) {
    float d = dur[b * 256 + l];
    run += d;
    mid[b * 256 + l] = run - 0.5f * d;
  }
}

// ---------------- persistent bi-LSTM encoder ----------------
#define EHS 258
__global__ __launch_bounds__(256) void k_enc_lstm(const float* __restrict__ GFp,
                                                  const float* __restrict__ GBp,
                                                  const float* __restrict__ Wf,
                                                  const float* __restrict__ Wb,
                                                  float* __restrict__ enc,
                                                  unsigned short* __restrict__ encB,
                                                  const int* __restrict__ lengths,
                                                  unsigned int* __restrict__ cnt) {
  const int tid = threadIdx.x;
  const int wg = blockIdx.x;
  const int dir = wg >> 6;
  const int w = wg & 63;
  const float* Gpre = dir ? GBp : GFp;
  const float* W = dir ? Wb : Wf;
  unsigned int* c_self = cnt + (size_t)dir * 256 * 128;

  __shared__ __align__(16) float hs[16 * EHS];
  __shared__ __align__(16) float wh[16 * EHS];
  __shared__ float part2[16 * 258];
  __shared__ float gl[256];
  __shared__ float cst[64];
  __shared__ int rs[16];

  for (int i = tid; i < 16 * 256; i += 256) {
    int gc = i >> 8, k = i & 255;
    wh[gc * EHS + k] = W[(size_t)(256 + k) * 1024 + (gc >> 2) * 256 + (w * 4 + (gc & 3))];
  }
  if (tid < 64) cst[tid] = 0.0f;
  __syncthreads();

  const int og = tid >> 4, s = tid & 15;
  const int bq = og >> 2, jj = og & 3;
  const int b_ = tid >> 4, j_ = (tid >> 2) & 3, g_ = tid & 3;
  const int bqr = tid >> 6, ar = (tid >> 4) & 3, jjr = (tid >> 2) & 3, gr = tid & 3;

  for (int t = 0; t < 256; ++t) {
    const int l = dir ? (255 - t) : t;
    if (tid < 16) rs[tid] = (dir == 1) && (l >= lengths[tid] - 1);
    float gpre = Gpre[((size_t)l * 64 + w) * 256 + b_ * 16 + g_ * 4 + j_];
    if (t > 0 && tid < 8) {
      const unsigned int* a = c_self + (size_t)(t - 1) * 128 + tid * 16;
      unsigned int gcount = 0;
      while (ldcnt(a) < 8u) {
        __builtin_amdgcn_s_sleep(2);
        if (++gcount > (1u << 16)) break;
      }
    }
    __syncthreads();
    if (t > 0) {
      const int lprev = dir ? (l + 1) : (l - 1);
      int b = tid & 15, q = tid >> 4;
      const unsigned short* p = encB + ((size_t)dir << 20) + (((size_t)lprev * 16 + b) << 8) + q * 16;
      uivec4 a0, a1;
      ldg2_sc(p, p + 8, a0, a1);
      if (rs[b]) {
        a0.x = a0.y = a0.z = a0.w = 0u;
        a1.x = a1.y = a1.z = a1.w = 0u;
      }
      float* d = &hs[b * EHS + q * 16];
      bf8_to_lds(d, a0);
      bf8_to_lds(d + 8, a1);
    }
    __syncthreads();

    float acc[4][4];
#pragma unroll
    for (int a = 0; a < 4; ++a) { acc[a][0] = 0; acc[a][1] = 0; acc[a][2] = 0; acc[a][3] = 0; }
    if (t > 0) {
      const int b0 = bq * 4;
#pragma unroll
      for (int i = 0; i < 8; ++i) {
        int kk = i * 32 + 2 * s;
        float2 h0 = *(const float2*)&hs[(b0 + 0) * EHS + kk];
        float2 h1 = *(const float2*)&hs[(b0 + 1) * EHS + kk];
        float2 h2 = *(const float2*)&hs[(b0 + 2) * EHS + kk];
        float2 h3 = *(const float2*)&hs[(b0 + 3) * EHS + kk];
#pragma unroll
        for (int g = 0; g < 4; ++g) {
          float2 wv = *(const float2*)&wh[(g * 4 + jj) * EHS + kk];
          acc[0][g] += h0.x * wv.x + h0.y * wv.y;
          acc[1][g] += h1.x * wv.x + h1.y * wv.y;
          acc[2][g] += h2.x * wv.x + h2.y * wv.y;
          acc[3][g] += h3.x * wv.x + h3.y * wv.y;
        }
      }
    }
#pragma unroll
    for (int a = 0; a < 4; ++a)
#pragma unroll
      for (int g = 0; g < 4; ++g)
        part2[(a * 4 + g) * 258 + tid] = acc[a][g];
    __syncthreads();
    {
      float sum = gpre;
      if (t > 0) {
        int base = (ar * 4 + gr) * 258 + (bqr * 4 + jjr) * 16;
#pragma unroll
        for (int ss = 0; ss < 16; ++ss) sum += part2[base + ss];
      }
      gl[tid] = sum;
    }
    __syncthreads();
    if (tid < 64) {
      int b = tid >> 2, j = tid & 3;
      float4 G = ((const float4*)gl)[tid];
      float c = cst[tid];
      if (t == 0 || rs[b]) c = 0.0f;
      c = sigm(G.z + 1.0f) * c + sigm(G.x) * tanhf(G.y);
      float h = sigm(G.w) * tanhf(c);
      cst[tid] = c;
      enc[(size_t)(b * 256 + l) * 512 + dir * 256 + (w * 4 + j)] = h;
      stg_bf16(&encB[((size_t)dir << 20) + (((size_t)l * 16 + b) << 8) + (w * 4 + j)], h);
    }
    vm0();
    __syncthreads();
    if (tid == 0)
      __hip_atomic_fetch_add(c_self + (size_t)t * 128 + (w >> 3) * 16, 1u,
                             __ATOMIC_RELAXED, __HIP_MEMORY_SCOPE_AGENT);
  }
}

// ---------------- Gaussian-softmax upsampling ----------------
__global__ __launch_bounds__(256) void k_upsample(const float* __restrict__ mid,
                                                  const float* __restrict__ enc,
                                                  float* __restrict__ cond) {
  int blk = blockIdx.x;
  int b = blk >> 5, t0 = (blk & 31) * 16;
  int tid = threadIdx.x;
  __shared__ float wls[16][256];
  __shared__ float red[256];
  float mp = mid[b * 256 + tid];
  for (int tt = 0; tt < 16; ++tt) {
    float tpos = (float)(t0 + tt);
    float d = mp - tpos;
    float d2 = d * d * 0.1f;
    red[tid] = d2; __syncthreads();
    for (int k = 128; k > 0; k >>= 1) { if (tid < k) red[tid] = fminf(red[tid], red[tid + k]); __syncthreads(); }
    float mn = red[0]; __syncthreads();
    float e = expf(mn - d2);
    red[tid] = e; __syncthreads();
    for (int k = 128; k > 0; k >>= 1) { if (tid < k) red[tid] += red[tid + k]; __syncthreads(); }
    float sum = red[0]; __syncthreads();
    wls[tt][tid] = e / sum;
  }
  __syncthreads();
  float a0[16], a1[16];
#pragma unroll
  for (int i = 0; i < 16; ++i) { a0[i] = 0; a1[i] = 0; }
  for (int l = 0; l < 256; ++l) {
    float e0 = enc[(size_t)(b * 256 + l) * 512 + tid];
    float e1 = enc[(size_t)(b * 256 + l) * 512 + 256 + tid];
#pragma unroll
    for (int tt = 0; tt < 16; ++tt) { float wv = wls[tt][l]; a0[tt] += wv * e0; a1[tt] += wv * e1; }
  }
  for (int tt = 0; tt < 16; ++tt) {
    cond[(size_t)(b * 512 + t0 + tt) * 512 + tid] = a0[tt];
    cond[(size_t)(b * 512 + t0 + tt) * 512 + 256 + tid] = a1[tt];
  }
}

// concat -> bf16 decoder input A-matrix [8192][768]
__global__ void k_concat(const float* __restrict__ cond, const float* __restrict__ p,
                         unsigned short* __restrict__ din) {
  size_t i = (size_t)blockIdx.x * 256 + threadIdx.x;
  int r = (int)(i / 768);
  int c = (int)(i % 768);
  float v = (c < 512) ? cond[(size_t)r * 512 + c] : p[(size_t)r * 256 + (c - 512)];
  din[i] = f2b(v);
}

// ---------------- merged 2-layer zoneout LSTM decoder ----------------
#define DHSU 776
#define DW1S 514
#define DW2S 520
__global__ __launch_bounds__(256) void k_dec_lstm(
    const unsigned short* __restrict__ D1x, const unsigned short* __restrict__ D2x,
    const float* __restrict__ W1, const float* __restrict__ W2,
    const void* __restrict__ zh1, const void* __restrict__ zc1,
    const void* __restrict__ zh2, const void* __restrict__ zc2,
    unsigned short* __restrict__ h1cB, unsigned short* __restrict__ h1nB,
    unsigned short* __restrict__ h2cB,
    float* __restrict__ h1n, float* __restrict__ h2n,
    unsigned int* __restrict__ cnt1,
    const int* __restrict__ flags) {
  const int tid = threadIdx.x;
  const int w = blockIdx.x;

  __shared__ __align__(16) unsigned int hsu[16 * DHSU];
  __shared__ __align__(16) float wh1[16 * DW1S];
  __shared__ __align__(16) unsigned int wh2u[16 * DW2S];
  __shared__ float part2[32 * 258];
  __shared__ float gl1[256], gl2[256];
  __shared__ float cst1[64], hst1[64], cst2[64], hst2[64];

  const int mmode = flags[1];

  for (int i = tid; i < 16 * 512; i += 256) {
    int gc = i >> 9, k = i & 511;
    wh1[gc * DW1S + k] = W1[(size_t)(768 + k) * 2048 + (gc >> 2) * 512 + (w * 4 + (gc & 3))];
  }
  for (int i = tid; i < 16 * 512; i += 256) {
    int gc = i >> 9, pu = i & 511;
    const float* src = &W2[(size_t)(768 + 2 * pu) * 2048 + (gc >> 2) * 512 + (w * 4 + (gc & 3))];
    unsigned int lo = f2b(src[0]);
    unsigned int hi = f2b(src[2048]);
    wh2u[gc * DW2S + pu] = lo | (hi << 16);
  }
  if (tid < 64) { cst1[tid] = 0; hst1[tid] = 0; cst2[tid] = 0; hst2[tid] = 0; }
  __syncthreads();

  const int og = tid >> 4, s = tid & 15;
  const int bq = og >> 2, jj = og & 3;
  const int b0 = bq * 4;
  const int b_ = tid >> 4, j_ = (tid >> 2) & 3, g_ = tid & 3;
  const int bqr = tid >> 6, ar = (tid >> 4) & 3, jjr = (tid >> 2) & 3, gr = tid & 3;

  for (int tau = 0; tau <= 512; ++tau) {
    float dxv1 = 0.0f, dxv2 = 0.0f;
    if (tau < 512)
      dxv1 = b2f(D1x[((size_t)tau * 128 + w) * 256 + b_ * 16 + g_ * 4 + j_]);
    if (tau >= 1)
      dxv2 = b2f(D2x[((size_t)(tau - 1) * 128 + w) * 256 + b_ * 16 + g_ * 4 + j_]);

    if (tau >= 1 && tid < 8) {
      const unsigned int* a = cnt1 + (size_t)(tau - 1) * 128 + tid * 16;
      unsigned int gcount = 0;
      while (ldcnt(a) < 16u) {
        __builtin_amdgcn_s_sleep(2);
        if (++gcount > (1u << 16)) break;
      }
    }
    __syncthreads();

    if (tau >= 1) {
      int b = tid >> 4, q = tid & 15;
      const unsigned short* p0 = h1cB + (((size_t)(tau - 1) * 16 + b) << 9) + q * 8;
      const unsigned short* p1 = h1nB + (((size_t)(tau - 1) * 16 + b) << 9) + q * 8;
      uivec4 r[12];
      ldg4f_nw(p0, r[0], r[1], r[2], r[3]);
      ldg4f_nw(p1, r[4], r[5], r[6], r[7]);
      if (tau >= 2) {
        const unsigned short* p2 = h2cB + (((size_t)(tau - 2) * 16 + b) << 9) + q * 8;
        ldg4f_nw(p2, r[8], r[9], r[10], r[11]);
      } else {
        uivec4 z; z.x = z.y = z.z = z.w = 0u;
        r[8] = z; r[9] = z; r[10] = z; r[11] = z;
      }
      vm0();
      unsigned int base = b * DHSU + q * 4;
#pragma unroll
      for (int m = 0; m < 4; ++m) *(uivec4*)&hsu[base + 64 * m] = r[m];
#pragma unroll
      for (int m = 0; m < 4; ++m) *(uivec4*)&hsu[base + 256 + 64 * m] = r[4 + m];
#pragma unroll
      for (int m = 0; m < 4; ++m) *(uivec4*)&hsu[base + 512 + 64 * m] = r[8 + m];
    }
    __syncthreads();

    const bool doDot1 = (tau >= 1 && tau < 512);
    const bool doDot2 = (tau >= 1);
    float acc1[4][4], acc2[4][4];
#pragma unroll
    for (int a = 0; a < 4; ++a)
#pragma unroll
      for (int g = 0; g < 4; ++g) { acc1[a][g] = 0.0f; acc2[a][g] = 0.0f; }

    if (doDot1) {
      for (int i = 0; i < 16; ++i) {
        int p = i * 16 + s;
        unsigned int u0 = hsu[(b0 + 0) * DHSU + p];
        unsigned int u1 = hsu[(b0 + 1) * DHSU + p];
        unsigned int u2 = hsu[(b0 + 2) * DHSU + p];
        unsigned int u3 = hsu[(b0 + 3) * DHSU + p];
        float l0 = bflo(u0), h0 = bfhi(u0), l1 = bflo(u1), h1 = bfhi(u1);
        float l2 = bflo(u2), h2 = bfhi(u2), l3 = bflo(u3), h3 = bfhi(u3);
#pragma unroll
        for (int g = 0; g < 4; ++g) {
          float2 wv = *(const float2*)&wh1[(g * 4 + jj) * DW1S + 2 * p];
          acc1[0][g] += l0 * wv.x + h0 * wv.y;
          acc1[1][g] += l1 * wv.x + h1 * wv.y;
          acc1[2][g] += l2 * wv.x + h2 * wv.y;
          acc1[3][g] += l3 * wv.x + h3 * wv.y;
        }
      }
    }
    if (doDot2) {
      for (int i = 0; i < 32; ++i) {
        int pk = i * 16 + s;
        int p = 256 + pk;
        unsigned int u0 = hsu[(b0 + 0) * DHSU + p];
        unsigned int u1 = hsu[(b0 + 1) * DHSU + p];
        unsigned int u2 = hsu[(b0 + 2) * DHSU + p];
        unsigned int u3 = hsu[(b0 + 3) * DHSU + p];
        float l0 = bflo(u0), h0 = bfhi(u0), l1 = bflo(u1), h1 = bfhi(u1);
        float l2 = bflo(u2), h2 = bfhi(u2), l3 = bflo(u3), h3 = bfhi(u3);
#pragma unroll
        for (int g = 0; g < 4; ++g) {
          unsigned int wu = wh2u[(g * 4 + jj) * DW2S + pk];
          float wl = bflo(wu), whi = bfhi(wu);
          acc2[0][g] += l0 * wl + h0 * whi;
          acc2[1][g] += l1 * wl + h1 * whi;
          acc2[2][g] += l2 * wl + h2 * whi;
          acc2[3][g] += l3 * wl + h3 * whi;
        }
      }
    }
#pragma unroll
    for (int a = 0; a < 4; ++a)
#pragma unroll
      for (int g = 0; g < 4; ++g) {
        part2[(a * 4 + g) * 258 + tid] = acc1[a][g];
        part2[(16 + a * 4 + g) * 258 + tid] = acc2[a][g];
      }
    __syncthreads();
    {
      int base = (ar * 4 + gr) * 258 + (bqr * 4 + jjr) * 16;
      float s1 = dxv1, s2 = dxv2;
      if (doDot1) {
#pragma unroll
        for (int ss = 0; ss < 16; ++ss) s1 += part2[base + ss];
      }
      if (doDot2) {
#pragma unroll
        for (int ss = 0; ss < 16; ++ss) s2 += part2[16 * 258 + base + ss];
      }
      gl1[tid] = s1;
      gl2[tid] = s2;
    }
    __syncthreads();

    if (tid < 64) {
      if (tau < 512) {
        int b = tid >> 2, j = tid & 3, colg = w * 4 + j;
        float4 G = ((const float4*)gl1)[tid];
        float cold = (tau == 0) ? 0.0f : cst1[tid];
        float hold = (tau == 0) ? 0.0f : hst1[tid];
        float nc = sigm(G.z + 1.0f) * cold + sigm(G.x) * tanhf(G.y);
        float nh = sigm(G.w) * tanhf(nc);
        size_t mi = ((size_t)b * 512 + tau) * 512 + colg;
        bool mh = mask_at(zh1, mi, mmode);
        bool mc = mask_at(zc1, mi, mmode);
        cst1[tid] = mc ? cold : nc;
        float hkeep = mh ? hold : nh;
        hst1[tid] = hkeep;
        h1n[(size_t)(tau * 16 + b) * 512 + colg] = nh;
        stg_bf16(&h1cB[(((size_t)tau * 16 + b) << 9) + colg], hkeep);
        stg_bf16(&h1nB[(((size_t)tau * 16 + b) << 9) + colg], nh);
      }
    } else if (tid < 128) {
      if (tau >= 1) {
        int u = tid - 64;
        int t2 = tau - 1;
        int b = u >> 2, j = u & 3, colg = w * 4 + j;
        float4 G = ((const float4*)gl2)[u];
        float cold = (tau == 1) ? 0.0f : cst2[u];
        float hold = (tau == 1) ? 0.0f : hst2[u];
        float nc = sigm(G.z + 1.0f) * cold + sigm(G.x) * tanhf(G.y);
        float nh = sigm(G.w) * tanhf(nc);
        size_t mi = ((size_t)b * 512 + t2) * 512 + colg;
        bool mh = mask_at(zh2, mi, mmode);
        bool mc = mask_at(zc2, mi, mmode);
        cst2[u] = mc ? cold : nc;
        float hkeep = mh ? hold : nh;
        hst2[u] = hkeep;
        h2n[(size_t)(t2 * 16 + b) * 512 + colg] = nh;
        stg_bf16(&h2cB[(((size_t)t2 * 16 + b) << 9) + colg], hkeep);
      }
    }
    vm0();
    __syncthreads();
    if (tid == 0)
      __hip_atomic_fetch_add(cnt1 + (size_t)tau * 128 + (w >> 4) * 16, 1u,
                             __ATOMIC_RELAXED, __HIP_MEMORY_SCOPE_AGENT);
  }
}

// ---------------- projection ----------------
__global__ __launch_bounds__(320) void k_proj(const float* __restrict__ cond,
                                              const float* __restrict__ h1n,
                                              const float* __restrict__ h2n,
                                              const float* __restrict__ pw,
                                              const float* __restrict__ pb,
                                              float* __restrict__ mel) {
  __shared__ float as_[4 * 1536];
  int r0 = blockIdx.x * 4;
  for (int i = threadIdx.x; i < 4 * 1536; i += 320) {
    int row = i / 1536, k = i % 1536;
    int r = r0 + row;
    int b = r >> 9, t = r & 511;
    float v;
    if (k < 512) v = cond[(size_t)r * 512 + k];
    else if (k < 1024) v = h1n[(size_t)(t * 16 + b) * 512 + (k - 512)];
    else v = h2n[(size_t)(t * 16 + b) * 512 + (k - 1024)];
    as_[i] = v;
  }
  __syncthreads();
  int row = threadIdx.x / 80, co = threadIdx.x % 80;
  float acc = pb[co];
  for (int k = 0; k < 1536; ++k) acc += as_[row * 1536 + k] * pw[(size_t)k * 80 + co];
  mel[(size_t)(r0 + row) * 80 + co] = acc;
}

// ---------------- k=5 conv (VALU; first 80->512 and last 512->80 only) ----------------
__global__ __launch_bounds__(256) void k_conv5(const float* __restrict__ X, int Cin,
                                               float* __restrict__ Y, int Cout,
                                               const float* __restrict__ Wc,
                                               const float* __restrict__ bias) {
  extern __shared__ float ys[];
  int blk = blockIdx.x;
  int b = blk >> 6, t0 = (blk & 63) * 8;
  for (int i = threadIdx.x; i < 12 * Cin; i += 256) {
    int rr = i / Cin, ci = i % Cin;
    int tt = t0 - 2 + rr;
    ys[i] = (tt >= 0 && tt < 512) ? X[(size_t)(b * 512 + tt) * Cin + ci] : 0.0f;
  }
  __syncthreads();
  for (int co = threadIdx.x; co < Cout; co += 256) {
    float acc[8];
    float bv = bias ? bias[co] : 0.0f;
#pragma unroll
    for (int j = 0; j < 8; ++j) acc[j] = bv;
    for (int dt = 0; dt < 5; ++dt)
      for (int ci = 0; ci < Cin; ++ci) {
        float wv = Wc[(size_t)(dt * Cin + ci) * Cout + co];
#pragma unroll
        for (int j = 0; j < 8; ++j) acc[j] += ys[(j + dt) * Cin + ci] * wv;
      }
#pragma unroll
    for (int j = 0; j < 8; ++j) Y[(size_t)(b * 512 + t0 + j) * Cout + co] = acc[j];
  }
}

__global__ void k_out(const float* __restrict__ mel, const float* __restrict__ res,
                      void* __restrict__ out, const int* __restrict__ flags) {
  int i = blockIdx.x * 256 + threadIdx.x;
  float m = mel[i];
  float f = m + res[i];
  if (flags[0]) {
    ((float*)out)[i] = m;
    ((float*)out)[655360 + i] = f;
  } else {
    unsigned short* o = (unsigned short*)out;
    o[i] = f2b(m);
    o[655360 + i] = f2b(f);
  }
}

// ---------------- host launch ----------------
extern "C" void kernel_launch(void* const* d_in, const int* in_sizes, int n_in,
                              void* d_out, int out_size, void* d_ws, size_t ws_size,
                              hipStream_t stream) {
  char* ws = (char*)d_ws;
  size_t o = 0;
  auto A_ = [&](size_t nb) { size_t r = o; o += (nb + 255) & ~(size_t)255; return r; };
  const size_t FLAGS = A_(256);
  const size_t SYNC = A_(786432);
  const size_t STATS = A_(4096);
  const size_t PARTS = A_(1048576 + 4096);
  const size_t XAB = A_(2097152);
  const size_t WTE1 = A_(524288), WTE2 = A_(524288);
  const size_t C_MELS = A_(655360ull * 4), C_DUR = A_(4096 * 4), C_EMB = A_(65536 * 4),
               C_ECW = A_(589824ull * 4), C_EBS = A_(768 * 4), C_EBO = A_(768 * 4),
               C_LFW = A_(524288ull * 4), C_LFB = A_(1024 * 4), C_LBW = A_(524288ull * 4),
               C_LBB = A_(1024 * 4), C_PW1 = A_(20480 * 4), C_P1S = A_(256 * 4),
               C_P1O = A_(256 * 4), C_PW2 = A_(65536 * 4), C_P2S = A_(256 * 4),
               C_P2O = A_(256 * 4), C_DW1 = A_(2621440ull * 4), C_DB1 = A_(2048 * 4),
               C_DW2 = A_(3670016ull * 4), C_DB2 = A_(2048 * 4), C_PRW = A_(122880ull * 4),
               C_PRB = A_(512), C_W0 = A_(204800ull * 4), C_WM = A_(3932160ull * 4),
               C_W4 = A_(204800ull * 4), C_B4 = A_(512), C_PBS = A_(2048 * 4),
               C_PBO = A_(2048 * 4);
  const size_t R1 = A_(16777216), R2 = A_(16777216), R3 = A_(16777216), R4 = A_(16777216),
               MID = A_(4096 * 4), R5 = A_(16777216), R6 = A_(16777216), R7 = A_(25165824),
               D1X = A_(33554432), D2X = A_(33554432), MELP = A_(2621440);
  const size_t XA = R1, XB = R1 + 4194304;
  const size_t GF = R2;
  const size_t GB = R3, H1N = R3;
  const size_t ENC = R4, H2N = R4;
  const size_t COND = R5, PA = R5;
  const size_t PREA = R6, PREB = R6 + 8388608, PB = R6;
  const size_t DECIN = R7, RESID = R7;
  const size_t H1CB = R1, H1NB = R1 + 8388608;
  const size_t H2CB = R2;
  const size_t ENCB = R7;
  // phase-local overlays:
  const size_t WT1 = R4, WT2 = R4 + 6291456;  // bf16 Wt for gate GEMMs (pre-decoder, R4 free)
  const size_t XCOL = R1;                     // postnet im2col bf16 [8192][2560] (spans R1..R3)
  const size_t WTP = D1X;                     // postnet bf16 Wt (post-decoder, D1X free)

  auto F = [&](size_t off) { return (float*)(ws + off); };
  auto U = [&](size_t off) { return (unsigned short*)(ws + off); };
  int* flags = (int*)(ws + FLAGS);
  unsigned int* cntE = (unsigned int*)(ws + SYNC);
  unsigned int* cnt1 = (unsigned int*)(ws + SYNC + 262144);

  hipMemsetAsync(ws + SYNC, 0, 786432, stream);
  k_detect<<<1, 256, 0, stream>>>(d_in[8], d_in[4], flags);

  struct CV { int idx; size_t off; int n; };
  const CV cvs[] = {
      {2, C_MELS, 655360}, {3, C_DUR, 4096}, {8, C_EMB, 65536}, {9, C_ECW, 589824},
      {10, C_EBS, 768}, {11, C_EBO, 768}, {12, C_LFW, 524288}, {13, C_LFB, 1024},
      {14, C_LBW, 524288}, {15, C_LBB, 1024}, {16, C_PW1, 20480}, {17, C_P1S, 256},
      {18, C_P1O, 256}, {19, C_PW2, 65536}, {20, C_P2S, 256}, {21, C_P2O, 256},
      {22, C_DW1, 2621440}, {23, C_DB1, 2048}, {24, C_DW2, 3670016}, {25, C_DB2, 2048},
      {26, C_PRW, 122880}, {27, C_PRB, 80}, {28, C_W0, 204800}, {29, C_WM, 3932160},
      {30, C_W4, 204800}, {31, C_B4, 80}, {32, C_PBS, 2048}, {33, C_PBO, 2048}};
  for (int i = 0; i < (int)(sizeof(cvs) / sizeof(cvs[0])); ++i)
    k_cvt<<<(cvs[i].n + 255) / 256, 256, 0, stream>>>(d_in[cvs[i].idx], F(cvs[i].off), cvs[i].n, flags);

  k_embed<<<4096, 256, 0, stream>>>((const int*)d_in[0], F(C_EMB), F(XA));
  for (int i = 0; i < 3; ++i) {
    k_conv3<<<1024, 256, 0, stream>>>(F(XA), F(C_ECW) + (size_t)i * 196608, F(XB));
    k_cs1<<<256, 256, 0, stream>>>(F(XB), 16, 256, F(PARTS));
    k_cs2<<<256, 256, 0, stream>>>(F(PARTS), 256, 4096, F(STATS));
    k_bnact<0><<<4096, 256, 0, stream>>>(F(XB), F(XA), F(STATS), F(C_EBS) + i * 256, F(C_EBO) + i * 256, 255, 1048576);
  }
  // encoder gate GEMMs via MFMA
  k_cvtb<<<4096, 256, 0, stream>>>(F(XA), U(XAB), 1048576);
  k_trb<<<dim3(4, 16), 256, 0, stream>>>(F(C_LFW), 1024, U(WTE1), 256, 1024);
  k_trb<<<dim3(4, 16), 256, 0, stream>>>(F(C_LBW), 1024, U(WTE2), 256, 1024);
  k_mf<3><<<dim3(64, 16), 256, 0, stream>>>(U(XAB), U(WTE1), F(C_LFB), (void*)(ws + GF), 4096, 1024, 256);
  k_mf<3><<<dim3(64, 16), 256, 0, stream>>>(U(XAB), U(WTE2), F(C_LBB), (void*)(ws + GB), 4096, 1024, 256);
  k_cumsum<<<1, 64, 0, stream>>>(F(C_DUR), F(MID));
  k_enc_lstm<<<128, 256, 0, stream>>>(F(GF), F(GB), F(C_LFW), F(C_LBW), F(ENC), U(ENCB),
                                      (const int*)d_in[1], cntE);
  k_upsample<<<512, 256, 0, stream>>>(F(MID), F(ENC), F(COND));

  k_gemm<0><<<dim3(512, 1), 256, 0, stream>>>(F(C_MELS), F(C_PW1), nullptr, (void*)(ws + PREA), 8192, 80, 256);
  k_cs1<<<256, 256, 0, stream>>>(F(PREA), 32, 256, F(PARTS));
  k_cs2<<<256, 256, 0, stream>>>(F(PARTS), 256, 8192, F(STATS));
  k_bnact<0><<<8192, 256, 0, stream>>>(F(PREA), F(PREB), F(STATS), F(C_P1S), F(C_P1O), 255, 2097152);
  k_gemm<0><<<dim3(512, 1), 256, 0, stream>>>(F(PREB), F(C_PW2), nullptr, (void*)(ws + PREA), 8192, 256, 256);
  k_cs1<<<256, 256, 0, stream>>>(F(PREA), 32, 256, F(PARTS));
  k_cs2<<<256, 256, 0, stream>>>(F(PARTS), 256, 8192, F(STATS));
  k_bnact<0><<<8192, 256, 0, stream>>>(F(PREA), F(PREB), F(STATS), F(C_P2S), F(C_P2O), 255, 2097152);

  k_concat<<<24576, 256, 0, stream>>>(F(COND), F(PREB), U(DECIN));
  // decoder gate GEMMs via MFMA
  k_trb<<<dim3(12, 32), 256, 0, stream>>>(F(C_DW1), 2048, U(WT1), 768, 2048);
  k_trb<<<dim3(12, 32), 256, 0, stream>>>(F(C_DW2), 2048, U(WT2), 768, 2048);
  k_mf<2><<<dim3(128, 32), 256, 0, stream>>>(U(DECIN), U(WT1), F(C_DB1), (void*)(ws + D1X), 8192, 2048, 768);
  k_mf<2><<<dim3(128, 32), 256, 0, stream>>>(U(DECIN), U(WT2), F(C_DB2), (void*)(ws + D2X), 8192, 2048, 768);
  k_dec_lstm<<<128, 256, 0, stream>>>((const unsigned short*)(ws + D1X), (const unsigned short*)(ws + D2X),
                                      F(C_DW1), F(C_DW2), d_in[4], d_in[5], d_in[6], d_in[7],
                                      U(H1CB), U(H1NB), U(H2CB),
                                      F(H1N), F(H2N), cnt1, flags);
  k_proj<<<2048, 320, 0, stream>>>(F(COND), F(H1N), F(H2N), F(C_PRW), F(C_PRB), F(MELP));

  k_conv5<<<1024, 256, 12 * 80 * 4, stream>>>(F(MELP), 80, F(PA), 512, F(C_W0), nullptr);
  k_cs1<<<256, 256, 0, stream>>>(F(PA), 32, 512, F(PARTS));
  k_cs2<<<512, 256, 0, stream>>>(F(PARTS), 512, 8192, F(STATS));
  k_bnact<1><<<16384, 256, 0, stream>>>(F(PA), F(PB), F(STATS), F(C_PBS), F(C_PBO), 511, 4194304);
  for (int i = 0; i < 3; ++i) {
    // mid conv = im2col GEMM on matrix cores
    k_i2c<<<8192, 256, 0, stream>>>(F(PB), U(XCOL));
    k_trb<<<dim3(40, 8), 256, 0, stream>>>(F(C_WM) + (size_t)i * 1310720, 512, U(WTP), 2560, 512);
    k_mf<0><<<dim3(128, 8), 256, 0, stream>>>(U(XCOL), U(WTP), nullptr, (void*)(ws + PA), 8192, 512, 2560);
    k_cs1<<<256, 256, 0, stream>>>(F(PA), 32, 512, F(PARTS));
    k_cs2<<<512, 256, 0, stream>>>(F(PARTS), 512, 8192, F(STATS));
    k_bnact<1><<<16384, 256, 0, stream>>>(F(PA), F(PB), F(STATS), F(C_PBS) + (i + 1) * 512, F(C_PBO) + (i + 1) * 512, 511, 4194304);
  }
  k_conv5<<<1024, 256, 12 * 512 * 4, stream>>>(F(PB), 512, F(RESID), 80, F(C_W4), F(C_B4));
  k_out<<<2560, 256, 0, stream>>>(F(MELP), F(RESID), d_out, flags);
}

// Round 9
// 5237.337 us; speedup vs baseline: 3.2371x; 1.8384x over previous
//
#include <hip/hip_runtime.h>

#define EPSV 1e-5f

typedef unsigned int uivec4 __attribute__((ext_vector_type(4)));
typedef short bh8 __attribute__((ext_vector_type(8)));
typedef float f32x4 __attribute__((ext_vector_type(4)));

__device__ __forceinline__ float b2f(unsigned short u) {
  unsigned int x = ((unsigned int)u) << 16;
  return __uint_as_float(x);
}
__device__ __forceinline__ unsigned short f2b(float f) {
  unsigned int x = __float_as_uint(f);
  unsigned int r = (x + 0x7FFFu + ((x >> 16) & 1u)) >> 16;
  return (unsigned short)r;
}
__device__ __forceinline__ float sigm(float x) { return 1.0f / (1.0f + expf(-x)); }

// ---- coherence-point (device-coherent) access: bypass L1+L2 both ways ----
__device__ __forceinline__ void stg_bf16(unsigned short* p, float v) {
  unsigned short h = f2b(v);
  asm volatile("global_store_short %0, %1, off sc0 sc1" ::"v"(p), "v"(h) : "memory");
}
__device__ __forceinline__ void ldg2_sc(const unsigned short* p0, const unsigned short* p1,
                                        uivec4& a, uivec4& b) {
  asm volatile(
      "global_load_dwordx4 %0, %2, off sc0 sc1\n\t"
      "global_load_dwordx4 %1, %3, off sc0 sc1\n\t"
      "s_waitcnt vmcnt(0)"
      : "=&v"(a), "=&v"(b)
      : "v"(p0), "v"(p1)
      : "memory");
}
// 4 x 16B from one pointer at byte offsets 0/256/512/768 (no wait)
__device__ __forceinline__ void ldg4f_nw(const unsigned short* p, uivec4& a, uivec4& b,
                                         uivec4& c, uivec4& d) {
  asm volatile(
      "global_load_dwordx4 %0, %4, off sc0 sc1\n\t"
      "global_load_dwordx4 %1, %4, off offset:256 sc0 sc1\n\t"
      "global_load_dwordx4 %2, %4, off offset:512 sc0 sc1\n\t"
      "global_load_dwordx4 %3, %4, off offset:768 sc0 sc1"
      : "=&v"(a), "=&v"(b), "=&v"(c), "=&v"(d)
      : "v"(p)
      : "memory");
}
__device__ __forceinline__ void vm0() { asm volatile("s_waitcnt vmcnt(0)" ::: "memory"); }
__device__ __forceinline__ unsigned int ldcnt(const unsigned int* p) {
  return __hip_atomic_load(p, __ATOMIC_RELAXED, __HIP_MEMORY_SCOPE_AGENT);
}

// ---------------- dtype detection ----------------
__global__ void k_detect(const void* __restrict__ embp, const void* __restrict__ zmp,
                         int* __restrict__ flags) {
  __shared__ int sh[4];
  int tid = threadIdx.x;
  if (tid < 4) sh[tid] = 0;
  __syncthreads();
  const unsigned short* u = (const unsigned short*)embp;
  int bad = 0;
  for (int i = tid; i < 4096; i += 256) {
    float f = fabsf(b2f(u[i]));
    if (!(f < 1e10f)) bad = 1;
  }
  if (bad) atomicAdd(&sh[3], 1);
  const unsigned char* p = (const unsigned char*)zmp;
  int codd = 0, c0 = 0, c1v = 0;
  for (int i = tid; i < 65536; i += 256) {
    unsigned char v = p[i];
    if (v) {
      if (i & 1) codd++;
      if ((i & 3) == 0) c0++;
      if (v == 1) c1v++;
    }
  }
  atomicAdd(&sh[0], codd); atomicAdd(&sh[1], c0); atomicAdd(&sh[2], c1v);
  __syncthreads();
  if (tid == 0) {
    flags[0] = sh[3] ? 1 : 0;
    int mode;
    if (sh[0] == 0) mode = 1;
    else if (sh[2] > 0) mode = 0;
    else if (sh[1] == 0) mode = 2;
    else mode = 3;
    flags[1] = mode;
  }
}

__global__ void k_cvt(const void* __restrict__ src, float* __restrict__ dst, int n,
                      const int* __restrict__ flags) {
  int i = blockIdx.x * 256 + threadIdx.x;
  if (i >= n) return;
  if (flags[0]) dst[i] = ((const float*)src)[i];
  else dst[i] = b2f(((const unsigned short*)src)[i]);
}

__global__ void k_cvtb(const float* __restrict__ src, unsigned short* __restrict__ dst, int n) {
  int i = blockIdx.x * 256 + threadIdx.x;
  if (i >= n) return;
  dst[i] = f2b(src[i]);
}

// cast row-wise with K -> Kpad zero padding
__global__ void k_cvtbp(const float* __restrict__ src, unsigned short* __restrict__ dst,
                        int K, int Kpad) {
  int r = blockIdx.x;
  int c = threadIdx.x;
  if (c < Kpad)
    dst[(size_t)r * Kpad + c] = (c < K) ? f2b(src[(size_t)r * K + c]) : (unsigned short)0;
}

__device__ __forceinline__ bool mask_at(const void* p, size_t i, int mode) {
  switch (mode) {
    case 0: return ((const unsigned char*)p)[i] != 0;
    case 1: return ((const int*)p)[i] != 0;
    case 2: return ((const float*)p)[i] != 0.0f;
    default: return ((const unsigned short*)p)[i] != 0;
  }
}

// ---------------- embedding ----------------
__global__ void k_embed(const int* __restrict__ ph, const float* __restrict__ emb,
                        float* __restrict__ X) {
  int bl = blockIdx.x;
  int p = ph[bl];
  X[(size_t)bl * 256 + threadIdx.x] = emb[(size_t)p * 256 + threadIdx.x];
}

// ---------------- per-channel mean/var: 2-stage coalesced, deterministic ----------------
__global__ __launch_bounds__(256) void k_cs1(const float* __restrict__ X, int RB, int C,
                                             float* __restrict__ part) {
  int blk = blockIdx.x;
  int r0 = blk * RB;
  float s0 = 0.f, q0 = 0.f, s1 = 0.f, q1 = 0.f;
  for (int rr = 0; rr < RB; ++rr) {
    const float* row = X + (size_t)(r0 + rr) * C;
    float v = row[threadIdx.x];
    s0 += v; q0 += v * v;
    if (C > 256) {
      float v1 = row[256 + threadIdx.x];
      s1 += v1; q1 += v1 * v1;
    }
  }
  float* pr = part + (size_t)blk * 2 * C;
  pr[threadIdx.x] = s0;
  pr[C + threadIdx.x] = q0;
  if (C > 256) {
    pr[256 + threadIdx.x] = s1;
    pr[C + 256 + threadIdx.x] = q1;
  }
}
__global__ __launch_bounds__(256) void k_cs2(const float* __restrict__ part, int C, int R,
                                             float* __restrict__ st) {
  int c = blockIdx.x;
  int t = threadIdx.x;
  __shared__ float rs_[256], rq_[256];
  rs_[t] = part[(size_t)t * 2 * C + c];
  rq_[t] = part[(size_t)t * 2 * C + C + c];
  __syncthreads();
  for (int k = 128; k > 0; k >>= 1) {
    if (t < k) { rs_[t] += rs_[t + k]; rq_[t] += rq_[t + k]; }
    __syncthreads();
  }
  if (t == 0) {
    float m = rs_[0] / R;
    st[c] = m;
    st[C + c] = rq_[0] / R - m * m;
  }
}

template <int ACT>
__global__ void k_bnact(const float* __restrict__ X, float* __restrict__ Y,
                        const float* __restrict__ st, const float* __restrict__ sc,
                        const float* __restrict__ of, int Cmask, int n) {
  int i = blockIdx.x * 256 + threadIdx.x;
  if (i >= n) return;
  int C = Cmask + 1;
  int c = i & Cmask;
  float m = st[c], v = st[C + c];
  float y = (X[i] - m) * rsqrtf(v + EPSV) * sc[c] + of[c];
  Y[i] = ACT ? tanhf(y) : fmaxf(y, 0.0f);
}

// ---------------- padded tiled transpose f32[K][ldn] -> bf16[Npad][Kpad] ----------------
__global__ __launch_bounds__(256) void k_trbp(const float* __restrict__ src, int ldn,
                                              unsigned short* __restrict__ dst,
                                              int K, int Kpad, int N, int Npad) {
  __shared__ float tl[64][65];
  int k0 = blockIdx.x * 64, n0 = blockIdx.y * 64;
  int tid = threadIdx.x;
#pragma unroll
  for (int p = 0; p < 16; ++p) {
    int idx = p * 256 + tid;
    int r = idx >> 6, c = idx & 63;
    float v = 0.0f;
    if (k0 + r < K && n0 + c < N) v = src[(size_t)(k0 + r) * ldn + n0 + c];
    tl[r][c] = v;
  }
  __syncthreads();
#pragma unroll
  for (int p = 0; p < 16; ++p) {
    int idx = p * 256 + tid;
    int rr = idx >> 6, cc = idx & 63;
    if (n0 + rr < Npad && k0 + cc < Kpad)
      dst[(size_t)(n0 + rr) * Kpad + k0 + cc] = f2b(tl[cc][rr]);
  }
}

// ---------------- im2col kernels (f32 -> bf16) ----------------
// k=3 SAME over l, Cin=256 -> [4096][768]
__global__ __launch_bounds__(256) void k_i2c3(const float* __restrict__ X,
                                              unsigned short* __restrict__ out) {
  int r = blockIdx.x;
  int b = r >> 8, l = r & 255;
#pragma unroll
  for (int p = 0; p < 3; ++p) {
    int col = p * 256 + threadIdx.x;
    int d = col >> 8, ci = col & 255;
    int ll = l + d - 1;
    float v = (ll >= 0 && ll < 256) ? X[(size_t)(b * 256 + ll) * 256 + ci] : 0.0f;
    out[(size_t)r * 768 + col] = f2b(v);
  }
}
// k=5 SAME over t, Cin=512 -> [8192][2560]
__global__ __launch_bounds__(256) void k_i2c(const float* __restrict__ X,
                                             unsigned short* __restrict__ out) {
  int r = blockIdx.x;
  int b = r >> 9, t = r & 511;
#pragma unroll
  for (int p = 0; p < 10; ++p) {
    int col = p * 256 + threadIdx.x;
    int dt = col >> 9, ci = col & 511;
    int tt = t + dt - 2;
    float v = (tt >= 0 && tt < 512) ? X[((size_t)(b * 512 + tt)) * 512 + ci] : 0.0f;
    out[(size_t)r * 2560 + col] = f2b(v);
  }
}
// k=5 SAME over t, Cin=80 -> [8192][416] (K=400 padded to 416)
__global__ __launch_bounds__(256) void k_i2c80(const float* __restrict__ X,
                                               unsigned short* __restrict__ out) {
  int r = blockIdx.x;
  int b = r >> 9, t = r & 511;
#pragma unroll
  for (int p = 0; p < 2; ++p) {
    int col = p * 256 + threadIdx.x;
    if (col < 416) {
      float v = 0.0f;
      if (col < 400) {
        int dt = col / 80, ci = col - dt * 80;
        int tt = t + dt - 2;
        if (tt >= 0 && tt < 512) v = X[(size_t)(b * 512 + tt) * 80 + ci];
      }
      out[(size_t)r * 416 + col] = f2b(v);
    }
  }
}

// build proj A-matrix bf16 [8192][1536] = [cond | h1n | h2n]
__global__ __launch_bounds__(256) void k_cat3b(const float* __restrict__ cond,
                                               const float* __restrict__ h1n,
                                               const float* __restrict__ h2n,
                                               unsigned short* __restrict__ out) {
  int r = blockIdx.x;
  int b = r >> 9, t = r & 511;
#pragma unroll
  for (int p = 0; p < 6; ++p) {
    int col = p * 256 + threadIdx.x;
    float v;
    if (col < 512) v = cond[(size_t)r * 512 + col];
    else if (col < 1024) v = h1n[(size_t)(t * 16 + b) * 512 + (col - 512)];
    else v = h2n[(size_t)(t * 16 + b) * 512 + (col - 1024)];
    out[(size_t)r * 1536 + col] = f2b(v);
  }
}

// ---------------- MFMA GEMM: C[M,N] = A[M,K]bf16 @ Bt[N,K]bf16^T (+bias) ----------------
// OBF: 0 = f32 row-major (ldc=N), 2 = bf16 decoder-gate layout, 3 = f32 encoder-gate layout,
//      4 = f32 row-major with ldc=Nst and col guard n<Nst (padded-N)
template <int OBF>
__global__ __launch_bounds__(256) void k_mf(const unsigned short* __restrict__ A,
                                            const unsigned short* __restrict__ Bt,
                                            const float* __restrict__ bias,
                                            void* __restrict__ Cp, int M, int N, int K,
                                            int Nst) {
  const int lane = threadIdx.x & 63, wv = threadIdx.x >> 6;
  const int m0 = blockIdx.x * 64 + wv * 16;
  const int n0 = blockIdx.y * 64;
  const int koff = (lane >> 4) << 3;
  const unsigned short* arow = A + (size_t)(m0 + (lane & 15)) * K + koff;
  const unsigned short* brow0 = Bt + (size_t)(n0 + 0 * 16 + (lane & 15)) * K + koff;
  const unsigned short* brow1 = Bt + (size_t)(n0 + 1 * 16 + (lane & 15)) * K + koff;
  const unsigned short* brow2 = Bt + (size_t)(n0 + 2 * 16 + (lane & 15)) * K + koff;
  const unsigned short* brow3 = Bt + (size_t)(n0 + 3 * 16 + (lane & 15)) * K + koff;
  f32x4 acc0 = {0.f, 0.f, 0.f, 0.f}, acc1 = {0.f, 0.f, 0.f, 0.f};
  f32x4 acc2 = {0.f, 0.f, 0.f, 0.f}, acc3 = {0.f, 0.f, 0.f, 0.f};
  for (int k = 0; k < K; k += 32) {
    bh8 a = *(const bh8*)(arow + k);
    bh8 b0 = *(const bh8*)(brow0 + k);
    bh8 b1 = *(const bh8*)(brow1 + k);
    bh8 b2 = *(const bh8*)(brow2 + k);
    bh8 b3 = *(const bh8*)(brow3 + k);
    acc0 = __builtin_amdgcn_mfma_f32_16x16x32_bf16(a, b0, acc0, 0, 0, 0);
    acc1 = __builtin_amdgcn_mfma_f32_16x16x32_bf16(a, b1, acc1, 0, 0, 0);
    acc2 = __builtin_amdgcn_mfma_f32_16x16x32_bf16(a, b2, acc2, 0, 0, 0);
    acc3 = __builtin_amdgcn_mfma_f32_16x16x32_bf16(a, b3, acc3, 0, 0, 0);
  }
  const int r0 = m0 + ((lane >> 4) << 2);
  const int nl = lane & 15;
  float av[4][4];
#pragma unroll
  for (int r = 0; r < 4; ++r) { av[0][r] = acc0[r]; av[1][r] = acc1[r]; av[2][r] = acc2[r]; av[3][r] = acc3[r]; }
#pragma unroll
  for (int t = 0; t < 4; ++t) {
    int n = n0 + t * 16 + nl;
    float bv = 0.0f;
    if (bias) {
      if (OBF == 4) bv = (n < Nst) ? bias[n] : 0.0f;
      else bv = bias[n];
    }
#pragma unroll
    for (int r = 0; r < 4; ++r) {
      float v = av[t][r] + bv;
      int row = r0 + r;
      if (OBF == 0) {
        ((float*)Cp)[(size_t)row * N + n] = v;
      } else if (OBF == 4) {
        if (n < Nst) ((float*)Cp)[(size_t)row * Nst + n] = v;
      } else if (OBF == 2) {
        int b = row >> 9, tt = row & 511;
        int g = n >> 9, w = (n & 511) >> 2, jj = n & 3;
        ((unsigned short*)Cp)[((size_t)tt * 128 + w) * 256 + b * 16 + g * 4 + jj] = f2b(v);
      } else {
        int b = row >> 8, l = row & 255;
        int g = n >> 8, w = (n & 255) >> 2, jj = n & 3;
        ((float*)Cp)[((size_t)l * 64 + w) * 256 + b * 16 + g * 4 + jj] = v;
      }
    }
  }
}

// ---------------- duration cumsum ----------------
__global__ void k_cumsum(const float* __restrict__ dur, float* __restrict__ mid) {
  int b = threadIdx.x;
  if (b >= 16) return;
  float run = 0.f;
  for (int l = 0; l < 256; ++l) {
    float d = dur[b * 256 + l];
    run += d;
    mid[b * 256 + l] = run - 0.5f * d;
  }
}

// ---------------- persistent bi-LSTM encoder (MFMA recurrent dot) ----------------
// grid 128: wg<64 fwd, >=64 bwd. Each wg owns 4 h-cols of 256 -> 16x16 gate tile per step.
#define EST 130  // u32 stride per batch row (260 bf16)
__global__ __launch_bounds__(256) void k_enc_lstm(const float* __restrict__ GFp,
                                                  const float* __restrict__ GBp,
                                                  const float* __restrict__ Wf,
                                                  const float* __restrict__ Wb,
                                                  float* __restrict__ enc,
                                                  unsigned short* __restrict__ encB,
                                                  const int* __restrict__ lengths,
                                                  unsigned int* __restrict__ cnt) {
  const int tid = threadIdx.x;
  const int wg = blockIdx.x;
  const int dir = wg >> 6;
  const int w = wg & 63;
  const float* Gpre = dir ? GBp : GFp;
  const float* W = dir ? Wb : Wf;
  unsigned int* c_self = cnt + (size_t)dir * 256 * 128;

  __shared__ __align__(16) unsigned int hsW[16 * EST];
  __shared__ __align__(16) float accb[4 * 264];
  __shared__ __align__(16) float gl[256];
  __shared__ float cst[64];
  __shared__ int rs[16];

  const int lane = tid & 63, wv = tid >> 6;
  const int n16 = lane & 15, lq = lane >> 4;
  const int colg = (n16 & 3) * 256 + w * 4 + (n16 >> 2);
  // preload B fragments (weights W^T[gatecol][k]) into registers: 2 chunks per wave
  bh8 BE[2];
#pragma unroll
  for (int c = 0; c < 2; ++c) {
#pragma unroll
    for (int jj = 0; jj < 8; ++jj) {
      int k = (wv * 2 + c) * 32 + lq * 8 + jj;
      BE[c][jj] = (short)f2b(W[(size_t)(256 + k) * 1024 + colg]);
    }
  }
  if (tid < 64) cst[tid] = 0.0f;
  __syncthreads();

  const int b_ = tid >> 4, j_ = (tid >> 2) & 3, g_ = tid & 3;

  for (int t = 0; t < 256; ++t) {
    const int l = dir ? (255 - t) : t;
    if (tid < 16) rs[tid] = (dir == 1) && (l >= lengths[tid] - 1);
    float gpre = Gpre[((size_t)l * 64 + w) * 256 + b_ * 16 + g_ * 4 + j_];
    if (t > 0 && tid < 8) {
      const unsigned int* a = c_self + (size_t)(t - 1) * 128 + tid * 16;
      unsigned int gcount = 0;
      while (ldcnt(a) < 8u) {
        __builtin_amdgcn_s_sleep(2);
        if (++gcount > (1u << 16)) break;
      }
    }
    __syncthreads();
    if (t > 0) {
      const int lprev = dir ? (l + 1) : (l - 1);
      int b = tid >> 4, q = tid & 15;  // 16 lanes read 512B contiguous per row
      const unsigned short* p = encB + ((size_t)dir << 20) + (((size_t)lprev * 16 + b) << 8) + q * 16;
      uivec4 a0, a1;
      ldg2_sc(p, p + 8, a0, a1);
      if (rs[b]) {
        a0.x = a0.y = a0.z = a0.w = 0u;
        a1.x = a1.y = a1.z = a1.w = 0u;
      }
      *(uivec4*)&hsW[b * EST + q * 8] = a0;
      *(uivec4*)&hsW[b * EST + q * 8 + 4] = a1;
    }
    __syncthreads();

    f32x4 acc = {0.f, 0.f, 0.f, 0.f};
    if (t > 0) {
#pragma unroll
      for (int c = 0; c < 2; ++c) {
        int kw = (wv * 2 + c) * 16 + lq * 4;
        bh8 af = *(const bh8*)&hsW[(lane & 15) * EST + kw];
        acc = __builtin_amdgcn_mfma_f32_16x16x32_bf16(af, BE[c], acc, 0, 0, 0);
      }
    }
    {
      int idx = lq * 64 + (lane & 15);
      float* pb = &accb[wv * 264];
#pragma unroll
      for (int r = 0; r < 4; ++r) pb[idx + r * 16] = acc[r];
    }
    __syncthreads();
    gl[tid] = gpre + accb[tid] + accb[264 + tid] + accb[528 + tid] + accb[792 + tid];
    __syncthreads();
    if (tid < 64) {
      int b = tid >> 2, j = tid & 3;
      float4 G = ((const float4*)gl)[tid];
      float c = cst[tid];
      if (t == 0 || rs[b]) c = 0.0f;
      c = sigm(G.z + 1.0f) * c + sigm(G.x) * tanhf(G.y);
      float h = sigm(G.w) * tanhf(c);
      cst[tid] = c;
      enc[(size_t)(b * 256 + l) * 512 + dir * 256 + (w * 4 + j)] = h;
      stg_bf16(&encB[((size_t)dir << 20) + (((size_t)l * 16 + b) << 8) + (w * 4 + j)], h);
    }
    vm0();
    __syncthreads();
    if (tid == 0)
      __hip_atomic_fetch_add(c_self + (size_t)t * 128 + (w >> 3) * 16, 1u,
                             __ATOMIC_RELAXED, __HIP_MEMORY_SCOPE_AGENT);
  }
}

// ---------------- Gaussian-softmax upsampling ----------------
__global__ __launch_bounds__(256) void k_upsample(const float* __restrict__ mid,
                                                  const float* __restrict__ enc,
                                                  float* __restrict__ cond) {
  int blk = blockIdx.x;
  int b = blk >> 5, t0 = (blk & 31) * 16;
  int tid = threadIdx.x;
  __shared__ float wls[16][256];
  __shared__ float red[256];
  float mp = mid[b * 256 + tid];
  for (int tt = 0; tt < 16; ++tt) {
    float tpos = (float)(t0 + tt);
    float d = mp - tpos;
    float d2 = d * d * 0.1f;
    red[tid] = d2; __syncthreads();
    for (int k = 128; k > 0; k >>= 1) { if (tid < k) red[tid] = fminf(red[tid], red[tid + k]); __syncthreads(); }
    float mn = red[0]; __syncthreads();
    float e = expf(mn - d2);
    red[tid] = e; __syncthreads();
    for (int k = 128; k > 0; k >>= 1) { if (tid < k) red[tid] += red[tid + k]; __syncthreads(); }
    float sum = red[0]; __syncthreads();
    wls[tt][tid] = e / sum;
  }
  __syncthreads();
  float a0[16], a1[16];
#pragma unroll
  for (int i = 0; i < 16; ++i) { a0[i] = 0; a1[i] = 0; }
  for (int l = 0; l < 256; ++l) {
    float e0 = enc[(size_t)(b * 256 + l) * 512 + tid];
    float e1 = enc[(size_t)(b * 256 + l) * 512 + 256 + tid];
#pragma unroll
    for (int tt = 0; tt < 16; ++tt) { float wv = wls[tt][l]; a0[tt] += wv * e0; a1[tt] += wv * e1; }
  }
  for (int tt = 0; tt < 16; ++tt) {
    cond[(size_t)(b * 512 + t0 + tt) * 512 + tid] = a0[tt];
    cond[(size_t)(b * 512 + t0 + tt) * 512 + 256 + tid] = a1[tt];
  }
}

// concat -> bf16 decoder input A-matrix [8192][768]
__global__ void k_concat(const float* __restrict__ cond, const float* __restrict__ p,
                         unsigned short* __restrict__ din) {
  size_t i = (size_t)blockIdx.x * 256 + threadIdx.x;
  int r = (int)(i / 768);
  int c = (int)(i % 768);
  float v = (c < 512) ? cond[(size_t)r * 512 + c] : p[(size_t)r * 256 + (c - 512)];
  din[i] = f2b(v);
}

// ---------------- merged 2-layer zoneout LSTM decoder (MFMA recurrent dots) ----------------
// 128 WGs; WG w owns cols [4w,4w+4) of BOTH layers (16x16 gate tile each). L2 lags L1 by 1.
#define DST 780  // u32 stride per batch row (1560 bf16: h1c|h1n|h2c + pad)
__global__ __launch_bounds__(256) void k_dec_lstm(
    const unsigned short* __restrict__ D1x, const unsigned short* __restrict__ D2x,
    const float* __restrict__ W1, const float* __restrict__ W2,
    const void* __restrict__ zh1, const void* __restrict__ zc1,
    const void* __restrict__ zh2, const void* __restrict__ zc2,
    unsigned short* __restrict__ h1cB, unsigned short* __restrict__ h1nB,
    unsigned short* __restrict__ h2cB,
    float* __restrict__ h1n, float* __restrict__ h2n,
    unsigned int* __restrict__ cnt1,
    const int* __restrict__ flags) {
  const int tid = threadIdx.x;
  const int w = blockIdx.x;

  __shared__ __align__(16) unsigned int hsW[16 * DST];
  __shared__ __align__(16) float accb[8 * 264];
  __shared__ __align__(16) float gl1[256], gl2[256];
  __shared__ float cst1[64], hst1[64], cst2[64], hst2[64];

  const int mmode = flags[1];
  const int lane = tid & 63, wv = tid >> 6;
  const int n16 = lane & 15, lq = lane >> 4;
  const int colg = (n16 & 3) * 512 + w * 4 + (n16 >> 2);

  // preload weight fragments: L1 4 chunks/wave (K=512), L2 8 chunks/wave (K=1024)
  bh8 B1[4], B2[8];
#pragma unroll
  for (int c = 0; c < 4; ++c) {
#pragma unroll
    for (int jj = 0; jj < 8; ++jj) {
      int k = (wv * 4 + c) * 32 + lq * 8 + jj;
      B1[c][jj] = (short)f2b(W1[(size_t)(768 + k) * 2048 + colg]);
    }
  }
#pragma unroll
  for (int c = 0; c < 8; ++c) {
#pragma unroll
    for (int jj = 0; jj < 8; ++jj) {
      int k = (wv * 8 + c) * 32 + lq * 8 + jj;
      B2[c][jj] = (short)f2b(W2[(size_t)(768 + k) * 2048 + colg]);
    }
  }
  if (tid < 64) { cst1[tid] = 0; hst1[tid] = 0; cst2[tid] = 0; hst2[tid] = 0; }
  __syncthreads();

  const int b_ = tid >> 4, j_ = (tid >> 2) & 3, g_ = tid & 3;

  for (int tau = 0; tau <= 512; ++tau) {
    float dxv1 = 0.0f, dxv2 = 0.0f;
    if (tau < 512)
      dxv1 = b2f(D1x[((size_t)tau * 128 + w) * 256 + b_ * 16 + g_ * 4 + j_]);
    if (tau >= 1)
      dxv2 = b2f(D2x[((size_t)(tau - 1) * 128 + w) * 256 + b_ * 16 + g_ * 4 + j_]);

    if (tau >= 1 && tid < 8) {
      const unsigned int* a = cnt1 + (size_t)(tau - 1) * 128 + tid * 16;
      unsigned int gcount = 0;
      while (ldcnt(a) < 16u) {
        __builtin_amdgcn_s_sleep(2);
        if (++gcount > (1u << 16)) break;
      }
    }
    __syncthreads();

    if (tau >= 1) {
      // coalesced stage: raw bf16 into LDS (no unpack; MFMA consumes bf16 directly)
      int b = tid >> 4, q = tid & 15;
      const unsigned short* p0 = h1cB + (((size_t)(tau - 1) * 16 + b) << 9) + q * 8;
      const unsigned short* p1 = h1nB + (((size_t)(tau - 1) * 16 + b) << 9) + q * 8;
      uivec4 r[12];
      ldg4f_nw(p0, r[0], r[1], r[2], r[3]);
      ldg4f_nw(p1, r[4], r[5], r[6], r[7]);
      if (tau >= 2) {
        const unsigned short* p2 = h2cB + (((size_t)(tau - 2) * 16 + b) << 9) + q * 8;
        ldg4f_nw(p2, r[8], r[9], r[10], r[11]);
      } else {
        uivec4 z; z.x = z.y = z.z = z.w = 0u;
        r[8] = z; r[9] = z; r[10] = z; r[11] = z;
      }
      vm0();
      unsigned int base = b * DST + q * 4;
#pragma unroll
      for (int m = 0; m < 4; ++m) *(uivec4*)&hsW[base + 64 * m] = r[m];
#pragma unroll
      for (int m = 0; m < 4; ++m) *(uivec4*)&hsW[base + 256 + 64 * m] = r[4 + m];
#pragma unroll
      for (int m = 0; m < 4; ++m) *(uivec4*)&hsW[base + 512 + 64 * m] = r[8 + m];
    }
    __syncthreads();

    f32x4 a1 = {0.f, 0.f, 0.f, 0.f}, a2 = {0.f, 0.f, 0.f, 0.f};
    if (tau >= 1) {
      if (tau < 512) {
#pragma unroll
        for (int c = 0; c < 4; ++c) {
          int kw = (wv * 4 + c) * 16 + lq * 4;
          bh8 af = *(const bh8*)&hsW[(lane & 15) * DST + kw];
          a1 = __builtin_amdgcn_mfma_f32_16x16x32_bf16(af, B1[c], a1, 0, 0, 0);
        }
      }
#pragma unroll
      for (int c = 0; c < 8; ++c) {
        int kw = 256 + (wv * 8 + c) * 16 + lq * 4;
        bh8 af = *(const bh8*)&hsW[(lane & 15) * DST + kw];
        a2 = __builtin_amdgcn_mfma_f32_16x16x32_bf16(af, B2[c], a2, 0, 0, 0);
      }
    }
    {
      int idx = lq * 64 + (lane & 15);
      float* p1b = &accb[wv * 264];
      float* p2b = &accb[(4 + wv) * 264];
#pragma unroll
      for (int r = 0; r < 4; ++r) p1b[idx + r * 16] = a1[r];
#pragma unroll
      for (int r = 0; r < 4; ++r) p2b[idx + r * 16] = a2[r];
    }
    __syncthreads();
    gl1[tid] = dxv1 + accb[tid] + accb[264 + tid] + accb[528 + tid] + accb[792 + tid];
    gl2[tid] = dxv2 + accb[1056 + tid] + accb[1320 + tid] + accb[1584 + tid] + accb[1848 + tid];
    __syncthreads();

    if (tid < 64) {
      if (tau < 512) {
        int b = tid >> 2, j = tid & 3, colgw = w * 4 + j;
        float4 G = ((const float4*)gl1)[tid];
        float cold = (tau == 0) ? 0.0f : cst1[tid];
        float hold = (tau == 0) ? 0.0f : hst1[tid];
        float nc = sigm(G.z + 1.0f) * cold + sigm(G.x) * tanhf(G.y);
        float nh = sigm(G.w) * tanhf(nc);
        size_t mi = ((size_t)b * 512 + tau) * 512 + colgw;
        bool mh = mask_at(zh1, mi, mmode);
        bool mc = mask_at(zc1, mi, mmode);
        cst1[tid] = mc ? cold : nc;
        float hkeep = mh ? hold : nh;
        hst1[tid] = hkeep;
        h1n[(size_t)(tau * 16 + b) * 512 + colgw] = nh;
        stg_bf16(&h1cB[(((size_t)tau * 16 + b) << 9) + colgw], hkeep);
        stg_bf16(&h1nB[(((size_t)tau * 16 + b) << 9) + colgw], nh);
      }
    } else if (tid < 128) {
      if (tau >= 1) {
        int u = tid - 64;
        int t2 = tau - 1;
        int b = u >> 2, j = u & 3, colgw = w * 4 + j;
        float4 G = ((const float4*)gl2)[u];
        float cold = (tau == 1) ? 0.0f : cst2[u];
        float hold = (tau == 1) ? 0.0f : hst2[u];
        float nc = sigm(G.z + 1.0f) * cold + sigm(G.x) * tanhf(G.y);
        float nh = sigm(G.w) * tanhf(nc);
        size_t mi = ((size_t)b * 512 + t2) * 512 + colgw;
        bool mh = mask_at(zh2, mi, mmode);
        bool mc = mask_at(zc2, mi, mmode);
        cst2[u] = mc ? cold : nc;
        float hkeep = mh ? hold : nh;
        hst2[u] = hkeep;
        h2n[(size_t)(t2 * 16 + b) * 512 + colgw] = nh;
        stg_bf16(&h2cB[(((size_t)t2 * 16 + b) << 9) + colgw], hkeep);
      }
    }
    vm0();
    __syncthreads();
    if (tid == 0)
      __hip_atomic_fetch_add(cnt1 + (size_t)tau * 128 + (w >> 4) * 16, 1u,
                             __ATOMIC_RELAXED, __HIP_MEMORY_SCOPE_AGENT);
  }
}

__global__ void k_out(const float* __restrict__ mel, const float* __restrict__ res,
                      void* __restrict__ out, const int* __restrict__ flags) {
  int i = blockIdx.x * 256 + threadIdx.x;
  float m = mel[i];
  float f = m + res[i];
  if (flags[0]) {
    ((float*)out)[i] = m;
    ((float*)out)[655360 + i] = f;
  } else {
    unsigned short* o = (unsigned short*)out;
    o[i] = f2b(m);
    o[655360 + i] = f2b(f);
  }
}

// ---------------- host launch ----------------
extern "C" void kernel_launch(void* const* d_in, const int* in_sizes, int n_in,
                              void* d_out, int out_size, void* d_ws, size_t ws_size,
                              hipStream_t stream) {
  char* ws = (char*)d_ws;
  size_t o = 0;
  auto A_ = [&](size_t nb) { size_t r = o; o += (nb + 255) & ~(size_t)255; return r; };
  const size_t FLAGS = A_(256);
  const size_t SYNC = A_(786432);
  const size_t STATS = A_(4096);
  const size_t PARTS = A_(1048576 + 4096);
  const size_t XAB = A_(2097152);
  const size_t WTE1 = A_(524288), WTE2 = A_(524288);
  const size_t C_MELS = A_(655360ull * 4), C_DUR = A_(4096 * 4), C_EMB = A_(65536 * 4),
               C_ECW = A_(589824ull * 4), C_EBS = A_(768 * 4), C_EBO = A_(768 * 4),
               C_LFW = A_(524288ull * 4), C_LFB = A_(1024 * 4), C_LBW = A_(524288ull * 4),
               C_LBB = A_(1024 * 4), C_PW1 = A_(20480 * 4), C_P1S = A_(256 * 4),
               C_P1O = A_(256 * 4), C_PW2 = A_(65536 * 4), C_P2S = A_(256 * 4),
               C_P2O = A_(256 * 4), C_DW1 = A_(2621440ull * 4), C_DB1 = A_(2048 * 4),
               C_DW2 = A_(3670016ull * 4), C_DB2 = A_(2048 * 4), C_PRW = A_(122880ull * 4),
               C_PRB = A_(512), C_W0 = A_(204800ull * 4), C_WM = A_(3932160ull * 4),
               C_W4 = A_(204800ull * 4), C_B4 = A_(512), C_PBS = A_(2048 * 4),
               C_PBO = A_(2048 * 4);
  const size_t R1 = A_(16777216), R2 = A_(16777216), R3 = A_(16777216), R4 = A_(16777216),
               MID = A_(4096 * 4), R5 = A_(16777216), R6 = A_(16777216), R7 = A_(25165824),
               D1X = A_(33554432), D2X = A_(33554432), MELP = A_(2621440);
  const size_t XA = R1, XB = R1 + 4194304;
  const size_t XCOL3 = R2, ECWT = R3;
  const size_t GF = R2;
  const size_t GB = R3, H1N = R3;
  const size_t ENC = R4, H2N = R4;
  const size_t COND = R5, PA = R5;
  const size_t PREA = R6, PREB = R6 + 8388608, PB = R6;
  const size_t DECIN = R7, RESID = R7;
  const size_t H1CB = R1, H1NB = R1 + 8388608;
  const size_t H2CB = R2;
  const size_t ENCB = R7;
  const size_t MELB = R1, PW1T = R1 + 2097152, PREBB = R1, PW2T = R1 + 8388608;
  const size_t WT1 = R4, WT2 = R4 + 4194304;
  const size_t PROJA = R1;  // spans R1..R2 (25MB)
  const size_t PRWT = R6;
  const size_t XCOL80 = R1, W0T = R2;
  const size_t XCOL = R1;  // spans R1..R3 (42MB)
  const size_t WTP = D1X, W4T = D2X;

  auto F = [&](size_t off) { return (float*)(ws + off); };
  auto U = [&](size_t off) { return (unsigned short*)(ws + off); };
  int* flags = (int*)(ws + FLAGS);
  unsigned int* cntE = (unsigned int*)(ws + SYNC);
  unsigned int* cnt1 = (unsigned int*)(ws + SYNC + 262144);

  hipMemsetAsync(ws + SYNC, 0, 786432, stream);
  k_detect<<<1, 256, 0, stream>>>(d_in[8], d_in[4], flags);

  struct CV { int idx; size_t off; int n; };
  const CV cvs[] = {
      {2, C_MELS, 655360}, {3, C_DUR, 4096}, {8, C_EMB, 65536}, {9, C_ECW, 589824},
      {10, C_EBS, 768}, {11, C_EBO, 768}, {12, C_LFW, 524288}, {13, C_LFB, 1024},
      {14, C_LBW, 524288}, {15, C_LBB, 1024}, {16, C_PW1, 20480}, {17, C_P1S, 256},
      {18, C_P1O, 256}, {19, C_PW2, 65536}, {20, C_P2S, 256}, {21, C_P2O, 256},
      {22, C_DW1, 2621440}, {23, C_DB1, 2048}, {24, C_DW2, 3670016}, {25, C_DB2, 2048},
      {26, C_PRW, 122880}, {27, C_PRB, 80}, {28, C_W0, 204800}, {29, C_WM, 3932160},
      {30, C_W4, 204800}, {31, C_B4, 80}, {32, C_PBS, 2048}, {33, C_PBO, 2048}};
  for (int i = 0; i < (int)(sizeof(cvs) / sizeof(cvs[0])); ++i)
    k_cvt<<<(cvs[i].n + 255) / 256, 256, 0, stream>>>(d_in[cvs[i].idx], F(cvs[i].off), cvs[i].n, flags);

  k_embed<<<4096, 256, 0, stream>>>((const int*)d_in[0], F(C_EMB), F(XA));
  // encoder convs via MFMA (im2col K=768)
  for (int i = 0; i < 3; ++i) {
    k_i2c3<<<4096, 256, 0, stream>>>(F(XA), U(XCOL3));
    k_trbp<<<dim3(12, 4), 256, 0, stream>>>(F(C_ECW) + (size_t)i * 196608, 256, U(ECWT), 768, 768, 256, 256);
    k_mf<0><<<dim3(64, 4), 256, 0, stream>>>(U(XCOL3), U(ECWT), nullptr, (void*)(ws + XB), 4096, 256, 768, 256);
    k_cs1<<<256, 256, 0, stream>>>(F(XB), 16, 256, F(PARTS));
    k_cs2<<<256, 256, 0, stream>>>(F(PARTS), 256, 4096, F(STATS));
    k_bnact<0><<<4096, 256, 0, stream>>>(F(XB), F(XA), F(STATS), F(C_EBS) + i * 256, F(C_EBO) + i * 256, 255, 1048576);
  }
  // encoder gate GEMMs via MFMA
  k_cvtb<<<4096, 256, 0, stream>>>(F(XA), U(XAB), 1048576);
  k_trbp<<<dim3(4, 16), 256, 0, stream>>>(F(C_LFW), 1024, U(WTE1), 256, 256, 1024, 1024);
  k_trbp<<<dim3(4, 16), 256, 0, stream>>>(F(C_LBW), 1024, U(WTE2), 256, 256, 1024, 1024);
  k_mf<3><<<dim3(64, 16), 256, 0, stream>>>(U(XAB), U(WTE1), F(C_LFB), (void*)(ws + GF), 4096, 1024, 256, 1024);
  k_mf<3><<<dim3(64, 16), 256, 0, stream>>>(U(XAB), U(WTE2), F(C_LBB), (void*)(ws + GB), 4096, 1024, 256, 1024);
  k_cumsum<<<1, 64, 0, stream>>>(F(C_DUR), F(MID));
  k_enc_lstm<<<128, 256, 0, stream>>>(F(GF), F(GB), F(C_LFW), F(C_LBW), F(ENC), U(ENCB),
                                      (const int*)d_in[1], cntE);
  k_upsample<<<512, 256, 0, stream>>>(F(MID), F(ENC), F(COND));

  // prenet via MFMA (K 80->96 padded, then 256)
  k_cvtbp<<<8192, 128, 0, stream>>>(F(C_MELS), U(MELB), 80, 96);
  k_trbp<<<dim3(2, 4), 256, 0, stream>>>(F(C_PW1), 256, U(PW1T), 80, 96, 256, 256);
  k_mf<0><<<dim3(128, 4), 256, 0, stream>>>(U(MELB), U(PW1T), nullptr, (void*)(ws + PREA), 8192, 256, 96, 256);
  k_cs1<<<256, 256, 0, stream>>>(F(PREA), 32, 256, F(PARTS));
  k_cs2<<<256, 256, 0, stream>>>(F(PARTS), 256, 8192, F(STATS));
  k_bnact<0><<<8192, 256, 0, stream>>>(F(PREA), F(PREB), F(STATS), F(C_P1S), F(C_P1O), 255, 2097152);
  k_cvtb<<<8192, 256, 0, stream>>>(F(PREB), U(PREBB), 2097152);
  k_trbp<<<dim3(4, 4), 256, 0, stream>>>(F(C_PW2), 256, U(PW2T), 256, 256, 256, 256);
  k_mf<0><<<dim3(128, 4), 256, 0, stream>>>(U(PREBB), U(PW2T), nullptr, (void*)(ws + PREA), 8192, 256, 256, 256);
  k_cs1<<<256, 256, 0, stream>>>(F(PREA), 32, 256, F(PARTS));
  k_cs2<<<256, 256, 0, stream>>>(F(PARTS), 256, 8192, F(STATS));
  k_bnact<0><<<8192, 256, 0, stream>>>(F(PREA), F(PREB), F(STATS), F(C_P2S), F(C_P2O), 255, 2097152);

  k_concat<<<24576, 256, 0, stream>>>(F(COND), F(PREB), U(DECIN));
  // decoder gate GEMMs via MFMA
  k_trbp<<<dim3(12, 32), 256, 0, stream>>>(F(C_DW1), 2048, U(WT1), 768, 768, 2048, 2048);
  k_trbp<<<dim3(12, 32), 256, 0, stream>>>(F(C_DW2), 2048, U(WT2), 768, 768, 2048, 2048);
  k_mf<2><<<dim3(128, 32), 256, 0, stream>>>(U(DECIN), U(WT1), F(C_DB1), (void*)(ws + D1X), 8192, 2048, 768, 2048);
  k_mf<2><<<dim3(128, 32), 256, 0, stream>>>(U(DECIN), U(WT2), F(C_DB2), (void*)(ws + D2X), 8192, 2048, 768, 2048);
  k_dec_lstm<<<128, 256, 0, stream>>>((const unsigned short*)(ws + D1X), (const unsigned short*)(ws + D2X),
                                      F(C_DW1), F(C_DW2), d_in[4], d_in[5], d_in[6], d_in[7],
                                      U(H1CB), U(H1NB), U(H2CB),
                                      F(H1N), F(H2N), cnt1, flags);
  // projection via MFMA (N 80->128 masked)
  k_cat3b<<<8192, 256, 0, stream>>>(F(COND), F(H1N), F(H2N), U(PROJA));
  k_trbp<<<dim3(24, 2), 256, 0, stream>>>(F(C_PRW), 80, U(PRWT), 1536, 1536, 80, 128);
  k_mf<4><<<dim3(128, 2), 256, 0, stream>>>(U(PROJA), U(PRWT), F(C_PRB), (void*)(ws + MELP), 8192, 128, 1536, 80);

  // postnet first conv via MFMA (im2col K=400->416)
  k_i2c80<<<8192, 256, 0, stream>>>(F(MELP), U(XCOL80));
  k_trbp<<<dim3(7, 8), 256, 0, stream>>>(F(C_W0), 512, U(W0T), 400, 416, 512, 512);
  k_mf<0><<<dim3(128, 8), 256, 0, stream>>>(U(XCOL80), U(W0T), nullptr, (void*)(ws + PA), 8192, 512, 416, 512);
  k_cs1<<<256, 256, 0, stream>>>(F(PA), 32, 512, F(PARTS));
  k_cs2<<<512, 256, 0, stream>>>(F(PARTS), 512, 8192, F(STATS));
  k_bnact<1><<<16384, 256, 0, stream>>>(F(PA), F(PB), F(STATS), F(C_PBS), F(C_PBO), 511, 4194304);
  for (int i = 0; i < 3; ++i) {
    k_i2c<<<8192, 256, 0, stream>>>(F(PB), U(XCOL));
    k_trbp<<<dim3(40, 8), 256, 0, stream>>>(F(C_WM) + (size_t)i * 1310720, 512, U(WTP), 2560, 2560, 512, 512);
    k_mf<0><<<dim3(128, 8), 256, 0, stream>>>(U(XCOL), U(WTP), nullptr, (void*)(ws + PA), 8192, 512, 2560, 512);
    k_cs1<<<256, 256, 0, stream>>>(F(PA), 32, 512, F(PARTS));
    k_cs2<<<512, 256, 0, stream>>>(F(PARTS), 512, 8192, F(STATS));
    k_bnact<1><<<16384, 256, 0, stream>>>(F(PA), F(PB), F(STATS), F(C_PBS) + (i + 1) * 512, F(C_PBO) + (i + 1) * 512, 511, 4194304);
  }
  // last conv via MFMA (N 80->128 masked)
  k_i2c<<<8192, 256, 0, stream>>>(F(PB), U(XCOL));
  k_trbp<<<dim3(40, 2), 256, 0, stream>>>(F(C_W4), 80, U(W4T), 2560, 2560, 80, 128);
  k_mf<4><<<dim3(128, 2), 256, 0, stream>>>(U(XCOL), U(W4T), F(C_B4), (void*)(ws + RESID), 8192, 128, 2560, 80);
  k_out<<<2560, 256, 0, stream>>>(F(MELP), F(RESID), d_out, flags);
}

// Round 11
// 4878.638 us; speedup vs baseline: 3.4751x; 1.0735x over previous
//
#include <hip/hip_runtime.h>

#define EPSV 1e-5f

typedef unsigned int uivec4 __attribute__((ext_vector_type(4)));
typedef short bh8 __attribute__((ext_vector_type(8)));
typedef float f32x4 __attribute__((ext_vector_type(4)));

__device__ __forceinline__ float b2f(unsigned short u) {
  unsigned int x = ((unsigned int)u) << 16;
  return __uint_as_float(x);
}
__device__ __forceinline__ unsigned short f2b(float f) {
  unsigned int x = __float_as_uint(f);
  unsigned int r = (x + 0x7FFFu + ((x >> 16) & 1u)) >> 16;
  return (unsigned short)r;
}
__device__ __forceinline__ float sigm(float x) { return 1.0f / (1.0f + expf(-x)); }

// ---- coherence-point (device-coherent) access: bypass L1+L2 both ways ----
__device__ __forceinline__ void stg_bf16(unsigned short* p, float v) {
  unsigned short h = f2b(v);
  asm volatile("global_store_short %0, %1, off sc0 sc1" ::"v"(p), "v"(h) : "memory");
}
__device__ __forceinline__ void ldg2_sc(const unsigned short* p0, const unsigned short* p1,
                                        uivec4& a, uivec4& b) {
  asm volatile(
      "global_load_dwordx4 %0, %2, off sc0 sc1\n\t"
      "global_load_dwordx4 %1, %3, off sc0 sc1\n\t"
      "s_waitcnt vmcnt(0)"
      : "=&v"(a), "=&v"(b)
      : "v"(p0), "v"(p1)
      : "memory");
}
// 4 x 16B from one pointer at byte offsets 0/256/512/768 (no wait)
__device__ __forceinline__ void ldg4f_nw(const unsigned short* p, uivec4& a, uivec4& b,
                                         uivec4& c, uivec4& d) {
  asm volatile(
      "global_load_dwordx4 %0, %4, off sc0 sc1\n\t"
      "global_load_dwordx4 %1, %4, off offset:256 sc0 sc1\n\t"
      "global_load_dwordx4 %2, %4, off offset:512 sc0 sc1\n\t"
      "global_load_dwordx4 %3, %4, off offset:768 sc0 sc1"
      : "=&v"(a), "=&v"(b), "=&v"(c), "=&v"(d)
      : "v"(p)
      : "memory");
}
__device__ __forceinline__ void vm0() { asm volatile("s_waitcnt vmcnt(0)" ::: "memory"); }
__device__ __forceinline__ unsigned int ldcnt(const unsigned int* p) {
  return __hip_atomic_load(p, __ATOMIC_RELAXED, __HIP_MEMORY_SCOPE_AGENT);
}

// ---------------- dtype detection ----------------
__global__ void k_detect(const void* __restrict__ embp, const void* __restrict__ zmp,
                         int* __restrict__ flags) {
  __shared__ int sh[4];
  int tid = threadIdx.x;
  if (tid < 4) sh[tid] = 0;
  __syncthreads();
  const unsigned short* u = (const unsigned short*)embp;
  int bad = 0;
  for (int i = tid; i < 4096; i += 256) {
    float f = fabsf(b2f(u[i]));
    if (!(f < 1e10f)) bad = 1;
  }
  if (bad) atomicAdd(&sh[3], 1);
  const unsigned char* p = (const unsigned char*)zmp;
  int codd = 0, c0 = 0, c1v = 0;
  for (int i = tid; i < 65536; i += 256) {
    unsigned char v = p[i];
    if (v) {
      if (i & 1) codd++;
      if ((i & 3) == 0) c0++;
      if (v == 1) c1v++;
    }
  }
  atomicAdd(&sh[0], codd); atomicAdd(&sh[1], c0); atomicAdd(&sh[2], c1v);
  __syncthreads();
  if (tid == 0) {
    flags[0] = sh[3] ? 1 : 0;
    int mode;
    if (sh[0] == 0) mode = 1;
    else if (sh[2] > 0) mode = 0;
    else if (sh[1] == 0) mode = 2;
    else mode = 3;
    flags[1] = mode;
  }
}

__global__ void k_cvt(const void* __restrict__ src, float* __restrict__ dst, int n,
                      const int* __restrict__ flags) {
  int i = blockIdx.x * 256 + threadIdx.x;
  if (i >= n) return;
  if (flags[0]) dst[i] = ((const float*)src)[i];
  else dst[i] = b2f(((const unsigned short*)src)[i]);
}

__global__ void k_cvtb(const float* __restrict__ src, unsigned short* __restrict__ dst, int n) {
  int i = blockIdx.x * 256 + threadIdx.x;
  if (i >= n) return;
  dst[i] = f2b(src[i]);
}

// cast row-wise with K -> Kpad zero padding
__global__ void k_cvtbp(const float* __restrict__ src, unsigned short* __restrict__ dst,
                        int K, int Kpad) {
  int r = blockIdx.x;
  int c = threadIdx.x;
  if (c < Kpad)
    dst[(size_t)r * Kpad + c] = (c < K) ? f2b(src[(size_t)r * K + c]) : (unsigned short)0;
}

__device__ __forceinline__ bool mask_at(const void* p, size_t i, int mode) {
  switch (mode) {
    case 0: return ((const unsigned char*)p)[i] != 0;
    case 1: return ((const int*)p)[i] != 0;
    case 2: return ((const float*)p)[i] != 0.0f;
    default: return ((const unsigned short*)p)[i] != 0;
  }
}

// ---------------- embedding (f32 + bf16 outputs) ----------------
__global__ void k_embed(const int* __restrict__ ph, const float* __restrict__ emb,
                        float* __restrict__ X, unsigned short* __restrict__ Xb) {
  int bl = blockIdx.x;
  int p = ph[bl];
  float v = emb[(size_t)p * 256 + threadIdx.x];
  X[(size_t)bl * 256 + threadIdx.x] = v;
  Xb[(size_t)bl * 256 + threadIdx.x] = f2b(v);
}

// ---------------- per-channel mean/var: 2-stage coalesced, deterministic ----------------
__global__ __launch_bounds__(256) void k_cs1(const float* __restrict__ X, int RB, int C,
                                             float* __restrict__ part) {
  int blk = blockIdx.x;
  int r0 = blk * RB;
  float s0 = 0.f, q0 = 0.f, s1 = 0.f, q1 = 0.f;
  for (int rr = 0; rr < RB; ++rr) {
    const float* row = X + (size_t)(r0 + rr) * C;
    float v = row[threadIdx.x];
    s0 += v; q0 += v * v;
    if (C > 256) {
      float v1 = row[256 + threadIdx.x];
      s1 += v1; q1 += v1 * v1;
    }
  }
  float* pr = part + (size_t)blk * 2 * C;
  pr[threadIdx.x] = s0;
  pr[C + threadIdx.x] = q0;
  if (C > 256) {
    pr[256 + threadIdx.x] = s1;
    pr[C + 256 + threadIdx.x] = q1;
  }
}
__global__ __launch_bounds__(256) void k_cs2(const float* __restrict__ part, int C, int R,
                                             float* __restrict__ st) {
  int c = blockIdx.x;
  int t = threadIdx.x;
  __shared__ float rs_[256], rq_[256];
  rs_[t] = part[(size_t)t * 2 * C + c];
  rq_[t] = part[(size_t)t * 2 * C + C + c];
  __syncthreads();
  for (int k = 128; k > 0; k >>= 1) {
    if (t < k) { rs_[t] += rs_[t + k]; rq_[t] += rq_[t + k]; }
    __syncthreads();
  }
  if (t == 0) {
    float m = rs_[0] / R;
    st[c] = m;
    st[C + c] = rq_[0] / R - m * m;
  }
}

template <int ACT>
__global__ void k_bnact(const float* __restrict__ X, float* __restrict__ Y,
                        unsigned short* __restrict__ Yb,
                        const float* __restrict__ st, const float* __restrict__ sc,
                        const float* __restrict__ of, int Cmask, int n) {
  int i = blockIdx.x * 256 + threadIdx.x;
  if (i >= n) return;
  int C = Cmask + 1;
  int c = i & Cmask;
  float m = st[c], v = st[C + c];
  float y = (X[i] - m) * rsqrtf(v + EPSV) * sc[c] + of[c];
  float r = ACT ? tanhf(y) : fmaxf(y, 0.0f);
  Y[i] = r;
  if (Yb) Yb[i] = f2b(r);
}

// ---------------- padded tiled transpose f32[K][ldn] -> bf16[Npad][Kpad] ----------------
__global__ __launch_bounds__(256) void k_trbp(const float* __restrict__ src, int ldn,
                                              unsigned short* __restrict__ dst,
                                              int K, int Kpad, int N, int Npad) {
  __shared__ float tl[64][65];
  int k0 = blockIdx.x * 64, n0 = blockIdx.y * 64;
  int tid = threadIdx.x;
#pragma unroll
  for (int p = 0; p < 16; ++p) {
    int idx = p * 256 + tid;
    int r = idx >> 6, c = idx & 63;
    float v = 0.0f;
    if (k0 + r < K && n0 + c < N) v = src[(size_t)(k0 + r) * ldn + n0 + c];
    tl[r][c] = v;
  }
  __syncthreads();
#pragma unroll
  for (int p = 0; p < 16; ++p) {
    int idx = p * 256 + tid;
    int rr = idx >> 6, cc = idx & 63;
    if (n0 + rr < Npad && k0 + cc < Kpad)
      dst[(size_t)(n0 + rr) * Kpad + k0 + cc] = f2b(tl[cc][rr]);
  }
}

// build proj A-matrix bf16 [8192][1536] = [cond | h1n | h2n]
__global__ __launch_bounds__(256) void k_cat3b(const float* __restrict__ cond,
                                               const float* __restrict__ h1n,
                                               const float* __restrict__ h2n,
                                               unsigned short* __restrict__ out) {
  int r = blockIdx.x;
  int b = r >> 9, t = r & 511;
#pragma unroll
  for (int p = 0; p < 6; ++p) {
    int col = p * 256 + threadIdx.x;
    float v;
    if (col < 512) v = cond[(size_t)r * 512 + col];
    else if (col < 1024) v = h1n[(size_t)(t * 16 + b) * 512 + (col - 512)];
    else v = h2n[(size_t)(t * 16 + b) * 512 + (col - 1024)];
    out[(size_t)r * 1536 + col] = f2b(v);
  }
}

// ---------------- MFMA GEMM: C[M,N] = A[M,K]bf16 @ Bt[N,K]bf16^T (+bias) ----------------
// OBF: 0 = f32 row-major (ldc=N), 2 = bf16 decoder-gate layout, 3 = f32 encoder-gate layout,
//      4 = f32 row-major with ldc=Nst and col guard n<Nst (padded-N)
template <int OBF>
__global__ __launch_bounds__(256) void k_mf(const unsigned short* __restrict__ A,
                                            const unsigned short* __restrict__ Bt,
                                            const float* __restrict__ bias,
                                            void* __restrict__ Cp, int M, int N, int K,
                                            int Nst) {
  const int lane = threadIdx.x & 63, wv = threadIdx.x >> 6;
  const int m0 = blockIdx.x * 64 + wv * 16;
  const int n0 = blockIdx.y * 64;
  const int koff = (lane >> 4) << 3;
  const unsigned short* arow = A + (size_t)(m0 + (lane & 15)) * K + koff;
  const unsigned short* brow0 = Bt + (size_t)(n0 + 0 * 16 + (lane & 15)) * K + koff;
  const unsigned short* brow1 = Bt + (size_t)(n0 + 1 * 16 + (lane & 15)) * K + koff;
  const unsigned short* brow2 = Bt + (size_t)(n0 + 2 * 16 + (lane & 15)) * K + koff;
  const unsigned short* brow3 = Bt + (size_t)(n0 + 3 * 16 + (lane & 15)) * K + koff;
  f32x4 acc0 = {0.f, 0.f, 0.f, 0.f}, acc1 = {0.f, 0.f, 0.f, 0.f};
  f32x4 acc2 = {0.f, 0.f, 0.f, 0.f}, acc3 = {0.f, 0.f, 0.f, 0.f};
  for (int k = 0; k < K; k += 32) {
    bh8 a = *(const bh8*)(arow + k);
    bh8 b0 = *(const bh8*)(brow0 + k);
    bh8 b1 = *(const bh8*)(brow1 + k);
    bh8 b2 = *(const bh8*)(brow2 + k);
    bh8 b3 = *(const bh8*)(brow3 + k);
    acc0 = __builtin_amdgcn_mfma_f32_16x16x32_bf16(a, b0, acc0, 0, 0, 0);
    acc1 = __builtin_amdgcn_mfma_f32_16x16x32_bf16(a, b1, acc1, 0, 0, 0);
    acc2 = __builtin_amdgcn_mfma_f32_16x16x32_bf16(a, b2, acc2, 0, 0, 0);
    acc3 = __builtin_amdgcn_mfma_f32_16x16x32_bf16(a, b3, acc3, 0, 0, 0);
  }
  const int r0 = m0 + ((lane >> 4) << 2);
  const int nl = lane & 15;
  float av[4][4];
#pragma unroll
  for (int r = 0; r < 4; ++r) { av[0][r] = acc0[r]; av[1][r] = acc1[r]; av[2][r] = acc2[r]; av[3][r] = acc3[r]; }
#pragma unroll
  for (int t = 0; t < 4; ++t) {
    int n = n0 + t * 16 + nl;
    float bv = 0.0f;
    if (bias) {
      if (OBF == 4) bv = (n < Nst) ? bias[n] : 0.0f;
      else bv = bias[n];
    }
#pragma unroll
    for (int r = 0; r < 4; ++r) {
      float v = av[t][r] + bv;
      int row = r0 + r;
      if (OBF == 0) {
        ((float*)Cp)[(size_t)row * N + n] = v;
      } else if (OBF == 4) {
        if (n < Nst) ((float*)Cp)[(size_t)row * Nst + n] = v;
      } else if (OBF == 2) {
        int b = row >> 9, tt = row & 511;
        int g = n >> 9, w = (n & 511) >> 2, jj = n & 3;
        ((unsigned short*)Cp)[((size_t)tt * 128 + w) * 256 + b * 16 + g * 4 + jj] = f2b(v);
      } else {
        int b = row >> 8, l = row & 255;
        int g = n >> 8, w = (n & 255) >> 2, jj = n & 3;
        ((float*)Cp)[((size_t)l * 64 + w) * 256 + b * 16 + g * 4 + jj] = v;
      }
    }
  }
}

// ---------------- MFMA conv GEMM with fused im2col A-operand ----------------
// X bf16 [B*TT][CIN]; A row = (b,t), col k = dt*CIN+ci -> X[b, t+dt-KW/2, ci] (0 outside)
template <int KW, int CIN, int TT, int OBF>
__global__ __launch_bounds__(256) void k_mfc(const unsigned short* __restrict__ Xb,
                                             const unsigned short* __restrict__ Bt,
                                             const float* __restrict__ bias,
                                             void* __restrict__ Cp, int M, int N, int K,
                                             int Nst) {
  const int lane = threadIdx.x & 63, wv = threadIdx.x >> 6;
  const int m0 = blockIdx.x * 64 + wv * 16;
  const int n0 = blockIdx.y * 64;
  const int koff = (lane >> 4) << 3;
  const int row = m0 + (lane & 15);
  const int bb = row / TT, t = row % TT;
  const unsigned short* brow0 = Bt + (size_t)(n0 + 0 * 16 + (lane & 15)) * K + koff;
  const unsigned short* brow1 = Bt + (size_t)(n0 + 1 * 16 + (lane & 15)) * K + koff;
  const unsigned short* brow2 = Bt + (size_t)(n0 + 2 * 16 + (lane & 15)) * K + koff;
  const unsigned short* brow3 = Bt + (size_t)(n0 + 3 * 16 + (lane & 15)) * K + koff;
  f32x4 acc0 = {0.f, 0.f, 0.f, 0.f}, acc1 = {0.f, 0.f, 0.f, 0.f};
  f32x4 acc2 = {0.f, 0.f, 0.f, 0.f}, acc3 = {0.f, 0.f, 0.f, 0.f};
  for (int k = 0; k < K; k += 32) {
    int ke = k + koff;
    int dt = ke / CIN;
    int ci = ke - dt * CIN;
    int tt = t + dt - (KW / 2);
    bh8 a = {0, 0, 0, 0, 0, 0, 0, 0};
    if (dt < KW && tt >= 0 && tt < TT)
      a = *(const bh8*)&Xb[((size_t)(bb * TT + tt)) * CIN + ci];
    bh8 b0 = *(const bh8*)(brow0 + k);
    bh8 b1 = *(const bh8*)(brow1 + k);
    bh8 b2 = *(const bh8*)(brow2 + k);
    bh8 b3 = *(const bh8*)(brow3 + k);
    acc0 = __builtin_amdgcn_mfma_f32_16x16x32_bf16(a, b0, acc0, 0, 0, 0);
    acc1 = __builtin_amdgcn_mfma_f32_16x16x32_bf16(a, b1, acc1, 0, 0, 0);
    acc2 = __builtin_amdgcn_mfma_f32_16x16x32_bf16(a, b2, acc2, 0, 0, 0);
    acc3 = __builtin_amdgcn_mfma_f32_16x16x32_bf16(a, b3, acc3, 0, 0, 0);
  }
  const int r0 = m0 + ((lane >> 4) << 2);
  const int nl = lane & 15;
  float av[4][4];
#pragma unroll
  for (int r = 0; r < 4; ++r) { av[0][r] = acc0[r]; av[1][r] = acc1[r]; av[2][r] = acc2[r]; av[3][r] = acc3[r]; }
#pragma unroll
  for (int tq = 0; tq < 4; ++tq) {
    int n = n0 + tq * 16 + nl;
    float bv = 0.0f;
    if (bias) {
      if (OBF == 4) bv = (n < Nst) ? bias[n] : 0.0f;
      else bv = bias[n];
    }
#pragma unroll
    for (int r = 0; r < 4; ++r) {
      float v = av[tq][r] + bv;
      int rw = r0 + r;
      if (OBF == 0) {
        ((float*)Cp)[(size_t)rw * N + n] = v;
      } else if (OBF == 4) {
        if (n < Nst) ((float*)Cp)[(size_t)rw * Nst + n] = v;
      }
    }
  }
}

// ---------------- duration cumsum ----------------
__global__ void k_cumsum(const float* __restrict__ dur, float* __restrict__ mid) {
  int b = threadIdx.x;
  if (b >= 16) return;
  float run = 0.f;
  for (int l = 0; l < 256; ++l) {
    float d = dur[b * 256 + l];
    run += d;
    mid[b * 256 + l] = run - 0.5f * d;
  }
}

// ---------------- persistent bi-LSTM encoder (64 WGs; 8 cols/WG; MFMA dot) ----------------
#define EST 130  // u32 stride per batch row (260 bf16)
__global__ __launch_bounds__(256) void k_enc_lstm(const float* __restrict__ GFp,
                                                  const float* __restrict__ GBp,
                                                  const float* __restrict__ Wf,
                                                  const float* __restrict__ Wb,
                                                  float* __restrict__ enc,
                                                  unsigned short* __restrict__ encB,
                                                  const int* __restrict__ lengths,
                                                  unsigned int* __restrict__ cnt) {
  const int tid = threadIdx.x;
  const int wg = blockIdx.x;
  const int dir = wg >> 5;
  const int w = wg & 31;  // owns cols 8w..8w+8 of 256
  const float* Gpre = dir ? GBp : GFp;
  const float* W = dir ? Wb : Wf;
  unsigned int* c_self = cnt + (size_t)dir * 256 * 128;

  __shared__ __align__(16) unsigned int hsW[16 * EST];
  __shared__ __align__(16) float accb[8 * 264];
  __shared__ __align__(16) float gl[16 * 33];
  __shared__ float cst[128];
  __shared__ int rs[16];

  const int lane = tid & 63, wv = tid >> 6;
  const int n16 = lane & 15, lq = lane >> 4;

  // B frags: subtile s in {0,1}; gate col n = s*16+n16 -> g=n>>3, jn=n&7
  bh8 BE[2][2];
#pragma unroll
  for (int s = 0; s < 2; ++s) {
    int n = s * 16 + n16;
    int colg = (n >> 3) * 256 + w * 8 + (n & 7);
#pragma unroll
    for (int c = 0; c < 2; ++c)
#pragma unroll
      for (int j = 0; j < 8; ++j) {
        int k = wv * 64 + c * 32 + lq * 8 + j;
        BE[c][s][j] = (short)f2b(W[(size_t)(256 + k) * 1024 + colg]);
      }
  }
  if (tid < 128) cst[tid] = 0.0f;
  __syncthreads();

  for (int t = 0; t < 256; ++t) {
    const int l = dir ? (255 - t) : t;
    if (tid < 16) rs[tid] = (dir == 1) && (l >= lengths[tid] - 1);
    // prefetch 2 precomputed gate values per thread
    float gp[2];
#pragma unroll
    for (int it = 0; it < 2; ++it) {
      int e = tid + it * 256;
      int b = e >> 5, n = e & 31;
      int jn = n & 7, g = n >> 3;
      int slot = w * 2 + (jn >> 2);
      gp[it] = Gpre[((size_t)l * 64 + slot) * 256 + b * 16 + g * 4 + (jn & 3)];
    }
    if (t > 0 && tid < 8) {
      const unsigned int* a = c_self + (size_t)(t - 1) * 128 + tid * 16;
      unsigned int gcount = 0;
      while (ldcnt(a) < 4u) {
        __builtin_amdgcn_s_sleep(2);
        if (++gcount > (1u << 16)) break;
      }
    }
    __syncthreads();
    if (t > 0) {
      const int lprev = dir ? (l + 1) : (l - 1);
      int b = tid >> 4, q = tid & 15;
      const unsigned short* p = encB + ((size_t)dir << 20) + (((size_t)lprev * 16 + b) << 8) + q * 16;
      uivec4 a0, a1;
      ldg2_sc(p, p + 8, a0, a1);
      if (rs[b]) {
        a0.x = a0.y = a0.z = a0.w = 0u;
        a1.x = a1.y = a1.z = a1.w = 0u;
      }
      *(uivec4*)&hsW[b * EST + q * 8] = a0;
      *(uivec4*)&hsW[b * EST + q * 8 + 4] = a1;
    }
    __syncthreads();

    f32x4 ac[2] = {{0.f, 0.f, 0.f, 0.f}, {0.f, 0.f, 0.f, 0.f}};
    if (t > 0) {
#pragma unroll
      for (int c = 0; c < 2; ++c) {
        int kw = wv * 32 + c * 16 + lq * 4;
        bh8 af = *(const bh8*)&hsW[(lane & 15) * EST + kw];
        ac[0] = __builtin_amdgcn_mfma_f32_16x16x32_bf16(af, BE[c][0], ac[0], 0, 0, 0);
        ac[1] = __builtin_amdgcn_mfma_f32_16x16x32_bf16(af, BE[c][1], ac[1], 0, 0, 0);
      }
    }
    {
      int idx = (lq * 4) * 16 + n16;
#pragma unroll
      for (int s = 0; s < 2; ++s) {
        float* pb = &accb[(s * 4 + wv) * 264];
#pragma unroll
        for (int r = 0; r < 4; ++r) pb[idx + r * 16] = ac[s][r];
      }
    }
    __syncthreads();
#pragma unroll
    for (int it = 0; it < 2; ++it) {
      int e = tid + it * 256;
      int b = e >> 5, n = e & 31;
      int s = n >> 4, nn = n & 15;
      float sum = gp[it];
      if (t > 0) {
#pragma unroll
        for (int v = 0; v < 4; ++v) sum += accb[(s * 4 + v) * 264 + b * 16 + nn];
      }
      gl[b * 33 + n] = sum;
    }
    __syncthreads();
    if (tid < 128) {
      int b = tid >> 3, jn = tid & 7;
      float gi = gl[b * 33 + 0 * 8 + jn];
      float gg = gl[b * 33 + 1 * 8 + jn];
      float gf = gl[b * 33 + 2 * 8 + jn];
      float go = gl[b * 33 + 3 * 8 + jn];
      float c = cst[tid];
      if (t == 0 || rs[b]) c = 0.0f;
      c = sigm(gf + 1.0f) * c + sigm(gi) * tanhf(gg);
      float h = sigm(go) * tanhf(c);
      cst[tid] = c;
      int col = w * 8 + jn;
      enc[(size_t)(b * 256 + l) * 512 + dir * 256 + col] = h;
      stg_bf16(&encB[((size_t)dir << 20) + (((size_t)l * 16 + b) << 8) + col], h);
    }
    vm0();
    __syncthreads();
    if (tid == 0)
      __hip_atomic_fetch_add(c_self + (size_t)t * 128 + (w >> 2) * 16, 1u,
                             __ATOMIC_RELAXED, __HIP_MEMORY_SCOPE_AGENT);
  }
}

// ---------------- Gaussian-softmax upsampling ----------------
__global__ __launch_bounds__(256) void k_upsample(const float* __restrict__ mid,
                                                  const float* __restrict__ enc,
                                                  float* __restrict__ cond) {
  int blk = blockIdx.x;
  int b = blk >> 5, t0 = (blk & 31) * 16;
  int tid = threadIdx.x;
  __shared__ float wls[16][256];
  __shared__ float red[256];
  float mp = mid[b * 256 + tid];
  for (int tt = 0; tt < 16; ++tt) {
    float tpos = (float)(t0 + tt);
    float d = mp - tpos;
    float d2 = d * d * 0.1f;
    red[tid] = d2; __syncthreads();
    for (int k = 128; k > 0; k >>= 1) { if (tid < k) red[tid] = fminf(red[tid], red[tid + k]); __syncthreads(); }
    float mn = red[0]; __syncthreads();
    float e = expf(mn - d2);
    red[tid] = e; __syncthreads();
    for (int k = 128; k > 0; k >>= 1) { if (tid < k) red[tid] += red[tid + k]; __syncthreads(); }
    float sum = red[0]; __syncthreads();
    wls[tt][tid] = e / sum;
  }
  __syncthreads();
  float a0[16], a1[16];
#pragma unroll
  for (int i = 0; i < 16; ++i) { a0[i] = 0; a1[i] = 0; }
  for (int l = 0; l < 256; ++l) {
    float e0 = enc[(size_t)(b * 256 + l) * 512 + tid];
    float e1 = enc[(size_t)(b * 256 + l) * 512 + 256 + tid];
#pragma unroll
    for (int tt = 0; tt < 16; ++tt) { float wv = wls[tt][l]; a0[tt] += wv * e0; a1[tt] += wv * e1; }
  }
  for (int tt = 0; tt < 16; ++tt) {
    cond[(size_t)(b * 512 + t0 + tt) * 512 + tid] = a0[tt];
    cond[(size_t)(b * 512 + t0 + tt) * 512 + 256 + tid] = a1[tt];
  }
}

// concat -> bf16 decoder input A-matrix [8192][768]
__global__ void k_concat(const float* __restrict__ cond, const float* __restrict__ p,
                         unsigned short* __restrict__ din) {
  size_t i = (size_t)blockIdx.x * 256 + threadIdx.x;
  int r = (int)(i / 768);
  int c = (int)(i % 768);
  float v = (c < 512) ? cond[(size_t)r * 512 + c] : p[(size_t)r * 256 + (c - 512)];
  din[i] = f2b(v);
}

// ---------------- merged 2-layer zoneout LSTM decoder (64 WGs; 8 cols/WG) ----------------
#define DST 780  // u32 stride per batch row (h1c|h1n|h2c + pad)
__global__ __launch_bounds__(256) void k_dec_lstm(
    const unsigned short* __restrict__ D1x, const unsigned short* __restrict__ D2x,
    const float* __restrict__ W1, const float* __restrict__ W2,
    const void* __restrict__ zh1, const void* __restrict__ zc1,
    const void* __restrict__ zh2, const void* __restrict__ zc2,
    unsigned short* __restrict__ h1cB, unsigned short* __restrict__ h1nB,
    unsigned short* __restrict__ h2cB,
    float* __restrict__ h1n, float* __restrict__ h2n,
    unsigned int* __restrict__ cnt1,
    const int* __restrict__ flags) {
  const int tid = threadIdx.x;
  const int w = blockIdx.x;  // 0..63, owns cols 8w..8w+8 of both layers

  __shared__ __align__(16) unsigned int hsW[16 * DST];
  __shared__ __align__(16) float accb1[8 * 264];
  __shared__ __align__(16) float accb2[8 * 264];
  __shared__ __align__(16) float gl1[16 * 33], gl2[16 * 33];
  __shared__ float cst1[128], hst1[128], cst2[128], hst2[128];

  const int mmode = flags[1];
  const int lane = tid & 63, wv = tid >> 6;
  const int n16 = lane & 15, lq = lane >> 4;

  // B frags: n = s*16+n16 -> g=n>>3, jn=n&7; col = g*512 + 8w + jn
  bh8 B1[4][2], B2[8][2];
#pragma unroll
  for (int s = 0; s < 2; ++s) {
    int n = s * 16 + n16;
    int colg = (n >> 3) * 512 + w * 8 + (n & 7);
#pragma unroll
    for (int c = 0; c < 4; ++c)
#pragma unroll
      for (int j = 0; j < 8; ++j) {
        int k = wv * 128 + c * 32 + lq * 8 + j;
        B1[c][s][j] = (short)f2b(W1[(size_t)(768 + k) * 2048 + colg]);
      }
#pragma unroll
    for (int c = 0; c < 8; ++c)
#pragma unroll
      for (int j = 0; j < 8; ++j) {
        int k = wv * 256 + c * 32 + lq * 8 + j;
        B2[c][s][j] = (short)f2b(W2[(size_t)(768 + k) * 2048 + colg]);
      }
  }
  if (tid < 128) { cst1[tid] = 0; hst1[tid] = 0; cst2[tid] = 0; hst2[tid] = 0; }
  __syncthreads();

  for (int tau = 0; tau <= 512; ++tau) {
    // prefetch gate values: 2 per layer per thread
    float dx1[2] = {0.f, 0.f}, dx2[2] = {0.f, 0.f};
    if (tau < 512) {
#pragma unroll
      for (int it = 0; it < 2; ++it) {
        int e = tid + it * 256;
        int b = e >> 5, n = e & 31;
        int jn = n & 7, g = n >> 3;
        int slot = w * 2 + (jn >> 2);
        dx1[it] = b2f(D1x[((size_t)tau * 128 + slot) * 256 + b * 16 + g * 4 + (jn & 3)]);
      }
    }
    if (tau >= 1) {
#pragma unroll
      for (int it = 0; it < 2; ++it) {
        int e = tid + it * 256;
        int b = e >> 5, n = e & 31;
        int jn = n & 7, g = n >> 3;
        int slot = w * 2 + (jn >> 2);
        dx2[it] = b2f(D2x[((size_t)(tau - 1) * 128 + slot) * 256 + b * 16 + g * 4 + (jn & 3)]);
      }
    }
    if (tau >= 1 && tid < 8) {
      const unsigned int* a = cnt1 + (size_t)(tau - 1) * 128 + tid * 16;
      unsigned int gcount = 0;
      while (ldcnt(a) < 8u) {
        __builtin_amdgcn_s_sleep(2);
        if (++gcount > (1u << 16)) break;
      }
    }
    __syncthreads();

    if (tau >= 1) {
      int b = tid >> 4, q = tid & 15;
      const unsigned short* p0 = h1cB + (((size_t)(tau - 1) * 16 + b) << 9) + q * 8;
      const unsigned short* p1 = h1nB + (((size_t)(tau - 1) * 16 + b) << 9) + q * 8;
      uivec4 r[12];
      ldg4f_nw(p0, r[0], r[1], r[2], r[3]);
      ldg4f_nw(p1, r[4], r[5], r[6], r[7]);
      if (tau >= 2) {
        const unsigned short* p2 = h2cB + (((size_t)(tau - 2) * 16 + b) << 9) + q * 8;
        ldg4f_nw(p2, r[8], r[9], r[10], r[11]);
      } else {
        uivec4 z; z.x = z.y = z.z = z.w = 0u;
        r[8] = z; r[9] = z; r[10] = z; r[11] = z;
      }
      vm0();
      unsigned int base = b * DST + q * 4;
#pragma unroll
      for (int m = 0; m < 4; ++m) *(uivec4*)&hsW[base + 64 * m] = r[m];
#pragma unroll
      for (int m = 0; m < 4; ++m) *(uivec4*)&hsW[base + 256 + 64 * m] = r[4 + m];
#pragma unroll
      for (int m = 0; m < 4; ++m) *(uivec4*)&hsW[base + 512 + 64 * m] = r[8 + m];
    }
    __syncthreads();

    f32x4 a1[2] = {{0.f, 0.f, 0.f, 0.f}, {0.f, 0.f, 0.f, 0.f}};
    f32x4 a2[2] = {{0.f, 0.f, 0.f, 0.f}, {0.f, 0.f, 0.f, 0.f}};
    if (tau >= 1) {
      if (tau < 512) {
#pragma unroll
        for (int c = 0; c < 4; ++c) {
          int kw = wv * 64 + c * 16 + lq * 4;
          bh8 af = *(const bh8*)&hsW[(lane & 15) * DST + kw];
          a1[0] = __builtin_amdgcn_mfma_f32_16x16x32_bf16(af, B1[c][0], a1[0], 0, 0, 0);
          a1[1] = __builtin_amdgcn_mfma_f32_16x16x32_bf16(af, B1[c][1], a1[1], 0, 0, 0);
        }
      }
#pragma unroll
      for (int c = 0; c < 8; ++c) {
        int kw = 256 + wv * 128 + c * 16 + lq * 4;
        bh8 af = *(const bh8*)&hsW[(lane & 15) * DST + kw];
        a2[0] = __builtin_amdgcn_mfma_f32_16x16x32_bf16(af, B2[c][0], a2[0], 0, 0, 0);
        a2[1] = __builtin_amdgcn_mfma_f32_16x16x32_bf16(af, B2[c][1], a2[1], 0, 0, 0);
      }
    }
    {
      int idx = (lq * 4) * 16 + n16;
#pragma unroll
      for (int s = 0; s < 2; ++s) {
        float* p1b = &accb1[(s * 4 + wv) * 264];
        float* p2b = &accb2[(s * 4 + wv) * 264];
#pragma unroll
        for (int r = 0; r < 4; ++r) { p1b[idx + r * 16] = a1[s][r]; p2b[idx + r * 16] = a2[s][r]; }
      }
    }
    __syncthreads();
#pragma unroll
    for (int it = 0; it < 2; ++it) {
      int e = tid + it * 256;
      int b = e >> 5, n = e & 31;
      int s = n >> 4, nn = n & 15;
      int off = b * 16 + nn;
      float s1 = dx1[it], s2 = dx2[it];
      if (tau >= 1) {
        if (tau < 512) {
#pragma unroll
          for (int v = 0; v < 4; ++v) s1 += accb1[(s * 4 + v) * 264 + off];
        }
#pragma unroll
        for (int v = 0; v < 4; ++v) s2 += accb2[(s * 4 + v) * 264 + off];
      }
      gl1[b * 33 + n] = s1;
      gl2[b * 33 + n] = s2;
    }
    __syncthreads();

    if (tid < 128) {
      if (tau < 512) {
        int b = tid >> 3, jn = tid & 7, colgw = w * 8 + jn;
        float gi = gl1[b * 33 + 0 * 8 + jn];
        float gg = gl1[b * 33 + 1 * 8 + jn];
        float gf = gl1[b * 33 + 2 * 8 + jn];
        float go = gl1[b * 33 + 3 * 8 + jn];
        float cold = (tau == 0) ? 0.0f : cst1[tid];
        float hold = (tau == 0) ? 0.0f : hst1[tid];
        float nc = sigm(gf + 1.0f) * cold + sigm(gi) * tanhf(gg);
        float nh = sigm(go) * tanhf(nc);
        size_t mi = ((size_t)b * 512 + tau) * 512 + colgw;
        bool mh = mask_at(zh1, mi, mmode);
        bool mc = mask_at(zc1, mi, mmode);
        cst1[tid] = mc ? cold : nc;
        float hkeep = mh ? hold : nh;
        hst1[tid] = hkeep;
        h1n[(size_t)(tau * 16 + b) * 512 + colgw] = nh;
        stg_bf16(&h1cB[(((size_t)tau * 16 + b) << 9) + colgw], hkeep);
        stg_bf16(&h1nB[(((size_t)tau * 16 + b) << 9) + colgw], nh);
      }
    } else {
      if (tau >= 1) {
        int u = tid - 128;
        int t2 = tau - 1;
        int b = u >> 3, jn = u & 7, colgw = w * 8 + jn;
        float gi = gl2[b * 33 + 0 * 8 + jn];
        float gg = gl2[b * 33 + 1 * 8 + jn];
        float gf = gl2[b * 33 + 2 * 8 + jn];
        float go = gl2[b * 33 + 3 * 8 + jn];
        float cold = (tau == 1) ? 0.0f : cst2[u];
        float hold = (tau == 1) ? 0.0f : hst2[u];
        float nc = sigm(gf + 1.0f) * cold + sigm(gi) * tanhf(gg);
        float nh = sigm(go) * tanhf(nc);
        size_t mi = ((size_t)b * 512 + t2) * 512 + colgw;
        bool mh = mask_at(zh2, mi, mmode);
        bool mc = mask_at(zc2, mi, mmode);
        cst2[u] = mc ? cold : nc;
        float hkeep = mh ? hold : nh;
        hst2[u] = hkeep;
        h2n[(size_t)(t2 * 16 + b) * 512 + colgw] = nh;
        stg_bf16(&h2cB[(((size_t)t2 * 16 + b) << 9) + colgw], hkeep);
      }
    }
    vm0();
    __syncthreads();
    if (tid == 0)
      __hip_atomic_fetch_add(cnt1 + (size_t)tau * 128 + (w >> 3) * 16, 1u,
                             __ATOMIC_RELAXED, __HIP_MEMORY_SCOPE_AGENT);
  }
}

__global__ void k_out(const float* __restrict__ mel, const float* __restrict__ res,
                      void* __restrict__ out, const int* __restrict__ flags) {
  int i = blockIdx.x * 256 + threadIdx.x;
  float m = mel[i];
  float f = m + res[i];
  if (flags[0]) {
    ((float*)out)[i] = m;
    ((float*)out)[655360 + i] = f;
  } else {
    unsigned short* o = (unsigned short*)out;
    o[i] = f2b(m);
    o[655360 + i] = f2b(f);
  }
}

// ---------------- host launch ----------------
extern "C" void kernel_launch(void* const* d_in, const int* in_sizes, int n_in,
                              void* d_out, int out_size, void* d_ws, size_t ws_size,
                              hipStream_t stream) {
  char* ws = (char*)d_ws;
  size_t o = 0;
  auto A_ = [&](size_t nb) { size_t r = o; o += (nb + 255) & ~(size_t)255; return r; };
  const size_t FLAGS = A_(256);
  const size_t SYNC = A_(786432);
  const size_t STATS = A_(4096);
  const size_t PARTS = A_(1048576 + 4096);
  const size_t XAB = A_(2097152);
  const size_t WTE1 = A_(524288), WTE2 = A_(524288);
  const size_t C_MELS = A_(655360ull * 4), C_DUR = A_(4096 * 4), C_EMB = A_(65536 * 4),
               C_ECW = A_(589824ull * 4), C_EBS = A_(768 * 4), C_EBO = A_(768 * 4),
               C_LFW = A_(524288ull * 4), C_LFB = A_(1024 * 4), C_LBW = A_(524288ull * 4),
               C_LBB = A_(1024 * 4), C_PW1 = A_(20480 * 4), C_P1S = A_(256 * 4),
               C_P1O = A_(256 * 4), C_PW2 = A_(65536 * 4), C_P2S = A_(256 * 4),
               C_P2O = A_(256 * 4), C_DW1 = A_(2621440ull * 4), C_DB1 = A_(2048 * 4),
               C_DW2 = A_(3670016ull * 4), C_DB2 = A_(2048 * 4), C_PRW = A_(122880ull * 4),
               C_PRB = A_(512), C_W0 = A_(204800ull * 4), C_WM = A_(3932160ull * 4),
               C_W4 = A_(204800ull * 4), C_B4 = A_(512), C_PBS = A_(2048 * 4),
               C_PBO = A_(2048 * 4);
  const size_t R1 = A_(16777216), R2 = A_(16777216), R3 = A_(16777216), R4 = A_(16777216),
               MID = A_(4096 * 4), R5 = A_(16777216), R6 = A_(16777216), R7 = A_(25165824),
               D1X = A_(33554432), D2X = A_(33554432), MELP = A_(2621440);
  const size_t XA = R1, XB = R1 + 4194304;
  const size_t ECWT = R3;
  const size_t GF = R2;
  const size_t GB = R3, H1N = R3;
  const size_t ENC = R4, H2N = R4;
  const size_t COND = R5, PA = R5;
  const size_t PREA = R6, PREB = R6 + 8388608, PB = R6;
  const size_t PBB = R3;  // postnet bf16 activations (R3 free after projection)
  const size_t DECIN = R7, RESID = R7;
  const size_t H1CB = R1, H1NB = R1 + 8388608;
  const size_t H2CB = R2;
  const size_t ENCB = R7;
  const size_t MELB = R1, PW1T = R1 + 2097152, PREBB = R1, PW2T = R1 + 8388608;
  const size_t WT1 = R4, WT2 = R4 + 4194304;
  const size_t PROJA = R1;  // spans R1..R2 (25MB)
  const size_t PRWT = R6;
  const size_t MELPB = R1, W0T = R2;
  const size_t WTP = D1X, W4T = D2X;

  auto F = [&](size_t off) { return (float*)(ws + off); };
  auto U = [&](size_t off) { return (unsigned short*)(ws + off); };
  int* flags = (int*)(ws + FLAGS);
  unsigned int* cntE = (unsigned int*)(ws + SYNC);
  unsigned int* cnt1 = (unsigned int*)(ws + SYNC + 262144);

  hipMemsetAsync(ws + SYNC, 0, 786432, stream);
  k_detect<<<1, 256, 0, stream>>>(d_in[8], d_in[4], flags);

  struct CV { int idx; size_t off; int n; };
  const CV cvs[] = {
      {2, C_MELS, 655360}, {3, C_DUR, 4096}, {8, C_EMB, 65536}, {9, C_ECW, 589824},
      {10, C_EBS, 768}, {11, C_EBO, 768}, {12, C_LFW, 524288}, {13, C_LFB, 1024},
      {14, C_LBW, 524288}, {15, C_LBB, 1024}, {16, C_PW1, 20480}, {17, C_P1S, 256},
      {18, C_P1O, 256}, {19, C_PW2, 65536}, {20, C_P2S, 256}, {21, C_P2O, 256},
      {22, C_DW1, 2621440}, {23, C_DB1, 2048}, {24, C_DW2, 3670016}, {25, C_DB2, 2048},
      {26, C_PRW, 122880}, {27, C_PRB, 80}, {28, C_W0, 204800}, {29, C_WM, 3932160},
      {30, C_W4, 204800}, {31, C_B4, 80}, {32, C_PBS, 2048}, {33, C_PBO, 2048}};
  for (int i = 0; i < (int)(sizeof(cvs) / sizeof(cvs[0])); ++i)
    k_cvt<<<(cvs[i].n + 255) / 256, 256, 0, stream>>>(d_in[cvs[i].idx], F(cvs[i].off), cvs[i].n, flags);

  k_embed<<<4096, 256, 0, stream>>>((const int*)d_in[0], F(C_EMB), F(XA), U(XAB));
  // encoder convs: fused-im2col MFMA (K=768)
  for (int i = 0; i < 3; ++i) {
    k_trbp<<<dim3(12, 4), 256, 0, stream>>>(F(C_ECW) + (size_t)i * 196608, 256, U(ECWT), 768, 768, 256, 256);
    k_mfc<3, 256, 256, 0><<<dim3(64, 4), 256, 0, stream>>>(U(XAB), U(ECWT), nullptr, (void*)(ws + XB), 4096, 256, 768, 256);
    k_cs1<<<256, 256, 0, stream>>>(F(XB), 16, 256, F(PARTS));
    k_cs2<<<256, 256, 0, stream>>>(F(PARTS), 256, 4096, F(STATS));
    k_bnact<0><<<4096, 256, 0, stream>>>(F(XB), F(XA), U(XAB), F(STATS), F(C_EBS) + i * 256, F(C_EBO) + i * 256, 255, 1048576);
  }
  // encoder gate GEMMs via MFMA
  k_trbp<<<dim3(4, 16), 256, 0, stream>>>(F(C_LFW), 1024, U(WTE1), 256, 256, 1024, 1024);
  k_trbp<<<dim3(4, 16), 256, 0, stream>>>(F(C_LBW), 1024, U(WTE2), 256, 256, 1024, 1024);
  k_mf<3><<<dim3(64, 16), 256, 0, stream>>>(U(XAB), U(WTE1), F(C_LFB), (void*)(ws + GF), 4096, 1024, 256, 1024);
  k_mf<3><<<dim3(64, 16), 256, 0, stream>>>(U(XAB), U(WTE2), F(C_LBB), (void*)(ws + GB), 4096, 1024, 256, 1024);
  k_cumsum<<<1, 64, 0, stream>>>(F(C_DUR), F(MID));
  k_enc_lstm<<<64, 256, 0, stream>>>(F(GF), F(GB), F(C_LFW), F(C_LBW), F(ENC), U(ENCB),
                                     (const int*)d_in[1], cntE);
  k_upsample<<<512, 256, 0, stream>>>(F(MID), F(ENC), F(COND));

  // prenet via MFMA (K 80->96 padded, then 256)
  k_cvtbp<<<8192, 128, 0, stream>>>(F(C_MELS), U(MELB), 80, 96);
  k_trbp<<<dim3(2, 4), 256, 0, stream>>>(F(C_PW1), 256, U(PW1T), 80, 96, 256, 256);
  k_mf<0><<<dim3(128, 4), 256, 0, stream>>>(U(MELB), U(PW1T), nullptr, (void*)(ws + PREA), 8192, 256, 96, 256);
  k_cs1<<<256, 256, 0, stream>>>(F(PREA), 32, 256, F(PARTS));
  k_cs2<<<256, 256, 0, stream>>>(F(PARTS), 256, 8192, F(STATS));
  k_bnact<0><<<8192, 256, 0, stream>>>(F(PREA), F(PREB), nullptr, F(STATS), F(C_P1S), F(C_P1O), 255, 2097152);
  k_cvtb<<<8192, 256, 0, stream>>>(F(PREB), U(PREBB), 2097152);
  k_trbp<<<dim3(4, 4), 256, 0, stream>>>(F(C_PW2), 256, U(PW2T), 256, 256, 256, 256);
  k_mf<0><<<dim3(128, 4), 256, 0, stream>>>(U(PREBB), U(PW2T), nullptr, (void*)(ws + PREA), 8192, 256, 256, 256);
  k_cs1<<<256, 256, 0, stream>>>(F(PREA), 32, 256, F(PARTS));
  k_cs2<<<256, 256, 0, stream>>>(F(PARTS), 256, 8192, F(STATS));
  k_bnact<0><<<8192, 256, 0, stream>>>(F(PREA), F(PREB), nullptr, F(STATS), F(C_P2S), F(C_P2O), 255, 2097152);

  k_concat<<<24576, 256, 0, stream>>>(F(COND), F(PREB), U(DECIN));
  // decoder gate GEMMs via MFMA
  k_trbp<<<dim3(12, 32), 256, 0, stream>>>(F(C_DW1), 2048, U(WT1), 768, 768, 2048, 2048);
  k_trbp<<<dim3(12, 32), 256, 0, stream>>>(F(C_DW2), 2048, U(WT2), 768, 768, 2048, 2048);
  k_mf<2><<<dim3(128, 32), 256, 0, stream>>>(U(DECIN), U(WT1), F(C_DB1), (void*)(ws + D1X), 8192, 2048, 768, 2048);
  k_mf<2><<<dim3(128, 32), 256, 0, stream>>>(U(DECIN), U(WT2), F(C_DB2), (void*)(ws + D2X), 8192, 2048, 768, 2048);
  k_dec_lstm<<<64, 256, 0, stream>>>((const unsigned short*)(ws + D1X), (const unsigned short*)(ws + D2X),
                                     F(C_DW1), F(C_DW2), d_in[4], d_in[5], d_in[6], d_in[7],
                                     U(H1CB), U(H1NB), U(H2CB),
                                     F(H1N), F(H2N), cnt1, flags);
  // projection via MFMA (N 80->128 masked)
  k_cat3b<<<8192, 256, 0, stream>>>(F(COND), F(H1N), F(H2N), U(PROJA));
  k_trbp<<<dim3(24, 2), 256, 0, stream>>>(F(C_PRW), 80, U(PRWT), 1536, 1536, 80, 128);
  k_mf<4><<<dim3(128, 2), 256, 0, stream>>>(U(PROJA), U(PRWT), F(C_PRB), (void*)(ws + MELP), 8192, 128, 1536, 80);

  // postnet first conv: fused-im2col MFMA (Cin=80, K=416 padded)
  k_cvtb<<<2560, 256, 0, stream>>>(F(MELP), U(MELPB), 655360);
  k_trbp<<<dim3(7, 8), 256, 0, stream>>>(F(C_W0), 512, U(W0T), 400, 416, 512, 512);
  k_mfc<5, 80, 512, 0><<<dim3(128, 8), 256, 0, stream>>>(U(MELPB), U(W0T), nullptr, (void*)(ws + PA), 8192, 512, 416, 512);
  k_cs1<<<256, 256, 0, stream>>>(F(PA), 32, 512, F(PARTS));
  k_cs2<<<512, 256, 0, stream>>>(F(PARTS), 512, 8192, F(STATS));
  k_bnact<1><<<16384, 256, 0, stream>>>(F(PA), F(PB), U(PBB), F(STATS), F(C_PBS), F(C_PBO), 511, 4194304);
  for (int i = 0; i < 3; ++i) {
    k_trbp<<<dim3(40, 8), 256, 0, stream>>>(F(C_WM) + (size_t)i * 1310720, 512, U(WTP), 2560, 2560, 512, 512);
    k_mfc<5, 512, 512, 0><<<dim3(128, 8), 256, 0, stream>>>(U(PBB), U(WTP), nullptr, (void*)(ws + PA), 8192, 512, 2560, 512);
    k_cs1<<<256, 256, 0, stream>>>(F(PA), 32, 512, F(PARTS));
    k_cs2<<<512, 256, 0, stream>>>(F(PARTS), 512, 8192, F(STATS));
    k_bnact<1><<<16384, 256, 0, stream>>>(F(PA), F(PB), U(PBB), F(STATS), F(C_PBS) + (i + 1) * 512, F(C_PBO) + (i + 1) * 512, 511, 4194304);
  }
  // last conv: fused-im2col MFMA (N 80->128 masked)
  k_trbp<<<dim3(40, 2), 256, 0, stream>>>(F(C_W4), 80, U(W4T), 2560, 2560, 80, 128);
  k_mfc<5, 512, 512, 4><<<dim3(128, 2), 256, 0, stream>>>(U(PBB), U(W4T), F(C_B4), (void*)(ws + RESID), 8192, 128, 2560, 80);
  k_out<<<2560, 256, 0, stream>>>(F(MELP), F(RESID), d_out, flags);
}

// Round 13
// 4871.244 us; speedup vs baseline: 3.4804x; 1.0015x over previous
//
#include <hip/hip_runtime.h>

#define EPSV 1e-5f

typedef unsigned int uivec4 __attribute__((ext_vector_type(4)));
typedef short bh8 __attribute__((ext_vector_type(8)));
typedef float f32x4 __attribute__((ext_vector_type(4)));

__device__ __forceinline__ float b2f(unsigned short u) {
  unsigned int x = ((unsigned int)u) << 16;
  return __uint_as_float(x);
}
__device__ __forceinline__ unsigned short f2b(float f) {
  unsigned int x = __float_as_uint(f);
  unsigned int r = (x + 0x7FFFu + ((x >> 16) & 1u)) >> 16;
  return (unsigned short)r;
}
__device__ __forceinline__ float sigm(float x) { return 1.0f / (1.0f + expf(-x)); }

// ---- coherence-point (device-coherent) access: bypass L1+L2 both ways ----
__device__ __forceinline__ void stg_bf16(unsigned short* p, float v) {
  unsigned short h = f2b(v);
  asm volatile("global_store_short %0, %1, off sc0 sc1" ::"v"(p), "v"(h) : "memory");
}
__device__ __forceinline__ void ldg2_sc(const unsigned short* p0, const unsigned short* p1,
                                        uivec4& a, uivec4& b) {
  asm volatile(
      "global_load_dwordx4 %0, %2, off sc0 sc1\n\t"
      "global_load_dwordx4 %1, %3, off sc0 sc1\n\t"
      "s_waitcnt vmcnt(0)"
      : "=&v"(a), "=&v"(b)
      : "v"(p0), "v"(p1)
      : "memory");
}
// 4 x 16B from one pointer at byte offsets 0/256/512/768 (no wait)
__device__ __forceinline__ void ldg4f_nw(const unsigned short* p, uivec4& a, uivec4& b,
                                         uivec4& c, uivec4& d) {
  asm volatile(
      "global_load_dwordx4 %0, %4, off sc0 sc1\n\t"
      "global_load_dwordx4 %1, %4, off offset:256 sc0 sc1\n\t"
      "global_load_dwordx4 %2, %4, off offset:512 sc0 sc1\n\t"
      "global_load_dwordx4 %3, %4, off offset:768 sc0 sc1"
      : "=&v"(a), "=&v"(b), "=&v"(c), "=&v"(d)
      : "v"(p)
      : "memory");
}
__device__ __forceinline__ void vm0() { asm volatile("s_waitcnt vmcnt(0)" ::: "memory"); }
__device__ __forceinline__ unsigned int ldcnt(const unsigned int* p) {
  return __hip_atomic_load(p, __ATOMIC_RELAXED, __HIP_MEMORY_SCOPE_AGENT);
}

// ---------------- dtype detection ----------------
__global__ void k_detect(const void* __restrict__ embp, const void* __restrict__ zmp,
                         int* __restrict__ flags) {
  __shared__ int sh[4];
  int tid = threadIdx.x;
  if (tid < 4) sh[tid] = 0;
  __syncthreads();
  const unsigned short* u = (const unsigned short*)embp;
  int bad = 0;
  for (int i = tid; i < 4096; i += 256) {
    float f = fabsf(b2f(u[i]));
    if (!(f < 1e10f)) bad = 1;
  }
  if (bad) atomicAdd(&sh[3], 1);
  const unsigned char* p = (const unsigned char*)zmp;
  int codd = 0, c0 = 0, c1v = 0;
  for (int i = tid; i < 65536; i += 256) {
    unsigned char v = p[i];
    if (v) {
      if (i & 1) codd++;
      if ((i & 3) == 0) c0++;
      if (v == 1) c1v++;
    }
  }
  atomicAdd(&sh[0], codd); atomicAdd(&sh[1], c0); atomicAdd(&sh[2], c1v);
  __syncthreads();
  if (tid == 0) {
    flags[0] = sh[3] ? 1 : 0;
    int mode;
    if (sh[0] == 0) mode = 1;
    else if (sh[2] > 0) mode = 0;
    else if (sh[1] == 0) mode = 2;
    else mode = 3;
    flags[1] = mode;
  }
}

__global__ void k_cvt(const void* __restrict__ src, float* __restrict__ dst, int n,
                      const int* __restrict__ flags) {
  int i = blockIdx.x * 256 + threadIdx.x;
  if (i >= n) return;
  if (flags[0]) dst[i] = ((const float*)src)[i];
  else dst[i] = b2f(((const unsigned short*)src)[i]);
}

__global__ void k_cvtb(const float* __restrict__ src, unsigned short* __restrict__ dst, int n) {
  int i = blockIdx.x * 256 + threadIdx.x;
  if (i >= n) return;
  dst[i] = f2b(src[i]);
}

// cast row-wise with K -> Kpad zero padding
__global__ void k_cvtbp(const float* __restrict__ src, unsigned short* __restrict__ dst,
                        int K, int Kpad) {
  int r = blockIdx.x;
  int c = threadIdx.x;
  if (c < Kpad)
    dst[(size_t)r * Kpad + c] = (c < K) ? f2b(src[(size_t)r * K + c]) : (unsigned short)0;
}

__device__ __forceinline__ bool mask_at(const void* p, size_t i, int mode) {
  switch (mode) {
    case 0: return ((const unsigned char*)p)[i] != 0;
    case 1: return ((const int*)p)[i] != 0;
    case 2: return ((const float*)p)[i] != 0.0f;
    default: return ((const unsigned short*)p)[i] != 0;
  }
}

// ---------------- embedding (f32 + bf16 outputs) ----------------
__global__ void k_embed(const int* __restrict__ ph, const float* __restrict__ emb,
                        float* __restrict__ X, unsigned short* __restrict__ Xb) {
  int bl = blockIdx.x;
  int p = ph[bl];
  float v = emb[(size_t)p * 256 + threadIdx.x];
  X[(size_t)bl * 256 + threadIdx.x] = v;
  Xb[(size_t)bl * 256 + threadIdx.x] = f2b(v);
}

// ---------------- per-channel mean/var: 2-stage coalesced, deterministic ----------------
__global__ __launch_bounds__(256) void k_cs1(const float* __restrict__ X, int RB, int C,
                                             float* __restrict__ part) {
  int blk = blockIdx.x;
  int r0 = blk * RB;
  float s0 = 0.f, q0 = 0.f, s1 = 0.f, q1 = 0.f;
  for (int rr = 0; rr < RB; ++rr) {
    const float* row = X + (size_t)(r0 + rr) * C;
    float v = row[threadIdx.x];
    s0 += v; q0 += v * v;
    if (C > 256) {
      float v1 = row[256 + threadIdx.x];
      s1 += v1; q1 += v1 * v1;
    }
  }
  float* pr = part + (size_t)blk * 2 * C;
  pr[threadIdx.x] = s0;
  pr[C + threadIdx.x] = q0;
  if (C > 256) {
    pr[256 + threadIdx.x] = s1;
    pr[C + 256 + threadIdx.x] = q1;
  }
}
__global__ __launch_bounds__(256) void k_cs2(const float* __restrict__ part, int C, int R,
                                             float* __restrict__ st) {
  int c = blockIdx.x;
  int t = threadIdx.x;
  __shared__ float rs_[256], rq_[256];
  rs_[t] = part[(size_t)t * 2 * C + c];
  rq_[t] = part[(size_t)t * 2 * C + C + c];
  __syncthreads();
  for (int k = 128; k > 0; k >>= 1) {
    if (t < k) { rs_[t] += rs_[t + k]; rq_[t] += rq_[t + k]; }
    __syncthreads();
  }
  if (t == 0) {
    float m = rs_[0] / R;
    st[c] = m;
    st[C + c] = rq_[0] / R - m * m;
  }
}

template <int ACT>
__global__ void k_bnact(const float* __restrict__ X, float* __restrict__ Y,
                        unsigned short* __restrict__ Yb,
                        const float* __restrict__ st, const float* __restrict__ sc,
                        const float* __restrict__ of, int Cmask, int n) {
  int i = blockIdx.x * 256 + threadIdx.x;
  if (i >= n) return;
  int C = Cmask + 1;
  int c = i & Cmask;
  float m = st[c], v = st[C + c];
  float y = (X[i] - m) * rsqrtf(v + EPSV) * sc[c] + of[c];
  float r = ACT ? tanhf(y) : fmaxf(y, 0.0f);
  Y[i] = r;
  if (Yb) Yb[i] = f2b(r);
}

// ---------------- padded tiled transpose f32[K][ldn] -> bf16[Npad][Kpad] ----------------
__global__ __launch_bounds__(256) void k_trbp(const float* __restrict__ src, int ldn,
                                              unsigned short* __restrict__ dst,
                                              int K, int Kpad, int N, int Npad) {
  __shared__ float tl[64][65];
  int k0 = blockIdx.x * 64, n0 = blockIdx.y * 64;
  int tid = threadIdx.x;
#pragma unroll
  for (int p = 0; p < 16; ++p) {
    int idx = p * 256 + tid;
    int r = idx >> 6, c = idx & 63;
    float v = 0.0f;
    if (k0 + r < K && n0 + c < N) v = src[(size_t)(k0 + r) * ldn + n0 + c];
    tl[r][c] = v;
  }
  __syncthreads();
#pragma unroll
  for (int p = 0; p < 16; ++p) {
    int idx = p * 256 + tid;
    int rr = idx >> 6, cc = idx & 63;
    if (n0 + rr < Npad && k0 + cc < Kpad)
      dst[(size_t)(n0 + rr) * Kpad + k0 + cc] = f2b(tl[cc][rr]);
  }
}

// build proj A-matrix bf16 [8192][1536] = [cond | h1n | h2n]
__global__ __launch_bounds__(256) void k_cat3b(const float* __restrict__ cond,
                                               const float* __restrict__ h1n,
                                               const float* __restrict__ h2n,
                                               unsigned short* __restrict__ out) {
  int r = blockIdx.x;
  int b = r >> 9, t = r & 511;
#pragma unroll
  for (int p = 0; p < 6; ++p) {
    int col = p * 256 + threadIdx.x;
    float v;
    if (col < 512) v = cond[(size_t)r * 512 + col];
    else if (col < 1024) v = h1n[(size_t)(t * 16 + b) * 512 + (col - 512)];
    else v = h2n[(size_t)(t * 16 + b) * 512 + (col - 1024)];
    out[(size_t)r * 1536 + col] = f2b(v);
  }
}

// ---------------- MFMA GEMM: C[M,N] = A[M,K]bf16 @ Bt[N,K]bf16^T (+bias) ----------------
// OBF: 0 = f32 row-major (ldc=N), 2 = bf16 decoder-gate layout, 3 = f32 encoder-gate layout,
//      4 = f32 row-major with ldc=Nst and col guard n<Nst (padded-N)
template <int OBF>
__global__ __launch_bounds__(256) void k_mf(const unsigned short* __restrict__ A,
                                            const unsigned short* __restrict__ Bt,
                                            const float* __restrict__ bias,
                                            void* __restrict__ Cp, int M, int N, int K,
                                            int Nst) {
  const int lane = threadIdx.x & 63, wv = threadIdx.x >> 6;
  const int m0 = blockIdx.x * 64 + wv * 16;
  const int n0 = blockIdx.y * 64;
  const int koff = (lane >> 4) << 3;
  const unsigned short* arow = A + (size_t)(m0 + (lane & 15)) * K + koff;
  const unsigned short* brow0 = Bt + (size_t)(n0 + 0 * 16 + (lane & 15)) * K + koff;
  const unsigned short* brow1 = Bt + (size_t)(n0 + 1 * 16 + (lane & 15)) * K + koff;
  const unsigned short* brow2 = Bt + (size_t)(n0 + 2 * 16 + (lane & 15)) * K + koff;
  const unsigned short* brow3 = Bt + (size_t)(n0 + 3 * 16 + (lane & 15)) * K + koff;
  f32x4 acc0 = {0.f, 0.f, 0.f, 0.f}, acc1 = {0.f, 0.f, 0.f, 0.f};
  f32x4 acc2 = {0.f, 0.f, 0.f, 0.f}, acc3 = {0.f, 0.f, 0.f, 0.f};
  for (int k = 0; k < K; k += 32) {
    bh8 a = *(const bh8*)(arow + k);
    bh8 b0 = *(const bh8*)(brow0 + k);
    bh8 b1 = *(const bh8*)(brow1 + k);
    bh8 b2 = *(const bh8*)(brow2 + k);
    bh8 b3 = *(const bh8*)(brow3 + k);
    acc0 = __builtin_amdgcn_mfma_f32_16x16x32_bf16(a, b0, acc0, 0, 0, 0);
    acc1 = __builtin_amdgcn_mfma_f32_16x16x32_bf16(a, b1, acc1, 0, 0, 0);
    acc2 = __builtin_amdgcn_mfma_f32_16x16x32_bf16(a, b2, acc2, 0, 0, 0);
    acc3 = __builtin_amdgcn_mfma_f32_16x16x32_bf16(a, b3, acc3, 0, 0, 0);
  }
  const int r0 = m0 + ((lane >> 4) << 2);
  const int nl = lane & 15;
  float av[4][4];
#pragma unroll
  for (int r = 0; r < 4; ++r) { av[0][r] = acc0[r]; av[1][r] = acc1[r]; av[2][r] = acc2[r]; av[3][r] = acc3[r]; }
#pragma unroll
  for (int t = 0; t < 4; ++t) {
    int n = n0 + t * 16 + nl;
    float bv = 0.0f;
    if (bias) {
      if (OBF == 4) bv = (n < Nst) ? bias[n] : 0.0f;
      else bv = bias[n];
    }
#pragma unroll
    for (int r = 0; r < 4; ++r) {
      float v = av[t][r] + bv;
      int row = r0 + r;
      if (OBF == 0) {
        ((float*)Cp)[(size_t)row * N + n] = v;
      } else if (OBF == 4) {
        if (n < Nst) ((float*)Cp)[(size_t)row * Nst + n] = v;
      } else if (OBF == 2) {
        int b = row >> 9, tt = row & 511;
        int g = n >> 9, w = (n & 511) >> 2, jj = n & 3;
        ((unsigned short*)Cp)[((size_t)tt * 128 + w) * 256 + b * 16 + g * 4 + jj] = f2b(v);
      } else {
        int b = row >> 8, l = row & 255;
        int g = n >> 8, w = (n & 255) >> 2, jj = n & 3;
        ((float*)Cp)[((size_t)l * 64 + w) * 256 + b * 16 + g * 4 + jj] = v;
      }
    }
  }
}

// ---------------- MFMA conv GEMM with fused im2col A-operand ----------------
// X bf16 [B*TT][CIN]; A row = (b,t), col k = dt*CIN+ci -> X[b, t+dt-KW/2, ci] (0 outside)
template <int KW, int CIN, int TT, int OBF>
__global__ __launch_bounds__(256) void k_mfc(const unsigned short* __restrict__ Xb,
                                             const unsigned short* __restrict__ Bt,
                                             const float* __restrict__ bias,
                                             void* __restrict__ Cp, int M, int N, int K,
                                             int Nst) {
  const int lane = threadIdx.x & 63, wv = threadIdx.x >> 6;
  const int m0 = blockIdx.x * 64 + wv * 16;
  const int n0 = blockIdx.y * 64;
  const int koff = (lane >> 4) << 3;
  const int row = m0 + (lane & 15);
  const int bb = row / TT, t = row % TT;
  const unsigned short* brow0 = Bt + (size_t)(n0 + 0 * 16 + (lane & 15)) * K + koff;
  const unsigned short* brow1 = Bt + (size_t)(n0 + 1 * 16 + (lane & 15)) * K + koff;
  const unsigned short* brow2 = Bt + (size_t)(n0 + 2 * 16 + (lane & 15)) * K + koff;
  const unsigned short* brow3 = Bt + (size_t)(n0 + 3 * 16 + (lane & 15)) * K + koff;
  f32x4 acc0 = {0.f, 0.f, 0.f, 0.f}, acc1 = {0.f, 0.f, 0.f, 0.f};
  f32x4 acc2 = {0.f, 0.f, 0.f, 0.f}, acc3 = {0.f, 0.f, 0.f, 0.f};
  for (int k = 0; k < K; k += 32) {
    int ke = k + koff;
    int dt = ke / CIN;
    int ci = ke - dt * CIN;
    int tt = t + dt - (KW / 2);
    bh8 a = {0, 0, 0, 0, 0, 0, 0, 0};
    if (dt < KW && tt >= 0 && tt < TT)
      a = *(const bh8*)&Xb[((size_t)(bb * TT + tt)) * CIN + ci];
    bh8 b0 = *(const bh8*)(brow0 + k);
    bh8 b1 = *(const bh8*)(brow1 + k);
    bh8 b2 = *(const bh8*)(brow2 + k);
    bh8 b3 = *(const bh8*)(brow3 + k);
    acc0 = __builtin_amdgcn_mfma_f32_16x16x32_bf16(a, b0, acc0, 0, 0, 0);
    acc1 = __builtin_amdgcn_mfma_f32_16x16x32_bf16(a, b1, acc1, 0, 0, 0);
    acc2 = __builtin_amdgcn_mfma_f32_16x16x32_bf16(a, b2, acc2, 0, 0, 0);
    acc3 = __builtin_amdgcn_mfma_f32_16x16x32_bf16(a, b3, acc3, 0, 0, 0);
  }
  const int r0 = m0 + ((lane >> 4) << 2);
  const int nl = lane & 15;
  float av[4][4];
#pragma unroll
  for (int r = 0; r < 4; ++r) { av[0][r] = acc0[r]; av[1][r] = acc1[r]; av[2][r] = acc2[r]; av[3][r] = acc3[r]; }
#pragma unroll
  for (int tq = 0; tq < 4; ++tq) {
    int n = n0 + tq * 16 + nl;
    float bv = 0.0f;
    if (bias) {
      if (OBF == 4) bv = (n < Nst) ? bias[n] : 0.0f;
      else bv = bias[n];
    }
#pragma unroll
    for (int r = 0; r < 4; ++r) {
      float v = av[tq][r] + bv;
      int rw = r0 + r;
      if (OBF == 0) {
        ((float*)Cp)[(size_t)rw * N + n] = v;
      } else if (OBF == 4) {
        if (n < Nst) ((float*)Cp)[(size_t)rw * Nst + n] = v;
      }
    }
  }
}

// ---------------- duration cumsum ----------------
__global__ void k_cumsum(const float* __restrict__ dur, float* __restrict__ mid) {
  int b = threadIdx.x;
  if (b >= 16) return;
  float run = 0.f;
  for (int l = 0; l < 256; ++l) {
    float d = dur[b * 256 + l];
    run += d;
    mid[b * 256 + l] = run - 0.5f * d;
  }
}

// ---------------- persistent bi-LSTM encoder (64 WGs; 8 cols/WG; MFMA dot) ----------------
#define EST 130  // u32 stride per batch row (260 bf16)
__global__ __launch_bounds__(256) void k_enc_lstm(const float* __restrict__ GFp,
                                                  const float* __restrict__ GBp,
                                                  const float* __restrict__ Wf,
                                                  const float* __restrict__ Wb,
                                                  float* __restrict__ enc,
                                                  unsigned short* __restrict__ encB,
                                                  const int* __restrict__ lengths,
                                                  unsigned int* __restrict__ cnt) {
  const int tid = threadIdx.x;
  const int wg = blockIdx.x;
  const int dir = wg >> 5;
  const int w = wg & 31;  // owns cols 8w..8w+8 of 256
  const float* Gpre = dir ? GBp : GFp;
  const float* W = dir ? Wb : Wf;
  unsigned int* c_self = cnt + (size_t)dir * 256 * 128;

  __shared__ __align__(16) unsigned int hsW[16 * EST];
  __shared__ __align__(16) float accb[8 * 264];
  __shared__ __align__(16) float gl[16 * 33];
  __shared__ float cst[128];
  __shared__ int rs[16];

  const int lane = tid & 63, wv = tid >> 6;
  const int n16 = lane & 15, lq = lane >> 4;

  // B frags: subtile s in {0,1}; gate col n = s*16+n16 -> g=n>>3, jn=n&7
  bh8 BE[2][2];
#pragma unroll
  for (int s = 0; s < 2; ++s) {
    int n = s * 16 + n16;
    int colg = (n >> 3) * 256 + w * 8 + (n & 7);
#pragma unroll
    for (int c = 0; c < 2; ++c)
#pragma unroll
      for (int j = 0; j < 8; ++j) {
        int k = wv * 64 + c * 32 + lq * 8 + j;
        BE[c][s][j] = (short)f2b(W[(size_t)(256 + k) * 1024 + colg]);
      }
  }
  if (tid < 128) cst[tid] = 0.0f;
  __syncthreads();

  for (int t = 0; t < 256; ++t) {
    const int l = dir ? (255 - t) : t;
    if (tid < 16) rs[tid] = (dir == 1) && (l >= lengths[tid] - 1);
    // prefetch 2 precomputed gate values per thread
    float gp[2];
#pragma unroll
    for (int it = 0; it < 2; ++it) {
      int e = tid + it * 256;
      int b = e >> 5, n = e & 31;
      int jn = n & 7, g = n >> 3;
      int slot = w * 2 + (jn >> 2);
      gp[it] = Gpre[((size_t)l * 64 + slot) * 256 + b * 16 + g * 4 + (jn & 3)];
    }
    if (t > 0 && tid < 8) {
      const unsigned int* a = c_self + (size_t)(t - 1) * 128 + tid * 16;
      unsigned int gcount = 0;
      while (ldcnt(a) < 4u) {
        __builtin_amdgcn_s_sleep(2);
        if (++gcount > (1u << 16)) break;
      }
    }
    __syncthreads();
    if (t > 0) {
      const int lprev = dir ? (l + 1) : (l - 1);
      int b = tid >> 4, q = tid & 15;
      const unsigned short* p = encB + ((size_t)dir << 20) + (((size_t)lprev * 16 + b) << 8) + q * 16;
      uivec4 a0, a1;
      ldg2_sc(p, p + 8, a0, a1);
      if (rs[b]) {
        a0.x = a0.y = a0.z = a0.w = 0u;
        a1.x = a1.y = a1.z = a1.w = 0u;
      }
      *(uivec4*)&hsW[b * EST + q * 8] = a0;
      *(uivec4*)&hsW[b * EST + q * 8 + 4] = a1;
    }
    __syncthreads();

    f32x4 ac[2] = {{0.f, 0.f, 0.f, 0.f}, {0.f, 0.f, 0.f, 0.f}};
    if (t > 0) {
#pragma unroll
      for (int c = 0; c < 2; ++c) {
        int kw = wv * 32 + c * 16 + lq * 4;
        bh8 af = *(const bh8*)&hsW[(lane & 15) * EST + kw];
        ac[0] = __builtin_amdgcn_mfma_f32_16x16x32_bf16(af, BE[c][0], ac[0], 0, 0, 0);
        ac[1] = __builtin_amdgcn_mfma_f32_16x16x32_bf16(af, BE[c][1], ac[1], 0, 0, 0);
      }
    }
    {
      int idx = (lq * 4) * 16 + n16;
#pragma unroll
      for (int s = 0; s < 2; ++s) {
        float* pb = &accb[(s * 4 + wv) * 264];
#pragma unroll
        for (int r = 0; r < 4; ++r) pb[idx + r * 16] = ac[s][r];
      }
    }
    __syncthreads();
#pragma unroll
    for (int it = 0; it < 2; ++it) {
      int e = tid + it * 256;
      int b = e >> 5, n = e & 31;
      int s = n >> 4, nn = n & 15;
      float sum = gp[it];
      if (t > 0) {
#pragma unroll
        for (int v = 0; v < 4; ++v) sum += accb[(s * 4 + v) * 264 + b * 16 + nn];
      }
      gl[b * 33 + n] = sum;
    }
    __syncthreads();
    if (tid < 128) {
      int b = tid >> 3, jn = tid & 7;
      float gi = gl[b * 33 + 0 * 8 + jn];
      float gg = gl[b * 33 + 1 * 8 + jn];
      float gf = gl[b * 33 + 2 * 8 + jn];
      float go = gl[b * 33 + 3 * 8 + jn];
      float c = cst[tid];
      if (t == 0 || rs[b]) c = 0.0f;
      c = sigm(gf + 1.0f) * c + sigm(gi) * tanhf(gg);
      float h = sigm(go) * tanhf(c);
      cst[tid] = c;
      int col = w * 8 + jn;
      enc[(size_t)(b * 256 + l) * 512 + dir * 256 + col] = h;
      stg_bf16(&encB[((size_t)dir << 20) + (((size_t)l * 16 + b) << 8) + col], h);
    }
    vm0();
    __syncthreads();
    if (tid == 0)
      __hip_atomic_fetch_add(c_self + (size_t)t * 128 + (w >> 2) * 16, 1u,
                             __ATOMIC_RELAXED, __HIP_MEMORY_SCOPE_AGENT);
  }
}

// ---------------- Gaussian-softmax upsampling ----------------
__global__ __launch_bounds__(256) void k_upsample(const float* __restrict__ mid,
                                                  const float* __restrict__ enc,
                                                  float* __restrict__ cond) {
  int blk = blockIdx.x;
  int b = blk >> 5, t0 = (blk & 31) * 16;
  int tid = threadIdx.x;
  __shared__ float wls[16][256];
  __shared__ float red[256];
  float mp = mid[b * 256 + tid];
  for (int tt = 0; tt < 16; ++tt) {
    float tpos = (float)(t0 + tt);
    float d = mp - tpos;
    float d2 = d * d * 0.1f;
    red[tid] = d2; __syncthreads();
    for (int k = 128; k > 0; k >>= 1) { if (tid < k) red[tid] = fminf(red[tid], red[tid + k]); __syncthreads(); }
    float mn = red[0]; __syncthreads();
    float e = expf(mn - d2);
    red[tid] = e; __syncthreads();
    for (int k = 128; k > 0; k >>= 1) { if (tid < k) red[tid] += red[tid + k]; __syncthreads(); }
    float sum = red[0]; __syncthreads();
    wls[tt][tid] = e / sum;
  }
  __syncthreads();
  float a0[16], a1[16];
#pragma unroll
  for (int i = 0; i < 16; ++i) { a0[i] = 0; a1[i] = 0; }
  for (int l = 0; l < 256; ++l) {
    float e0 = enc[(size_t)(b * 256 + l) * 512 + tid];
    float e1 = enc[(size_t)(b * 256 + l) * 512 + 256 + tid];
#pragma unroll
    for (int tt = 0; tt < 16; ++tt) { float wv = wls[tt][l]; a0[tt] += wv * e0; a1[tt] += wv * e1; }
  }
  for (int tt = 0; tt < 16; ++tt) {
    cond[(size_t)(b * 512 + t0 + tt) * 512 + tid] = a0[tt];
    cond[(size_t)(b * 512 + t0 + tt) * 512 + 256 + tid] = a1[tt];
  }
}

// concat -> bf16 decoder input A-matrix [8192][768]
__global__ void k_concat(const float* __restrict__ cond, const float* __restrict__ p,
                         unsigned short* __restrict__ din) {
  size_t i = (size_t)blockIdx.x * 256 + threadIdx.x;
  int r = (int)(i / 768);
  int c = (int)(i % 768);
  float v = (c < 512) ? cond[(size_t)r * 512 + c] : p[(size_t)r * 256 + (c - 512)];
  din[i] = f2b(v);
}

// ---------------- merged 2-layer zoneout LSTM decoder (64 WGs; 8 cols/WG) ----------------
#define DST 780  // u32 stride per batch row (h1c|h1n|h2c + pad)
__global__ __launch_bounds__(256) void k_dec_lstm(
    const unsigned short* __restrict__ D1x, const unsigned short* __restrict__ D2x,
    const float* __restrict__ W1, const float* __restrict__ W2,
    const void* __restrict__ zh1, const void* __restrict__ zc1,
    const void* __restrict__ zh2, const void* __restrict__ zc2,
    unsigned short* __restrict__ h1cB, unsigned short* __restrict__ h1nB,
    unsigned short* __restrict__ h2cB,
    float* __restrict__ h1n, float* __restrict__ h2n,
    unsigned int* __restrict__ cnt1,
    const int* __restrict__ flags) {
  const int tid = threadIdx.x;
  const int w = blockIdx.x;  // 0..63, owns cols 8w..8w+8 of both layers

  __shared__ __align__(16) unsigned int hsW[16 * DST];
  __shared__ __align__(16) float accb1[8 * 264];
  __shared__ __align__(16) float accb2[8 * 264];
  __shared__ __align__(16) float gl1[16 * 33], gl2[16 * 33];
  __shared__ float cst1[128], hst1[128], cst2[128], hst2[128];

  const int mmode = flags[1];
  const int lane = tid & 63, wv = tid >> 6;
  const int n16 = lane & 15, lq = lane >> 4;

  // B frags: n = s*16+n16 -> g=n>>3, jn=n&7; col = g*512 + 8w + jn
  bh8 B1[4][2], B2[8][2];
#pragma unroll
  for (int s = 0; s < 2; ++s) {
    int n = s * 16 + n16;
    int colg = (n >> 3) * 512 + w * 8 + (n & 7);
#pragma unroll
    for (int c = 0; c < 4; ++c)
#pragma unroll
      for (int j = 0; j < 8; ++j) {
        int k = wv * 128 + c * 32 + lq * 8 + j;
        B1[c][s][j] = (short)f2b(W1[(size_t)(768 + k) * 2048 + colg]);
      }
#pragma unroll
    for (int c = 0; c < 8; ++c)
#pragma unroll
      for (int j = 0; j < 8; ++j) {
        int k = wv * 256 + c * 32 + lq * 8 + j;
        B2[c][s][j] = (short)f2b(W2[(size_t)(768 + k) * 2048 + colg]);
      }
  }
  if (tid < 128) { cst1[tid] = 0; hst1[tid] = 0; cst2[tid] = 0; hst2[tid] = 0; }
  __syncthreads();

  for (int tau = 0; tau <= 512; ++tau) {
    // prefetch gate values: 2 per layer per thread
    float dx1[2] = {0.f, 0.f}, dx2[2] = {0.f, 0.f};
    if (tau < 512) {
#pragma unroll
      for (int it = 0; it < 2; ++it) {
        int e = tid + it * 256;
        int b = e >> 5, n = e & 31;
        int jn = n & 7, g = n >> 3;
        int slot = w * 2 + (jn >> 2);
        dx1[it] = b2f(D1x[((size_t)tau * 128 + slot) * 256 + b * 16 + g * 4 + (jn & 3)]);
      }
    }
    if (tau >= 1) {
#pragma unroll
      for (int it = 0; it < 2; ++it) {
        int e = tid + it * 256;
        int b = e >> 5, n = e & 31;
        int jn = n & 7, g = n >> 3;
        int slot = w * 2 + (jn >> 2);
        dx2[it] = b2f(D2x[((size_t)(tau - 1) * 128 + slot) * 256 + b * 16 + g * 4 + (jn & 3)]);
      }
    }
    if (tau >= 1 && tid < 8) {
      const unsigned int* a = cnt1 + (size_t)(tau - 1) * 128 + tid * 16;
      unsigned int gcount = 0;
      while (ldcnt(a) < 8u) {
        __builtin_amdgcn_s_sleep(2);
        if (++gcount > (1u << 16)) break;
      }
    }
    __syncthreads();

    if (tau >= 1) {
      int b = tid >> 4, q = tid & 15;
      const unsigned short* p0 = h1cB + (((size_t)(tau - 1) * 16 + b) << 9) + q * 8;
      const unsigned short* p1 = h1nB + (((size_t)(tau - 1) * 16 + b) << 9) + q * 8;
      uivec4 r[12];
      ldg4f_nw(p0, r[0], r[1], r[2], r[3]);
      ldg4f_nw(p1, r[4], r[5], r[6], r[7]);
      if (tau >= 2) {
        const unsigned short* p2 = h2cB + (((size_t)(tau - 2) * 16 + b) << 9) + q * 8;
        ldg4f_nw(p2, r[8], r[9], r[10], r[11]);
      } else {
        uivec4 z; z.x = z.y = z.z = z.w = 0u;
        r[8] = z; r[9] = z; r[10] = z; r[11] = z;
      }
      vm0();
      unsigned int base = b * DST + q * 4;
#pragma unroll
      for (int m = 0; m < 4; ++m) *(uivec4*)&hsW[base + 64 * m] = r[m];
#pragma unroll
      for (int m = 0; m < 4; ++m) *(uivec4*)&hsW[base + 256 + 64 * m] = r[4 + m];
#pragma unroll
      for (int m = 0; m < 4; ++m) *(uivec4*)&hsW[base + 512 + 64 * m] = r[8 + m];
    }
    __syncthreads();

    f32x4 a1[2] = {{0.f, 0.f, 0.f, 0.f}, {0.f, 0.f, 0.f, 0.f}};
    f32x4 a2[2] = {{0.f, 0.f, 0.f, 0.f}, {0.f, 0.f, 0.f, 0.f}};
    if (tau >= 1) {
      if (tau < 512) {
#pragma unroll
        for (int c = 0; c < 4; ++c) {
          int kw = wv * 64 + c * 16 + lq * 4;
          bh8 af = *(const bh8*)&hsW[(lane & 15) * DST + kw];
          a1[0] = __builtin_amdgcn_mfma_f32_16x16x32_bf16(af, B1[c][0], a1[0], 0, 0, 0);
          a1[1] = __builtin_amdgcn_mfma_f32_16x16x32_bf16(af, B1[c][1], a1[1], 0, 0, 0);
        }
      }
#pragma unroll
      for (int c = 0; c < 8; ++c) {
        int kw = 256 + wv * 128 + c * 16 + lq * 4;
        bh8 af = *(const bh8*)&hsW[(lane & 15) * DST + kw];
        a2[0] = __builtin_amdgcn_mfma_f32_16x16x32_bf16(af, B2[c][0], a2[0], 0, 0, 0);
        a2[1] = __builtin_amdgcn_mfma_f32_16x16x32_bf16(af, B2[c][1], a2[1], 0, 0, 0);
      }
    }
    {
      int idx = (lq * 4) * 16 + n16;
#pragma unroll
      for (int s = 0; s < 2; ++s) {
        float* p1b = &accb1[(s * 4 + wv) * 264];
        float* p2b = &accb2[(s * 4 + wv) * 264];
#pragma unroll
        for (int r = 0; r < 4; ++r) { p1b[idx + r * 16] = a1[s][r]; p2b[idx + r * 16] = a2[s][r]; }
      }
    }
    __syncthreads();
#pragma unroll
    for (int it = 0; it < 2; ++it) {
      int e = tid + it * 256;
      int b = e >> 5, n = e & 31;
      int s = n >> 4, nn = n & 15;
      int off = b * 16 + nn;
      float s1 = dx1[it], s2 = dx2[it];
      if (tau >= 1) {
        if (tau < 512) {
#pragma unroll
          for (int v = 0; v < 4; ++v) s1 += accb1[(s * 4 + v) * 264 + off];
        }
#pragma unroll
        for (int v = 0; v < 4; ++v) s2 += accb2[(s * 4 + v) * 264 + off];
      }
      gl1[b * 33 + n] = s1;
      gl2[b * 33 + n] = s2;
    }
    __syncthreads();

    if (tid < 128) {
      if (tau < 512) {
        int b = tid >> 3, jn = tid & 7, colgw = w * 8 + jn;
        float gi = gl1[b * 33 + 0 * 8 + jn];
        float gg = gl1[b * 33 + 1 * 8 + jn];
        float gf = gl1[b * 33 + 2 * 8 + jn];
        float go = gl1[b * 33 + 3 * 8 + jn];
        float cold = (tau == 0) ? 0.0f : cst1[tid];
        float hold = (tau == 0) ? 0.0f : hst1[tid];
        float nc = sigm(gf + 1.0f) * cold + sigm(gi) * tanhf(gg);
        float nh = sigm(go) * tanhf(nc);
        size_t mi = ((size_t)b * 512 + tau) * 512 + colgw;
        bool mh = mask_at(zh1, mi, mmode);
        bool mc = mask_at(zc1, mi, mmode);
        cst1[tid] = mc ? cold : nc;
        float hkeep = mh ? hold : nh;
        hst1[tid] = hkeep;
        h1n[(size_t)(tau * 16 + b) * 512 + colgw] = nh;
        stg_bf16(&h1cB[(((size_t)tau * 16 + b) << 9) + colgw], hkeep);
        stg_bf16(&h1nB[(((size_t)tau * 16 + b) << 9) + colgw], nh);
      }
    } else {
      if (tau >= 1) {
        int u = tid - 128;
        int t2 = tau - 1;
        int b = u >> 3, jn = u & 7, colgw = w * 8 + jn;
        float gi = gl2[b * 33 + 0 * 8 + jn];
        float gg = gl2[b * 33 + 1 * 8 + jn];
        float gf = gl2[b * 33 + 2 * 8 + jn];
        float go = gl2[b * 33 + 3 * 8 + jn];
        float cold = (tau == 1) ? 0.0f : cst2[u];
        float hold = (tau == 1) ? 0.0f : hst2[u];
        float nc = sigm(gf + 1.0f) * cold + sigm(gi) * tanhf(gg);
        float nh = sigm(go) * tanhf(nc);
        size_t mi = ((size_t)b * 512 + t2) * 512 + colgw;
        bool mh = mask_at(zh2, mi, mmode);
        bool mc = mask_at(zc2, mi, mmode);
        cst2[u] = mc ? cold : nc;
        float hkeep = mh ? hold : nh;
        hst2[u] = hkeep;
        h2n[(size_t)(t2 * 16 + b) * 512 + colgw] = nh;
        stg_bf16(&h2cB[(((size_t)t2 * 16 + b) << 9) + colgw], hkeep);
      }
    }
    vm0();
    __syncthreads();
    if (tid == 0)
      __hip_atomic_fetch_add(cnt1 + (size_t)tau * 128 + (w >> 3) * 16, 1u,
                             __ATOMIC_RELAXED, __HIP_MEMORY_SCOPE_AGENT);
  }
}

__global__ void k_out(const float* __restrict__ mel, const float* __restrict__ res,
                      void* __restrict__ out, const int* __restrict__ flags) {
  int i = blockIdx.x * 256 + threadIdx.x;
  float m = mel[i];
  float f = m + res[i];
  if (flags[0]) {
    ((float*)out)[i] = m;
    ((float*)out)[655360 + i] = f;
  } else {
    unsigned short* o = (unsigned short*)out;
    o[i] = f2b(m);
    o[655360 + i] = f2b(f);
  }
}

// ---------------- host launch ----------------
extern "C" void kernel_launch(void* const* d_in, const int* in_sizes, int n_in,
                              void* d_out, int out_size, void* d_ws, size_t ws_size,
                              hipStream_t stream) {
  char* ws = (char*)d_ws;
  size_t o = 0;
  auto A_ = [&](size_t nb) { size_t r = o; o += (nb + 255) & ~(size_t)255; return r; };
  const size_t FLAGS = A_(256);
  const size_t SYNC = A_(786432);
  const size_t STATS = A_(4096);
  const size_t PARTS = A_(1048576 + 4096);
  const size_t XAB = A_(2097152);
  const size_t WTE1 = A_(524288), WTE2 = A_(524288);
  const size_t C_MELS = A_(655360ull * 4), C_DUR = A_(4096 * 4), C_EMB = A_(65536 * 4),
               C_ECW = A_(589824ull * 4), C_EBS = A_(768 * 4), C_EBO = A_(768 * 4),
               C_LFW = A_(524288ull * 4), C_LFB = A_(1024 * 4), C_LBW = A_(524288ull * 4),
               C_LBB = A_(1024 * 4), C_PW1 = A_(20480 * 4), C_P1S = A_(256 * 4),
               C_P1O = A_(256 * 4), C_PW2 = A_(65536 * 4), C_P2S = A_(256 * 4),
               C_P2O = A_(256 * 4), C_DW1 = A_(2621440ull * 4), C_DB1 = A_(2048 * 4),
               C_DW2 = A_(3670016ull * 4), C_DB2 = A_(2048 * 4), C_PRW = A_(122880ull * 4),
               C_PRB = A_(512), C_W0 = A_(204800ull * 4), C_WM = A_(3932160ull * 4),
               C_W4 = A_(204800ull * 4), C_B4 = A_(512), C_PBS = A_(2048 * 4),
               C_PBO = A_(2048 * 4);
  const size_t R1 = A_(16777216), R2 = A_(16777216), R3 = A_(16777216), R4 = A_(16777216),
               MID = A_(4096 * 4), R5 = A_(16777216), R6 = A_(16777216), R7 = A_(25165824),
               D1X = A_(33554432), D2X = A_(33554432), MELP = A_(2621440);
  const size_t XA = R1, XB = R1 + 4194304;
  const size_t ECWT = R3;
  const size_t GF = R2;
  const size_t GB = R3, H1N = R3;
  const size_t ENC = R4, H2N = R4;
  const size_t COND = R5, PA = R5;
  const size_t PREA = R6, PREB = R6 + 8388608, PB = R6;
  const size_t PBB = R3;  // postnet bf16 activations (R3 free after projection)
  const size_t DECIN = R7, RESID = R7;
  const size_t H1CB = R1, H1NB = R1 + 8388608;
  const size_t H2CB = R2;
  const size_t ENCB = R7;
  const size_t MELB = R1, PW1T = R1 + 2097152, PREBB = R1, PW2T = R1 + 8388608;
  const size_t WT1 = R4, WT2 = R4 + 4194304;
  const size_t PROJA = R1;  // spans R1..R2 (25MB)
  const size_t PRWT = R6;
  const size_t MELPB = R1, W0T = R2;
  const size_t WTP = D1X, W4T = D2X;

  auto F = [&](size_t off) { return (float*)(ws + off); };
  auto U = [&](size_t off) { return (unsigned short*)(ws + off); };
  int* flags = (int*)(ws + FLAGS);
  unsigned int* cntE = (unsigned int*)(ws + SYNC);
  unsigned int* cnt1 = (unsigned int*)(ws + SYNC + 262144);

  hipMemsetAsync(ws + SYNC, 0, 786432, stream);
  k_detect<<<1, 256, 0, stream>>>(d_in[8], d_in[4], flags);

  struct CV { int idx; size_t off; int n; };
  const CV cvs[] = {
      {2, C_MELS, 655360}, {3, C_DUR, 4096}, {8, C_EMB, 65536}, {9, C_ECW, 589824},
      {10, C_EBS, 768}, {11, C_EBO, 768}, {12, C_LFW, 524288}, {13, C_LFB, 1024},
      {14, C_LBW, 524288}, {15, C_LBB, 1024}, {16, C_PW1, 20480}, {17, C_P1S, 256},
      {18, C_P1O, 256}, {19, C_PW2, 65536}, {20, C_P2S, 256}, {21, C_P2O, 256},
      {22, C_DW1, 2621440}, {23, C_DB1, 2048}, {24, C_DW2, 3670016}, {25, C_DB2, 2048},
      {26, C_PRW, 122880}, {27, C_PRB, 80}, {28, C_W0, 204800}, {29, C_WM, 3932160},
      {30, C_W4, 204800}, {31, C_B4, 80}, {32, C_PBS, 2048}, {33, C_PBO, 2048}};
  for (int i = 0; i < (int)(sizeof(cvs) / sizeof(cvs[0])); ++i)
    k_cvt<<<(cvs[i].n + 255) / 256, 256, 0, stream>>>(d_in[cvs[i].idx], F(cvs[i].off), cvs[i].n, flags);

  k_embed<<<4096, 256, 0, stream>>>((const int*)d_in[0], F(C_EMB), F(XA), U(XAB));
  // encoder convs: fused-im2col MFMA (K=768)
  for (int i = 0; i < 3; ++i) {
    k_trbp<<<dim3(12, 4), 256, 0, stream>>>(F(C_ECW) + (size_t)i * 196608, 256, U(ECWT), 768, 768, 256, 256);
    k_mfc<3, 256, 256, 0><<<dim3(64, 4), 256, 0, stream>>>(U(XAB), U(ECWT), nullptr, (void*)(ws + XB), 4096, 256, 768, 256);
    k_cs1<<<256, 256, 0, stream>>>(F(XB), 16, 256, F(PARTS));
    k_cs2<<<256, 256, 0, stream>>>(F(PARTS), 256, 4096, F(STATS));
    k_bnact<0><<<4096, 256, 0, stream>>>(F(XB), F(XA), U(XAB), F(STATS), F(C_EBS) + i * 256, F(C_EBO) + i * 256, 255, 1048576);
  }
  // encoder gate GEMMs via MFMA
  k_trbp<<<dim3(4, 16), 256, 0, stream>>>(F(C_LFW), 1024, U(WTE1), 256, 256, 1024, 1024);
  k_trbp<<<dim3(4, 16), 256, 0, stream>>>(F(C_LBW), 1024, U(WTE2), 256, 256, 1024, 1024);
  k_mf<3><<<dim3(64, 16), 256, 0, stream>>>(U(XAB), U(WTE1), F(C_LFB), (void*)(ws + GF), 4096, 1024, 256, 1024);
  k_mf<3><<<dim3(64, 16), 256, 0, stream>>>(U(XAB), U(WTE2), F(C_LBB), (void*)(ws + GB), 4096, 1024, 256, 1024);
  k_cumsum<<<1, 64, 0, stream>>>(F(C_DUR), F(MID));
  k_enc_lstm<<<64, 256, 0, stream>>>(F(GF), F(GB), F(C_LFW), F(C_LBW), F(ENC), U(ENCB),
                                     (const int*)d_in[1], cntE);
  k_upsample<<<512, 256, 0, stream>>>(F(MID), F(ENC), F(COND));

  // prenet via MFMA (K 80->96 padded, then 256)
  k_cvtbp<<<8192, 128, 0, stream>>>(F(C_MELS), U(MELB), 80, 96);
  k_trbp<<<dim3(2, 4), 256, 0, stream>>>(F(C_PW1), 256, U(PW1T), 80, 96, 256, 256);
  k_mf<0><<<dim3(128, 4), 256, 0, stream>>>(U(MELB), U(PW1T), nullptr, (void*)(ws + PREA), 8192, 256, 96, 256);
  k_cs1<<<256, 256, 0, stream>>>(F(PREA), 32, 256, F(PARTS));
  k_cs2<<<256, 256, 0, stream>>>(F(PARTS), 256, 8192, F(STATS));
  k_bnact<0><<<8192, 256, 0, stream>>>(F(PREA), F(PREB), nullptr, F(STATS), F(C_P1S), F(C_P1O), 255, 2097152);
  k_cvtb<<<8192, 256, 0, stream>>>(F(PREB), U(PREBB), 2097152);
  k_trbp<<<dim3(4, 4), 256, 0, stream>>>(F(C_PW2), 256, U(PW2T), 256, 256, 256, 256);
  k_mf<0><<<dim3(128, 4), 256, 0, stream>>>(U(PREBB), U(PW2T), nullptr, (void*)(ws + PREA), 8192, 256, 256, 256);
  k_cs1<<<256, 256, 0, stream>>>(F(PREA), 32, 256, F(PARTS));
  k_cs2<<<256, 256, 0, stream>>>(F(PARTS), 256, 8192, F(STATS));
  k_bnact<0><<<8192, 256, 0, stream>>>(F(PREA), F(PREB), nullptr, F(STATS), F(C_P2S), F(C_P2O), 255, 2097152);

  k_concat<<<24576, 256, 0, stream>>>(F(COND), F(PREB), U(DECIN));
  // decoder gate GEMMs via MFMA
  k_trbp<<<dim3(12, 32), 256, 0, stream>>>(F(C_DW1), 2048, U(WT1), 768, 768, 2048, 2048);
  k_trbp<<<dim3(12, 32), 256, 0, stream>>>(F(C_DW2), 2048, U(WT2), 768, 768, 2048, 2048);
  k_mf<2><<<dim3(128, 32), 256, 0, stream>>>(U(DECIN), U(WT1), F(C_DB1), (void*)(ws + D1X), 8192, 2048, 768, 2048);
  k_mf<2><<<dim3(128, 32), 256, 0, stream>>>(U(DECIN), U(WT2), F(C_DB2), (void*)(ws + D2X), 8192, 2048, 768, 2048);
  k_dec_lstm<<<64, 256, 0, stream>>>((const unsigned short*)(ws + D1X), (const unsigned short*)(ws + D2X),
                                     F(C_DW1), F(C_DW2), d_in[4], d_in[5], d_in[6], d_in[7],
                                     U(H1CB), U(H1NB), U(H2CB),
                                     F(H1N), F(H2N), cnt1, flags);
  // projection via MFMA (N 80->128 masked)
  k_cat3b<<<8192, 256, 0, stream>>>(F(COND), F(H1N), F(H2N), U(PROJA));
  k_trbp<<<dim3(24, 2), 256, 0, stream>>>(F(C_PRW), 80, U(PRWT), 1536, 1536, 80, 128);
  k_mf<4><<<dim3(128, 2), 256, 0, stream>>>(U(PROJA), U(PRWT), F(C_PRB), (void*)(ws + MELP), 8192, 128, 1536, 80);

  // postnet first conv: fused-im2col MFMA (Cin=80, K=416 padded)
  k_cvtb<<<2560, 256, 0, stream>>>(F(MELP), U(MELPB), 655360);
  k_trbp<<<dim3(7, 8), 256, 0, stream>>>(F(C_W0), 512, U(W0T), 400, 416, 512, 512);
  k_mfc<5, 80, 512, 0><<<dim3(128, 8), 256, 0, stream>>>(U(MELPB), U(W0T), nullptr, (void*)(ws + PA), 8192, 512, 416, 512);
  k_cs1<<<256, 256, 0, stream>>>(F(PA), 32, 512, F(PARTS));
  k_cs2<<<512, 256, 0, stream>>>(F(PARTS), 512, 8192, F(STATS));
  k_bnact<1><<<16384, 256, 0, stream>>>(F(PA), F(PB), U(PBB), F(STATS), F(C_PBS), F(C_PBO), 511, 4194304);
  for (int i = 0; i < 3; ++i) {
    k_trbp<<<dim3(40, 8), 256, 0, stream>>>(F(C_WM) + (size_t)i * 1310720, 512, U(WTP), 2560, 2560, 512, 512);
    k_mfc<5, 512, 512, 0><<<dim3(128, 8), 256, 0, stream>>>(U(PBB), U(WTP), nullptr, (void*)(ws + PA), 8192, 512, 2560, 512);
    k_cs1<<<256, 256, 0, stream>>>(F(PA), 32, 512, F(PARTS));
    k_cs2<<<512, 256, 0, stream>>>(F(PARTS), 512, 8192, F(STATS));
    k_bnact<1><<<16384, 256, 0, stream>>>(F(PA), F(PB), U(PBB), F(STATS), F(C_PBS) + (i + 1) * 512, F(C_PBO) + (i + 1) * 512, 511, 4194304);
  }
  // last conv: fused-im2col MFMA (N 80->128 masked)
  k_trbp<<<dim3(40, 2), 256, 0, stream>>>(F(C_W4), 80, U(W4T), 2560, 2560, 80, 128);
  k_mfc<5, 512, 512, 4><<<dim3(128, 2), 256, 0, stream>>>(U(PBB), U(W4T), F(C_B4), (void*)(ws + RESID), 8192, 128, 2560, 80);
  k_out<<<2560, 256, 0, stream>>>(F(MELP), F(RESID), d_out, flags);
}